// Round 10
// baseline (347.923 us; speedup 1.0000x reference)
//
#include <hip/hip_runtime.h>

// MOTCAT_Surv R20. R19 passed (absmax 0.0156, 336.4 us); screen2 top again at
// 66.5 us -- and INVARIANT (66.4-66.7) across three schedules (R16/R17/R18):
// it's bound by per-CU resource totals, not latency. The untouched lever: LDS
// read volume = 2048/r b128 per tile per CU (r = rows/wave). R20: r=32 -> 64.
// Wave = rowset (w>>1, 64 rows = 4 bfr sets, ~210 VGPR) x col-half (w&1);
// 4 waves x 256 thr, block = 128 rows, grid (4,64). Reads/tile/CU 64 -> 32
// (halved), read conflicts halve; staging (2-tile groups, R18-proven), MFMA,
// insert VALU totals unchanged. 1 wave/SIMD (R16 proved not-worse than 2).
// Everything outside screen2 byte-identical to R19 (proven).

typedef __attribute__((ext_vector_type(8))) short short8;
typedef __attribute__((ext_vector_type(4))) short short4v;
typedef __attribute__((ext_vector_type(4))) float f32x4;

__device__ inline float bf2f(unsigned short b) {
    unsigned u = ((unsigned)b) << 16;
    return __builtin_bit_cast(float, u);
}
__device__ inline unsigned short f2bf(float f) {   // round-to-nearest-even
    unsigned u = __builtin_bit_cast(unsigned, f);
    unsigned r = u + 0x7fffu + ((u >> 16) & 1u);
    return (unsigned short)(r >> 16);
}
__device__ inline f32x4 mfma16(short8 a, short8 b, f32x4 c) {
    return __builtin_amdgcn_mfma_f32_16x16x32_bf16(a, b, c, 0, 0, 0);
}
// A-frag: lane holds A[m=lane&15][k=(lane>>4)*8+j]; B-frag: B[k][n=lane&15];
// C/D: col=lane&15 (n), row=(lane>>4)*4+reg (m) (learn_hip m89).

__device__ inline void gload_lds16(const unsigned short* g, unsigned short* l) {
    __builtin_amdgcn_global_load_lds(
        (const __attribute__((address_space(1))) void*)g,
        (__attribute__((address_space(3))) void*)l, 16, 0, 0);
}

// split fp32 -> bf16 hi/mid/lo (residual subtractions are exact: operands close)
__device__ inline void split8(const f32x4 v0, const f32x4 v1,
                              short8& hi, short8& md, short8& lo) {
    #pragma unroll
    for (int e = 0; e < 8; e++) {
        float a = (e < 4) ? v0[e] : v1[e - 4];
        unsigned short h = f2bf(a);
        float r1 = a - bf2f(h);
        unsigned short m = f2bf(r1);
        float r2 = r1 - bf2f(m);
        unsigned short l = f2bf(r2);
        hi[e] = (short)h; md[e] = (short)m; lo[e] = (short)l;
    }
}

// ---------------------------------------------------------------------------
// tsplit3: W [K][N] fp32 -> Bt planes [n][k] bf16 (hi, mid, lo) at out + p*PS.
// ---------------------------------------------------------------------------
__launch_bounds__(256)
__global__ void tsplit3(const float* __restrict__ W, unsigned short* __restrict__ out,
                        int K, int N, int PS) {
    __shared__ float T[32][33];
    const int t = threadIdx.x;
    const int n0 = blockIdx.x * 32, k0 = blockIdx.y * 32;
    {
        const int r = t >> 3, c = (t & 7) * 4;
        f32x4 v = *(const f32x4*)&W[(size_t)(k0 + r) * N + n0 + c];
        #pragma unroll
        for (int e = 0; e < 4; e++) T[r][c + e] = v[e];
    }
    __syncthreads();
    const int nr = t >> 3, kc = (t & 7) * 4;
    short4v h4, m4, l4;
    #pragma unroll
    for (int e = 0; e < 4; e++) {
        float a = T[kc + e][nr];
        unsigned short h = f2bf(a);
        float r1 = a - bf2f(h);
        unsigned short m = f2bf(r1);
        float r2 = r1 - bf2f(m);
        h4[e] = (short)h; m4[e] = (short)m; l4[e] = (short)f2bf(r2);
    }
    const size_t o = (size_t)(n0 + nr) * K + k0 + kc;
    *(short4v*)&out[o] = h4;
    *(short4v*)&out[(size_t)PS + o] = m4;
    *(short4v*)&out[(size_t)2 * PS + o] = l4;
}

// ---------------------------------------------------------------------------
// gemmM (proven R15): C = act(A@B + bias) (+=C if ACCUM) on matrix cores.
// ---------------------------------------------------------------------------
template <int ASPLIT, int ACT, int ACCUM>
__launch_bounds__(256)
__global__ void gemmM(const void* __restrict__ Av,
                      const unsigned short* __restrict__ Bt,
                      const float* __restrict__ bias, float* __restrict__ C,
                      int N, int K, int BPS) {
    constexpr int APL = ASPLIT ? 3 : 1;
    constexpr int BPL = ASPLIT ? 3 : 2;
    __shared__ __align__(16) unsigned short LA[2][APL * 2048];
    __shared__ __align__(16) unsigned short LB[2][BPL * 2048];
    const int t = threadIdx.x;
    const int r0 = blockIdx.y * 64, c0 = blockIdx.x * 64;
    const int lid = t & 63, w = t >> 6, g = lid >> 4, m16 = lid & 15;
    const int wm = w >> 1, wn = w & 1;

    f32x4 acc[2][2];
    #pragma unroll
    for (int mf = 0; mf < 2; mf++)
        #pragma unroll
        for (int nf = 0; nf < 2; nf++) acc[mf][nf] = {0.0f, 0.0f, 0.0f, 0.0f};

    const int KT = K >> 5;
    const size_t aoff = (size_t)(r0 + (t >> 2)) * K + (t & 3) * 8;
    const size_t boff = (size_t)(c0 + (t >> 2)) * K + (t & 3) * 8;

    {
        #pragma unroll
        for (int p = 0; p < BPL; p++)
            gload_lds16(&Bt[(size_t)p * BPS + boff], &LB[0][p * 2048 + 8 * t]);
        if (ASPLIT) {
            const float* A = (const float*)Av;
            f32x4 v0 = *(const f32x4*)&A[aoff];
            f32x4 v1 = *(const f32x4*)&A[aoff + 4];
            short8 hi, md, lo;
            split8(v0, v1, hi, md, lo);
            *(short8*)&LA[0][8 * t] = hi;
            *(short8*)&LA[0][2048 + 8 * t] = md;
            *(short8*)&LA[0][4096 + 8 * t] = lo;
        } else {
            const unsigned short* A16 = (const unsigned short*)Av;
            gload_lds16(&A16[aoff], &LA[0][8 * t]);
        }
    }
    __syncthreads();

    for (int kt = 0; kt < KT; kt++) {
        const int cur = kt & 1, nxt = cur ^ 1;
        const bool hn = (kt + 1) < KT;
        f32x4 v0, v1;
        if (hn) {
            const size_t ko = (size_t)(kt + 1) * 32;
            #pragma unroll
            for (int p = 0; p < BPL; p++)
                gload_lds16(&Bt[(size_t)p * BPS + boff + ko],
                            &LB[nxt][p * 2048 + 8 * t]);
            if (ASPLIT) {
                const float* A = (const float*)Av;
                v0 = *(const f32x4*)&A[aoff + ko];
                v1 = *(const f32x4*)&A[aoff + ko + 4];
            } else {
                const unsigned short* A16 = (const unsigned short*)Av;
                gload_lds16(&A16[aoff + ko], &LA[nxt][8 * t]);
            }
        }
        short8 af[2][APL], bf[2][BPL];
        #pragma unroll
        for (int mf = 0; mf < 2; mf++) {
            const int row = wm * 32 + mf * 16 + m16;
            #pragma unroll
            for (int p = 0; p < APL; p++)
                af[mf][p] = *(const short8*)&LA[cur][p * 2048 + row * 32 + g * 8];
        }
        #pragma unroll
        for (int nf = 0; nf < 2; nf++) {
            const int col = wn * 32 + nf * 16 + m16;
            #pragma unroll
            for (int p = 0; p < BPL; p++)
                bf[nf][p] = *(const short8*)&LB[cur][p * 2048 + col * 32 + g * 8];
        }
        #pragma unroll
        for (int mf = 0; mf < 2; mf++)
            #pragma unroll
            for (int nf = 0; nf < 2; nf++) {
                if (ASPLIT) {
                    acc[mf][nf] = mfma16(af[mf][0], bf[nf][0], acc[mf][nf]); // hh
                    acc[mf][nf] = mfma16(af[mf][0], bf[nf][1], acc[mf][nf]); // hm
                    acc[mf][nf] = mfma16(af[mf][1], bf[nf][0], acc[mf][nf]); // mh
                    acc[mf][nf] = mfma16(af[mf][0], bf[nf][2], acc[mf][nf]); // hl
                    acc[mf][nf] = mfma16(af[mf][1], bf[nf][1], acc[mf][nf]); // mm
                    acc[mf][nf] = mfma16(af[mf][2], bf[nf][0], acc[mf][nf]); // lh
                } else {
                    acc[mf][nf] = mfma16(af[mf][0], bf[nf][0], acc[mf][nf]);
                    acc[mf][nf] = mfma16(af[mf][0], bf[nf][1], acc[mf][nf]);
                }
            }
        if (hn && ASPLIT) {
            short8 hi, md, lo;
            split8(v0, v1, hi, md, lo);
            *(short8*)&LA[nxt][8 * t] = hi;
            *(short8*)&LA[nxt][2048 + 8 * t] = md;
            *(short8*)&LA[nxt][4096 + 8 * t] = lo;
        }
        __syncthreads();
    }

    #pragma unroll
    for (int nf = 0; nf < 2; nf++) {
        const int col = c0 + wn * 32 + nf * 16 + m16;
        const float bv = bias[col];
        #pragma unroll
        for (int mf = 0; mf < 2; mf++) {
            #pragma unroll
            for (int r = 0; r < 4; r++) {
                const int row = r0 + wm * 32 + mf * 16 + g * 4 + r;
                float v = acc[mf][nf][r] + bv;
                if (ACT == 1) v = v > 0.0f ? v : 0.01f * v;
                size_t idx = (size_t)row * N + col;
                if (ACCUM) v += C[idx];
                C[idx] = v;
            }
        }
    }
}

// ---------------------------------------------------------------------------
__global__ void colsum_k(const float* __restrict__ x, float* __restrict__ out) {
    int d = threadIdx.x, b = blockIdx.x;
    float s = 0.0f;
    int i0 = b * 128;
    for (int i = 0; i < 128; i++) s += x[(size_t)(i0 + i) * 256 + d];
    out[b * 256 + d] = s;
}
__global__ void meanred_k(const float* __restrict__ p, float* __restrict__ mean) {
    int d = threadIdx.x;
    float s = 0.0f;
    for (int b = 0; b < 64; b++) s += p[b * 256 + d];
    mean[d] = s * (1.0f / 8192.0f);
}
__global__ void finalize_x(float* __restrict__ x, const float* __restrict__ mean) {
    size_t idx = (size_t)blockIdx.x * blockDim.x + threadIdx.x;
    f32x4 v = *(f32x4*)&x[idx * 4];
    int d4 = (int)((idx * 4) & 255);
    f32x4 m = *(const f32x4*)&mean[d4];
    #pragma unroll
    for (int e = 0; e < 4; e++) v[e] = (v[e] + m[e]) * 0.5f;
    *(f32x4*)&x[idx * 4] = v;
}
// prep_k: blocks 0..2047: eh -> eh16 (f2bf); blocks 2048..4095: et -> et16 + rowsum.
__launch_bounds__(256)
__global__ void prep_k(const float* __restrict__ eh, const float* __restrict__ et,
                       unsigned short* __restrict__ eh16,
                       unsigned short* __restrict__ et16,
                       float* __restrict__ rowsum) {
    const int b = blockIdx.x;
    if (b < 2048) {
        size_t idx = (size_t)b * 256 + threadIdx.x;
        f32x4 v = *(const f32x4*)&eh[idx * 4];
        short4v h;
        #pragma unroll
        for (int e = 0; e < 4; e++) h[e] = (short)f2bf(v[e]);
        *(short4v*)&eh16[idx * 4] = h;
    } else {
        const int w = threadIdx.x >> 6, l = threadIdx.x & 63;
        const int i = (b - 2048) * 4 + w;
        f32x4 v = *(const f32x4*)&et[(size_t)i * 256 + l * 4];
        short4v h;
        #pragma unroll
        for (int e = 0; e < 4; e++) h[e] = (short)f2bf(v[e]);
        *(short4v*)&et16[(size_t)i * 256 + l * 4] = h;
        float s = v[0] + v[1] + v[2] + v[3];
        #pragma unroll
        for (int st = 1; st < 64; st <<= 1) s += __shfl_xor(s, st);
        if (l == 0) rowsum[i] = s;
    }
}

// ---------------------------------------------------------------------------
// float keys (col in low-11 mantissa bits), med3 insert. Ascending, tk[0]=min.
// ---------------------------------------------------------------------------
__device__ inline float packkey(float v, unsigned col) {
    unsigned u = (__builtin_bit_cast(unsigned, v) & 0xFFFFF800u) | col;
    return __builtin_bit_cast(float, u);
}
template<int NK>
__device__ inline void insf(float (&tk)[NK], float key) {
    #pragma unroll
    for (int k = 0; k < NK - 1; k++)
        tk[k] = __builtin_amdgcn_fmed3f(key, tk[k + 1], tk[k]);
    tk[NK - 1] = fmaxf(tk[NK - 1], key);
}

// ---------------------------------------------------------------------------
// screen2 R20: 256 thr = 4 waves, block = 128 rows, grid (4,64) = 1 block/CU.
// Wave w: rowset rs=w>>1 (64 rows = 4 bfr sets) x col-half ch=w&1 (16 of 32
// tile cols). Per wave/tile: 8 swizzled ds_read_b128 (reused by 4 row-sets),
// 32 MFMA, 16 med3 inserts -> per-CU reads/tile = 32 (was 64). Staging: 2-tile
// groups double-buffered (R18-proven), 4 granules/thread/tile, 1 barrier/group.
// End: per-queue lg-butterfly top-8 -> mbuf[rs*4+s][ch] -> 128-thread
// cross-half merge -> candi top-8/quarter/row.
// ---------------------------------------------------------------------------
__launch_bounds__(256)
__global__ void screen2(const unsigned short* __restrict__ eh16,
                        const unsigned short* __restrict__ et16,
                        int* __restrict__ candi) {
    __shared__ __align__(16) unsigned short Bs[2][2][8192];  // [buf][tile-in-group]
    __shared__ float mbuf[8][2][16][8];                      // [rowgrp][half][m16][q]
    const int t = threadIdx.x;
    const int cs = blockIdx.x;
    const int r0 = blockIdx.y * 128;
    const int w = t >> 6, lid = t & 63, lg = lid >> 4, m16 = lid & 15;
    const int rs = w >> 1, ch = w & 1;

    short8 bfr[4][8];   // eh B-frags: rows r0+rs*64+s*16+m16, k = ks*32 + lg*8 + j
    #pragma unroll
    for (int s = 0; s < 4; s++)
        #pragma unroll
        for (int ks = 0; ks < 8; ks++)
            bfr[s][ks] = *(const short8*)
                &eh16[(size_t)(r0 + rs * 64 + s * 16 + m16) * 256 + ks * 32 + lg * 8];

    float tk[4][6];
    #pragma unroll
    for (int s = 0; s < 4; s++)
        #pragma unroll
        for (int q = 0; q < 6; q++) tk[s][q] = -3.0e38f;

    // staging map (verbatim R16): per tile, thread stages 4 granules c=0..3:
    // linear granule L = (w*4+c)*64 + lid in [0,1024); L holds (col = L>>5,
    // gorig = (gs&24)|((gs^col)&7)), gs = L&31  (XOR-swizzle)
    int scol[4], goff[4], ldsl[4];
    #pragma unroll
    for (int c = 0; c < 4; c++) {
        int L = (w * 4 + c) * 64 + lid;
        int col = L >> 5, gs = L & 31;
        int gorig = (gs & 24) | ((gs ^ col) & 7);
        scol[c] = col; goff[c] = gorig * 8; ldsl[c] = L * 8;
    }

    // prologue: stage group 0 (tiles 0,1) into buf 0
    #pragma unroll
    for (int tt = 0; tt < 2; tt++) {
        const int j0 = cs * 2048 + tt * 32;
        #pragma unroll
        for (int c = 0; c < 4; c++)
            gload_lds16(&et16[(size_t)(j0 + scol[c]) * 256 + goff[c]],
                        &Bs[0][tt][ldsl[c]]);
    }
    __syncthreads();

    const int swz = m16 & 7;
    const int cbase = (ch * 16 + m16) * 32;   // this wave's col-half, lane's col
    for (int gi = 0; gi < 32; gi++) {
        const int cur = gi & 1;
        if (gi + 1 < 32) {   // issue next group's loads first (overlap compute)
            #pragma unroll
            for (int tt = 0; tt < 2; tt++) {
                const int j1 = cs * 2048 + ((gi + 1) * 2 + tt) * 32;
                #pragma unroll
                for (int c = 0; c < 4; c++)
                    gload_lds16(&et16[(size_t)(j1 + scol[c]) * 256 + goff[c]],
                                &Bs[cur ^ 1][tt][ldsl[c]]);
            }
        }
        #pragma unroll
        for (int tt = 0; tt < 2; tt++) {
            const int tile = gi * 2 + tt;
            const unsigned short* bst = Bs[cur][tt];
            f32x4 a0 = {0.0f, 0.0f, 0.0f, 0.0f}, a1 = a0, a2 = a0, a3 = a0;
            #pragma unroll
            for (int ks = 0; ks < 8; ks++) {
                const int gq = ks * 4 + lg;
                short8 e = *(const short8*)&bst[(cbase + (gq ^ swz)) * 8];
                a0 = mfma16(e, bfr[0][ks], a0);   // A = et (LDS), B = eh (regs)
                a1 = mfma16(e, bfr[1][ks], a1);
                a2 = mfma16(e, bfr[2][ks], a2);
                a3 = mfma16(e, bfr[3][ks], a3);
            }
            const unsigned cb = (unsigned)(tile * 32 + ch * 16 + lg * 4);
            #pragma unroll
            for (int r = 0; r < 4; r++) {
                insf<6>(tk[0], packkey(a0[r], cb + (unsigned)r));
                insf<6>(tk[1], packkey(a1[r], cb + (unsigned)r));
                insf<6>(tk[2], packkey(a2[r], cb + (unsigned)r));
                insf<6>(tk[3], packkey(a3[r], cb + (unsigned)r));
            }
        }
        __syncthreads();   // next group landed; reads of buf cur done
    }

    // per queue: widen to 8 (sentinels), butterfly over the 4 lg-lanes, stash
    #pragma unroll
    for (int s = 0; s < 4; s++) {
        float tk8[8];
        tk8[0] = -3.0e38f; tk8[1] = -3.0e38f;
        #pragma unroll
        for (int q = 0; q < 6; q++) tk8[q + 2] = tk[s][q];
        #pragma unroll
        for (int step = 16; step <= 32; step <<= 1) {
            float ok[8];
            #pragma unroll
            for (int q = 0; q < 8; q++) ok[q] = __shfl_xor(tk8[q], step);
            #pragma unroll
            for (int q = 0; q < 8; q++) insf<8>(tk8, ok[q]);
        }
        if (lg == 0) {
            #pragma unroll
            for (int q = 0; q < 8; q++) mbuf[rs * 4 + s][ch][m16][q] = tk8[q];
        }
    }
    __syncthreads();

    // cross-half merge: thread t (<128) owns row r0+t; both halves' lists sorted.
    if (t < 128) {
        float tk8[8];
        #pragma unroll
        for (int q = 0; q < 8; q++) tk8[q] = mbuf[t >> 4][0][t & 15][q];
        #pragma unroll
        for (int q = 0; q < 8; q++) insf<8>(tk8, mbuf[t >> 4][1][t & 15][q]);
        const int row = r0 + t;
        #pragma unroll
        for (int q = 0; q < 8; q++)
            candi[(size_t)row * 32 + cs * 8 + q] =
                cs * 2048 + (int)(__builtin_bit_cast(unsigned, tk8[q]) & 0x7FFu);
    }
}

// ---------------------------------------------------------------------------
// Stage D (proven R19): LDS-free, barrier-free; 4 waves/block, one row per wave.
// Coalesced 8-lanes/candidate rescore; packed-key fmax-butterfly top-6.
// ---------------------------------------------------------------------------
__launch_bounds__(256)
__global__ void stageD(const float* __restrict__ eh, const float* __restrict__ et,
                       const float* __restrict__ rowsum,
                       const int* __restrict__ candi,
                       unsigned short* __restrict__ m1, unsigned short* __restrict__ m2) {
    const int w = threadIdx.x >> 6, l = threadIdx.x & 63;
    const int i = blockIdx.x * 4 + w;
    const int c_own = l & 31;

    const int jown = candi[(size_t)i * 32 + c_own] & 8191;

    // ---- phase 1: fp64 rescore, 8 lanes per candidate, 4 passes ----
    const int q = l & 7, g8 = l >> 3;
    const float* er = &eh[(size_t)i * 256];
    double vres[4];
    #pragma unroll
    for (int p = 0; p < 4; p++) {
        const int cc = p * 8 + g8;
        const int jc = __shfl(jown, cc);
        const float* tr = &et[(size_t)jc * 256];
        double a = 0.0;
        #pragma unroll
        for (int tt = 0; tt < 8; tt++) {
            const int o = (tt * 8 + q) * 4;
            f32x4 av = *(const f32x4*)&er[o];
            f32x4 bv = *(const f32x4*)&tr[o];
            a += (double)av[0] * bv[0] + (double)av[1] * bv[1] +
                 (double)av[2] * bv[2] + (double)av[3] * bv[3];
        }
        a += __shfl_xor(a, 1);
        a += __shfl_xor(a, 2);
        a += __shfl_xor(a, 4);
        vres[p] = a * 0.0625;
    }
    const int src = (c_own & 7) * 8;
    double t0 = __shfl(vres[0], src), t1 = __shfl(vres[1], src);
    double t2 = __shfl(vres[2], src), t3 = __shfl(vres[3], src);
    const int ps = c_own >> 3;
    double v = ps == 0 ? t0 : ps == 1 ? t1 : ps == 2 ? t2 : t3;

    // ---- phase 2: packed-key top-6 (5-step fmax butterflies) ----
    unsigned long long kb = __builtin_bit_cast(unsigned long long, v);
    double key = __builtin_bit_cast(double, (kb & ~31ULL) | (unsigned long long)c_own);
    float wf[6]; int selc[6];
    #pragma unroll
    for (int s = 0; s < 6; s++) {
        double b = key;
        #pragma unroll
        for (int st = 1; st < 32; st <<= 1) {
            double ob = __shfl_xor(b, st);
            b = b > ob ? b : ob;
        }
        selc[s] = (int)(__builtin_bit_cast(unsigned long long, b) & 31ULL);
        wf[s] = (float)b;
        if (key == b) key = -1.0e300;   // kill winner (keys unique)
    }
    int selj[6];
    #pragma unroll
    for (int s = 0; s < 6; s++) selj[s] = __shfl(jown, selc[s]);

    float sp[6];
    {
        float mx = wf[0];
        #pragma unroll
        for (int s = 1; s < 6; s++) mx = fmaxf(mx, wf[s]);
        float se = 0.0f, e6[6];
        #pragma unroll
        for (int s = 0; s < 6; s++) { e6[s] = expf(wf[s] - mx); se += e6[s]; }
        #pragma unroll
        for (int s = 0; s < 6; s++) sp[s] = e6[s] / se;
    }

    // ---- phase 3: message construction, per-lane d-slice ----
    f32x4 eh4 = *(const f32x4*)&eh[(size_t)i * 256 + l * 4];
    f32x4 nb[6];
    #pragma unroll
    for (int k = 0; k < 6; k++)
        nb[k] = *(const f32x4*)&et[(size_t)selj[k] * 256 + l * 4];

    float pgs[6], pns[6];
    #pragma unroll
    for (int k = 0; k < 6; k++) {
        const float pk = sp[k];
        float pg = 0.0f;
        #pragma unroll
        for (int e = 0; e < 4; e++) {
            float ehd = eh4[e], nbd = nb[k][e];
            float ehr = pk * nbd + (1.0f - pk) * ehd;
            pg += tanhf(ehd + ehr);
        }
        #pragma unroll
        for (int st = 1; st < 64; st <<= 1) pg += __shfl_xor(pg, st);
        pgs[k] = pg;
        pns[k] = rowsum[selj[k]];
    }

    float skp[6];
    {
        float ka[6], mx = -3.0e38f, se = 0.0f;
        #pragma unroll
        for (int k = 0; k < 6; k++) { ka[k] = pns[k] * pgs[k]; mx = fmaxf(mx, ka[k]); }
        #pragma unroll
        for (int k = 0; k < 6; k++) { ka[k] = expf(ka[k] - mx); se += ka[k]; }
        #pragma unroll
        for (int k = 0; k < 6; k++) skp[k] = ka[k] / se;
    }

    f32x4 enh = {0.0f, 0.0f, 0.0f, 0.0f};
    #pragma unroll
    for (int k = 0; k < 6; k++) {
        const float kp = skp[k];
        #pragma unroll
        for (int e = 0; e < 4; e++) enh[e] += kp * nb[k][e];
    }
    short4v h1, h2;
    #pragma unroll
    for (int e = 0; e < 4; e++) {
        h1[e] = (short)f2bf(eh4[e] + enh[e]);
        h2[e] = (short)f2bf(eh4[e] * enh[e]);
    }
    *(short4v*)&m1[(size_t)i * 256 + l * 4] = h1;
    *(short4v*)&m2[(size_t)i * 256 + l * 4] = h2;
}

// ---------------------------------------------------------------------------
__launch_bounds__(256)
__global__ void gate2_k(const float* __restrict__ g1, const float* __restrict__ Ag2,
                        const float* __restrict__ bg2, float* __restrict__ glog) {
    const int i = blockIdx.x * 256 + threadIdx.x;
    float s = 0.0f;
    #pragma unroll 4
    for (int h = 0; h < 128; h++) s += g1[(size_t)i * 128 + h] * Ag2[h];
    glog[i] = s + bg2[0];
}

__launch_bounds__(1024)
__global__ void softmax_g(const float* __restrict__ glog, float* __restrict__ gexp,
                          float* __restrict__ scal) {
    const int t = threadIdx.x;
    __shared__ float red[1024];
    float v[8];
    float m = -3.0e38f;
    #pragma unroll
    for (int c = 0; c < 8; c++) { v[c] = glog[t + c * 1024]; m = fmaxf(m, v[c]); }
    red[t] = m; __syncthreads();
    for (int st = 512; st > 0; st >>= 1) {
        if (t < st) red[t] = fmaxf(red[t], red[t + st]);
        __syncthreads();
    }
    float gm = red[0]; __syncthreads();
    float s = 0.0f;
    #pragma unroll
    for (int c = 0; c < 8; c++) {
        float e = expf(v[c] - gm);
        gexp[t + c * 1024] = e;
        s += e;
    }
    red[t] = s; __syncthreads();
    for (int st = 512; st > 0; st >>= 1) {
        if (t < st) red[t] += red[t + st];
        __syncthreads();
    }
    if (t == 0) scal[0] = 1.0f / red[0];
}

__launch_bounds__(256)
__global__ void wsum_k(const float* __restrict__ emsg, const float* __restrict__ gexp,
                       float* __restrict__ egp) {
    const int b = blockIdx.x, d = threadIdx.x;
    float s = 0.0f;
    const int i0 = b * 128;
    for (int i = 0; i < 128; i++) s += gexp[i0 + i] * emsg[(size_t)(i0 + i) * 256 + d];
    egp[b * 256 + d] = s;
}
__global__ void egfinal_f(const float* __restrict__ egp, const float* __restrict__ scal,
                          float* __restrict__ out) {
    const int d = threadIdx.x;
    float s = 0.0f;
    for (int b = 0; b < 64; b++) s += egp[b * 256 + d];
    out[d] = s * scal[0];
}

__global__ void wsbad_k(float* __restrict__ out) { out[3] = 9000.0f; }

// ---------------------------------------------------------------------------
extern "C" void kernel_launch(void* const* d_in, const int* in_sizes, int n_in,
                              void* d_out, int out_size, void* d_ws, size_t ws_size,
                              hipStream_t stream) {
    (void)in_sizes; (void)n_in; (void)out_size;
    const float* x_path = (const float*)d_in[0];
    const float* fc1_W  = (const float*)d_in[1];
    const float* fc1_b  = (const float*)d_in[2];
    const float* Wh     = (const float*)d_in[3];
    const float* bh     = (const float*)d_in[4];
    const float* Wt     = (const float*)d_in[5];
    const float* bt     = (const float*)d_in[6];
    const float* W1     = (const float*)d_in[7];
    const float* b1     = (const float*)d_in[8];
    const float* W2     = (const float*)d_in[9];
    const float* b2     = (const float*)d_in[10];
    const float* Ag1    = (const float*)d_in[11];
    const float* bg1    = (const float*)d_in[12];
    const float* Ag2    = (const float*)d_in[13];
    const float* bg2    = (const float*)d_in[14];
    float* out_f = (float*)d_out;   // fp32: e_msg [0,2097152), e_g [2097152,2097408)

    const size_t WS_NEEDED = 26412048;
    if (ws_size < WS_NEEDED) {
        hipLaunchKernelGGL(wsbad_k, dim3(1), dim3(1), 0, stream, out_f);
        return;
    }

    char* ws = (char*)d_ws;
    float* x     = (float*)(ws + 0);
    unsigned short* eh16 = (unsigned short*)(ws + 0);
    unsigned short* et16 = (unsigned short*)(ws + 4194304);
    unsigned short* m1b  = (unsigned short*)(ws + 0);
    unsigned short* m2b  = (unsigned short*)(ws + 4194304);
    float* g1    = (float*)(ws + 0);          // 8192x128 fp32 (after m1b/m2b dead)
    float* eh    = (float*)(ws + 8388608);
    float* emsg  = out_f;                     // e_msg written straight to d_out
    float* et    = (float*)(ws + 16777216);
    int*   candi = (int*)  (ws + 25165824);
    float* rowsum= (float*)(ws + 26214400);   // meanp slot (dead after meanred)
    float* meanp = (float*)(ws + 26214400);
    float* meanv = (float*)(ws + 26279936);
    float* glog  = (float*)(ws + 26280960);
    float* gexp  = (float*)(ws + 26313728);
    float* egp   = (float*)(ws + 26346496);
    float* scal  = (float*)(ws + 26412032);

    // weight planes in temporarily-dead regions (all stream-ordered safe):
    unsigned short* Fp = (unsigned short*)(ws + 16777216);   // fc1, in et region
    unsigned short* WHp = (unsigned short*)(ws + 25165824);  // in candi region
    unsigned short* WTp = (unsigned short*)(ws + 25559040);
    unsigned short* P1 = (unsigned short*)(ws + 16777216);   // in et region (post-stageD)
    unsigned short* P2 = (unsigned short*)(ws + 17170432);
    unsigned short* Gp = (unsigned short*)(ws + 25165824);   // in candi region (post-stageD)

    dim3 gg(4, 128);
    // 1) x = leaky(x_path @ fc1_W + fc1_b)  [MFMA 3-split]
    hipLaunchKernelGGL(tsplit3, dim3(8, 32), dim3(256), 0, stream,
                       fc1_W, Fp, 1024, 256, 262144);
    hipLaunchKernelGGL((gemmM<1, 1, 0>), gg, dim3(256), 0, stream,
                       (const void*)x_path, Fp, fc1_b, x, 256, 1024, 262144);
    // 2) x = (x + mean(x)) * 0.5
    hipLaunchKernelGGL(colsum_k, dim3(64), dim3(256), 0, stream, x, meanp);
    hipLaunchKernelGGL(meanred_k, dim3(1), dim3(256), 0, stream, meanp, meanv);
    hipLaunchKernelGGL(finalize_x, dim3(2048), dim3(256), 0, stream, x, meanv);
    // 3) e_h, e_t  [MFMA 3-split, fp32-accurate]
    hipLaunchKernelGGL(tsplit3, dim3(8, 8), dim3(256), 0, stream,
                       Wh, WHp, 256, 256, 65536);
    hipLaunchKernelGGL(tsplit3, dim3(8, 8), dim3(256), 0, stream,
                       Wt, WTp, 256, 256, 65536);
    hipLaunchKernelGGL((gemmM<1, 0, 0>), gg, dim3(256), 0, stream,
                       (const void*)x, WHp, bh, eh, 256, 256, 65536);
    hipLaunchKernelGGL((gemmM<1, 0, 0>), gg, dim3(256), 0, stream,
                       (const void*)x, WTp, bt, et, 256, 256, 65536);
    // 4) bf16 copies + et row sums (fused)
    hipLaunchKernelGGL(prep_k, dim3(4096), dim3(256), 0, stream,
                       eh, et, eh16, et16, rowsum);
    // 5) screening: 256-thr blocks, 64 rows/wave, 2-tile groups, 1 block/CU
    hipLaunchKernelGGL(screen2, dim3(4, 64), dim3(256), 0, stream, eh16, et16, candi);
    // 6) fp64 select + message -> m1b/m2b
    hipLaunchKernelGGL(stageD, dim3(2048), dim3(256), 0, stream, eh, et, rowsum,
                       candi, m1b, m2b);
    // 7) e_msg = leaky(m1@W1+b1) + leaky(m2@W2+b2)  -> straight into out_f
    hipLaunchKernelGGL(tsplit3, dim3(8, 8), dim3(256), 0, stream,
                       W1, P1, 256, 256, 65536);
    hipLaunchKernelGGL(tsplit3, dim3(8, 8), dim3(256), 0, stream,
                       W2, P2, 256, 256, 65536);
    hipLaunchKernelGGL((gemmM<0, 1, 0>), gg, dim3(256), 0, stream,
                       (const void*)m1b, P1, b1, emsg, 256, 256, 65536);
    hipLaunchKernelGGL((gemmM<0, 1, 1>), gg, dim3(256), 0, stream,
                       (const void*)m2b, P2, b2, emsg, 256, 256, 65536);
    // 8) readout: g1 = leaky(emsg@Ag1+bg1) [MFMA 3-split]; then small ops
    hipLaunchKernelGGL(tsplit3, dim3(4, 8), dim3(256), 0, stream,
                       Ag1, Gp, 256, 128, 32768);
    hipLaunchKernelGGL((gemmM<1, 1, 0>), dim3(2, 128), dim3(256), 0, stream,
                       (const void*)emsg, Gp, bg1, g1, 128, 256, 32768);
    hipLaunchKernelGGL(gate2_k, dim3(32), dim3(256), 0, stream, g1, Ag2, bg2, glog);
    hipLaunchKernelGGL(softmax_g, dim3(1), dim3(1024), 0, stream, glog, gexp, scal);
    hipLaunchKernelGGL(wsum_k, dim3(64), dim3(256), 0, stream, emsg, gexp, egp);
    hipLaunchKernelGGL(egfinal_f, dim3(1), dim3(256), 0, stream, egp, scal, out_f + 2097152);
}

// Round 11
// 328.194 us; speedup vs baseline: 1.0601x; 1.0601x over previous
//
#include <hip/hip_runtime.h>

// MOTCAT_Surv R21. R20 REGRESSED (screen2 76 vs 66.5, total 348): r=64 halved
// LDS reads (conflicts 4.2e6->2.1e6 as predicted) but 124 VGPR + doubled serial
// insert work at 1 wave/SIMD cost more. screen2 @66us = 517 TF effective
// (MfmaUtil 20% x 2.5PF) -- at the fused-GEMM structural ceiling; REVERTED to
// proven R18/R19 512-thr version. New lever: gemmM's on-the-fly split8 is ~16
// VALU ops/elem (~224 cyc/kt/wave vs 120 MFMA) -- dominates fc1's K-loop.
// R21: truncation-based split (planes = mantissa-truncate, exact residual
// subtractions; h+m+l error <=2^-24 rel vs 2^-26 RNE -- still fp32-ulp class,
// ~6 orders below top-6 logit gaps) at ~7 ops/elem. Everything else = R19.

typedef __attribute__((ext_vector_type(8))) short short8;
typedef __attribute__((ext_vector_type(4))) short short4v;
typedef __attribute__((ext_vector_type(4))) float f32x4;

__device__ inline float bf2f(unsigned short b) {
    unsigned u = ((unsigned)b) << 16;
    return __builtin_bit_cast(float, u);
}
__device__ inline unsigned short f2bf(float f) {   // round-to-nearest-even
    unsigned u = __builtin_bit_cast(unsigned, f);
    unsigned r = u + 0x7fffu + ((u >> 16) & 1u);
    return (unsigned short)(r >> 16);
}
__device__ inline f32x4 mfma16(short8 a, short8 b, f32x4 c) {
    return __builtin_amdgcn_mfma_f32_16x16x32_bf16(a, b, c, 0, 0, 0);
}
// A-frag: lane holds A[m=lane&15][k=(lane>>4)*8+j]; B-frag: B[k][n=lane&15];
// C/D: col=lane&15 (n), row=(lane>>4)*4+reg (m) (learn_hip m89).

__device__ inline void gload_lds16(const unsigned short* g, unsigned short* l) {
    __builtin_amdgcn_global_load_lds(
        (const __attribute__((address_space(1))) void*)g,
        (__attribute__((address_space(3))) void*)l, 16, 0, 0);
}

// fast trunc-split fp32 -> bf16 hi/mid/lo. Planes are mantissa truncations;
// residual subtractions are exact (same-exponent suffixes). h+m+l = a with
// error <= 2^-24 rel (fp32-ulp class; selection gaps are ~6 orders larger).
__device__ inline void split8(const f32x4 v0, const f32x4 v1,
                              short8& hi, short8& md, short8& lo) {
    #pragma unroll
    for (int e = 0; e < 8; e++) {
        float a = (e < 4) ? v0[e] : v1[e - 4];
        unsigned ua = __builtin_bit_cast(unsigned, a);
        float h = __builtin_bit_cast(float, ua & 0xFFFF0000u);
        float r1 = a - h;                       // exact
        unsigned u1 = __builtin_bit_cast(unsigned, r1);
        float m = __builtin_bit_cast(float, u1 & 0xFFFF0000u);
        float r2 = r1 - m;                      // exact
        unsigned u2 = __builtin_bit_cast(unsigned, r2);
        hi[e] = (short)(ua >> 16);
        md[e] = (short)(u1 >> 16);
        lo[e] = (short)(u2 >> 16);
    }
}

// ---------------------------------------------------------------------------
// tsplit3: W [K][N] fp32 -> Bt planes [n][k] bf16 (hi, mid, lo) at out + p*PS.
// (one-time cost; keeps RNE split -- unchanged from proven R15)
// ---------------------------------------------------------------------------
__launch_bounds__(256)
__global__ void tsplit3(const float* __restrict__ W, unsigned short* __restrict__ out,
                        int K, int N, int PS) {
    __shared__ float T[32][33];
    const int t = threadIdx.x;
    const int n0 = blockIdx.x * 32, k0 = blockIdx.y * 32;
    {
        const int r = t >> 3, c = (t & 7) * 4;
        f32x4 v = *(const f32x4*)&W[(size_t)(k0 + r) * N + n0 + c];
        #pragma unroll
        for (int e = 0; e < 4; e++) T[r][c + e] = v[e];
    }
    __syncthreads();
    const int nr = t >> 3, kc = (t & 7) * 4;
    short4v h4, m4, l4;
    #pragma unroll
    for (int e = 0; e < 4; e++) {
        float a = T[kc + e][nr];
        unsigned short h = f2bf(a);
        float r1 = a - bf2f(h);
        unsigned short m = f2bf(r1);
        float r2 = r1 - bf2f(m);
        h4[e] = (short)h; m4[e] = (short)m; l4[e] = (short)f2bf(r2);
    }
    const size_t o = (size_t)(n0 + nr) * K + k0 + kc;
    *(short4v*)&out[o] = h4;
    *(short4v*)&out[(size_t)PS + o] = m4;
    *(short4v*)&out[(size_t)2 * PS + o] = l4;
}

// ---------------------------------------------------------------------------
// gemmM (proven R15 + trunc split8): C = act(A@B + bias) (+=C if ACCUM).
// ---------------------------------------------------------------------------
template <int ASPLIT, int ACT, int ACCUM>
__launch_bounds__(256)
__global__ void gemmM(const void* __restrict__ Av,
                      const unsigned short* __restrict__ Bt,
                      const float* __restrict__ bias, float* __restrict__ C,
                      int N, int K, int BPS) {
    constexpr int APL = ASPLIT ? 3 : 1;
    constexpr int BPL = ASPLIT ? 3 : 2;
    __shared__ __align__(16) unsigned short LA[2][APL * 2048];
    __shared__ __align__(16) unsigned short LB[2][BPL * 2048];
    const int t = threadIdx.x;
    const int r0 = blockIdx.y * 64, c0 = blockIdx.x * 64;
    const int lid = t & 63, w = t >> 6, g = lid >> 4, m16 = lid & 15;
    const int wm = w >> 1, wn = w & 1;

    f32x4 acc[2][2];
    #pragma unroll
    for (int mf = 0; mf < 2; mf++)
        #pragma unroll
        for (int nf = 0; nf < 2; nf++) acc[mf][nf] = {0.0f, 0.0f, 0.0f, 0.0f};

    const int KT = K >> 5;
    const size_t aoff = (size_t)(r0 + (t >> 2)) * K + (t & 3) * 8;
    const size_t boff = (size_t)(c0 + (t >> 2)) * K + (t & 3) * 8;

    {
        #pragma unroll
        for (int p = 0; p < BPL; p++)
            gload_lds16(&Bt[(size_t)p * BPS + boff], &LB[0][p * 2048 + 8 * t]);
        if (ASPLIT) {
            const float* A = (const float*)Av;
            f32x4 v0 = *(const f32x4*)&A[aoff];
            f32x4 v1 = *(const f32x4*)&A[aoff + 4];
            short8 hi, md, lo;
            split8(v0, v1, hi, md, lo);
            *(short8*)&LA[0][8 * t] = hi;
            *(short8*)&LA[0][2048 + 8 * t] = md;
            *(short8*)&LA[0][4096 + 8 * t] = lo;
        } else {
            const unsigned short* A16 = (const unsigned short*)Av;
            gload_lds16(&A16[aoff], &LA[0][8 * t]);
        }
    }
    __syncthreads();

    for (int kt = 0; kt < KT; kt++) {
        const int cur = kt & 1, nxt = cur ^ 1;
        const bool hn = (kt + 1) < KT;
        f32x4 v0, v1;
        if (hn) {
            const size_t ko = (size_t)(kt + 1) * 32;
            #pragma unroll
            for (int p = 0; p < BPL; p++)
                gload_lds16(&Bt[(size_t)p * BPS + boff + ko],
                            &LB[nxt][p * 2048 + 8 * t]);
            if (ASPLIT) {
                const float* A = (const float*)Av;
                v0 = *(const f32x4*)&A[aoff + ko];
                v1 = *(const f32x4*)&A[aoff + ko + 4];
            } else {
                const unsigned short* A16 = (const unsigned short*)Av;
                gload_lds16(&A16[aoff + ko], &LA[nxt][8 * t]);
            }
        }
        short8 af[2][APL], bf[2][BPL];
        #pragma unroll
        for (int mf = 0; mf < 2; mf++) {
            const int row = wm * 32 + mf * 16 + m16;
            #pragma unroll
            for (int p = 0; p < APL; p++)
                af[mf][p] = *(const short8*)&LA[cur][p * 2048 + row * 32 + g * 8];
        }
        #pragma unroll
        for (int nf = 0; nf < 2; nf++) {
            const int col = wn * 32 + nf * 16 + m16;
            #pragma unroll
            for (int p = 0; p < BPL; p++)
                bf[nf][p] = *(const short8*)&LB[cur][p * 2048 + col * 32 + g * 8];
        }
        #pragma unroll
        for (int mf = 0; mf < 2; mf++)
            #pragma unroll
            for (int nf = 0; nf < 2; nf++) {
                if (ASPLIT) {
                    acc[mf][nf] = mfma16(af[mf][0], bf[nf][0], acc[mf][nf]); // hh
                    acc[mf][nf] = mfma16(af[mf][0], bf[nf][1], acc[mf][nf]); // hm
                    acc[mf][nf] = mfma16(af[mf][1], bf[nf][0], acc[mf][nf]); // mh
                    acc[mf][nf] = mfma16(af[mf][0], bf[nf][2], acc[mf][nf]); // hl
                    acc[mf][nf] = mfma16(af[mf][1], bf[nf][1], acc[mf][nf]); // mm
                    acc[mf][nf] = mfma16(af[mf][2], bf[nf][0], acc[mf][nf]); // lh
                } else {
                    acc[mf][nf] = mfma16(af[mf][0], bf[nf][0], acc[mf][nf]);
                    acc[mf][nf] = mfma16(af[mf][0], bf[nf][1], acc[mf][nf]);
                }
            }
        if (hn && ASPLIT) {
            short8 hi, md, lo;
            split8(v0, v1, hi, md, lo);
            *(short8*)&LA[nxt][8 * t] = hi;
            *(short8*)&LA[nxt][2048 + 8 * t] = md;
            *(short8*)&LA[nxt][4096 + 8 * t] = lo;
        }
        __syncthreads();
    }

    #pragma unroll
    for (int nf = 0; nf < 2; nf++) {
        const int col = c0 + wn * 32 + nf * 16 + m16;
        const float bv = bias[col];
        #pragma unroll
        for (int mf = 0; mf < 2; mf++) {
            #pragma unroll
            for (int r = 0; r < 4; r++) {
                const int row = r0 + wm * 32 + mf * 16 + g * 4 + r;
                float v = acc[mf][nf][r] + bv;
                if (ACT == 1) v = v > 0.0f ? v : 0.01f * v;
                size_t idx = (size_t)row * N + col;
                if (ACCUM) v += C[idx];
                C[idx] = v;
            }
        }
    }
}

// ---------------------------------------------------------------------------
__global__ void colsum_k(const float* __restrict__ x, float* __restrict__ out) {
    int d = threadIdx.x, b = blockIdx.x;
    float s = 0.0f;
    int i0 = b * 128;
    for (int i = 0; i < 128; i++) s += x[(size_t)(i0 + i) * 256 + d];
    out[b * 256 + d] = s;
}
__global__ void meanred_k(const float* __restrict__ p, float* __restrict__ mean) {
    int d = threadIdx.x;
    float s = 0.0f;
    for (int b = 0; b < 64; b++) s += p[b * 256 + d];
    mean[d] = s * (1.0f / 8192.0f);
}
__global__ void finalize_x(float* __restrict__ x, const float* __restrict__ mean) {
    size_t idx = (size_t)blockIdx.x * blockDim.x + threadIdx.x;
    f32x4 v = *(f32x4*)&x[idx * 4];
    int d4 = (int)((idx * 4) & 255);
    f32x4 m = *(const f32x4*)&mean[d4];
    #pragma unroll
    for (int e = 0; e < 4; e++) v[e] = (v[e] + m[e]) * 0.5f;
    *(f32x4*)&x[idx * 4] = v;
}
// prep_k: blocks 0..2047: eh -> eh16 (f2bf); blocks 2048..4095: et -> et16 + rowsum.
__launch_bounds__(256)
__global__ void prep_k(const float* __restrict__ eh, const float* __restrict__ et,
                       unsigned short* __restrict__ eh16,
                       unsigned short* __restrict__ et16,
                       float* __restrict__ rowsum) {
    const int b = blockIdx.x;
    if (b < 2048) {
        size_t idx = (size_t)b * 256 + threadIdx.x;
        f32x4 v = *(const f32x4*)&eh[idx * 4];
        short4v h;
        #pragma unroll
        for (int e = 0; e < 4; e++) h[e] = (short)f2bf(v[e]);
        *(short4v*)&eh16[idx * 4] = h;
    } else {
        const int w = threadIdx.x >> 6, l = threadIdx.x & 63;
        const int i = (b - 2048) * 4 + w;
        f32x4 v = *(const f32x4*)&et[(size_t)i * 256 + l * 4];
        short4v h;
        #pragma unroll
        for (int e = 0; e < 4; e++) h[e] = (short)f2bf(v[e]);
        *(short4v*)&et16[(size_t)i * 256 + l * 4] = h;
        float s = v[0] + v[1] + v[2] + v[3];
        #pragma unroll
        for (int st = 1; st < 64; st <<= 1) s += __shfl_xor(s, st);
        if (l == 0) rowsum[i] = s;
    }
}

// ---------------------------------------------------------------------------
// float keys (col in low-11 mantissa bits), med3 insert. Ascending, tk[0]=min.
// ---------------------------------------------------------------------------
__device__ inline float packkey(float v, unsigned col) {
    unsigned u = (__builtin_bit_cast(unsigned, v) & 0xFFFFF800u) | col;
    return __builtin_bit_cast(float, u);
}
template<int NK>
__device__ inline void insf(float (&tk)[NK], float key) {
    #pragma unroll
    for (int k = 0; k < NK - 1; k++)
        tk[k] = __builtin_amdgcn_fmed3f(key, tk[k + 1], tk[k]);
    tk[NK - 1] = fmaxf(tk[NK - 1], key);
}

// ---------------------------------------------------------------------------
// screen2 (proven R18/R19, REVERTED from R20): 512 thr = 8 waves, 128 rows/
// block, grid (4,64), 2-tile groups double-buffered, 1 barrier per group.
// Wave = rowset (w>>1, 32 rows) x col-half (w&1).
// ---------------------------------------------------------------------------
__launch_bounds__(512)
__global__ void screen2(const unsigned short* __restrict__ eh16,
                        const unsigned short* __restrict__ et16,
                        int* __restrict__ candi) {
    __shared__ __align__(16) unsigned short Bs[2][2][8192];  // [buf][tile-in-group]
    __shared__ float mbuf[8][2][16][8];                      // [rowgrp][half][m16][q]
    const int t = threadIdx.x;
    const int cs = blockIdx.x;
    const int r0 = blockIdx.y * 128;
    const int w = t >> 6, lid = t & 63, lg = lid >> 4, m16 = lid & 15;
    const int rs = w >> 1, ch = w & 1;

    short8 bfr[2][8];   // eh B-frags: rows r0+rs*32+s*16+m16, k = ks*32 + lg*8 + j
    #pragma unroll
    for (int s = 0; s < 2; s++)
        #pragma unroll
        for (int ks = 0; ks < 8; ks++)
            bfr[s][ks] = *(const short8*)
                &eh16[(size_t)(r0 + rs * 32 + s * 16 + m16) * 256 + ks * 32 + lg * 8];

    float tk0[6], tk1[6];
    #pragma unroll
    for (int q = 0; q < 6; q++) { tk0[q] = -3.0e38f; tk1[q] = -3.0e38f; }

    int scol[2], goff[2], ldsl[2];
    #pragma unroll
    for (int c = 0; c < 2; c++) {
        int L = (w * 2 + c) * 64 + lid;
        int col = L >> 5, gs = L & 31;
        int gorig = (gs & 24) | ((gs ^ col) & 7);
        scol[c] = col; goff[c] = gorig * 8; ldsl[c] = L * 8;
    }

    #pragma unroll
    for (int tt = 0; tt < 2; tt++) {
        const int j0 = cs * 2048 + tt * 32;
        #pragma unroll
        for (int c = 0; c < 2; c++)
            gload_lds16(&et16[(size_t)(j0 + scol[c]) * 256 + goff[c]],
                        &Bs[0][tt][ldsl[c]]);
    }
    __syncthreads();

    const int swz = m16 & 7;
    const int cbase = (ch * 16 + m16) * 32;
    for (int gi = 0; gi < 32; gi++) {
        const int cur = gi & 1;
        if (gi + 1 < 32) {
            #pragma unroll
            for (int tt = 0; tt < 2; tt++) {
                const int j1 = cs * 2048 + ((gi + 1) * 2 + tt) * 32;
                #pragma unroll
                for (int c = 0; c < 2; c++)
                    gload_lds16(&et16[(size_t)(j1 + scol[c]) * 256 + goff[c]],
                                &Bs[cur ^ 1][tt][ldsl[c]]);
            }
        }
        #pragma unroll
        for (int tt = 0; tt < 2; tt++) {
            const int tile = gi * 2 + tt;
            const unsigned short* bst = Bs[cur][tt];
            f32x4 a0 = {0.0f, 0.0f, 0.0f, 0.0f}, a1 = a0;
            #pragma unroll
            for (int ks = 0; ks < 8; ks++) {
                const int gq = ks * 4 + lg;
                short8 e = *(const short8*)&bst[(cbase + (gq ^ swz)) * 8];
                a0 = mfma16(e, bfr[0][ks], a0);
                a1 = mfma16(e, bfr[1][ks], a1);
            }
            const unsigned cb = (unsigned)(tile * 32 + ch * 16 + lg * 4);
            #pragma unroll
            for (int r = 0; r < 4; r++) {
                insf<6>(tk0, packkey(a0[r], cb + (unsigned)r));
                insf<6>(tk1, packkey(a1[r], cb + (unsigned)r));
            }
        }
        __syncthreads();
    }

    #pragma unroll
    for (int s = 0; s < 2; s++) {
        float tk8[8];
        tk8[0] = -3.0e38f; tk8[1] = -3.0e38f;
        #pragma unroll
        for (int q = 0; q < 6; q++) tk8[q + 2] = s ? tk1[q] : tk0[q];
        #pragma unroll
        for (int step = 16; step <= 32; step <<= 1) {
            float ok[8];
            #pragma unroll
            for (int q = 0; q < 8; q++) ok[q] = __shfl_xor(tk8[q], step);
            #pragma unroll
            for (int q = 0; q < 8; q++) insf<8>(tk8, ok[q]);
        }
        if (lg == 0) {
            #pragma unroll
            for (int q = 0; q < 8; q++) mbuf[rs * 2 + s][ch][m16][q] = tk8[q];
        }
    }
    __syncthreads();

    if (t < 128) {
        float tk8[8];
        #pragma unroll
        for (int q = 0; q < 8; q++) tk8[q] = mbuf[t >> 4][0][t & 15][q];
        #pragma unroll
        for (int q = 0; q < 8; q++) insf<8>(tk8, mbuf[t >> 4][1][t & 15][q]);
        const int row = r0 + t;
        #pragma unroll
        for (int q = 0; q < 8; q++)
            candi[(size_t)row * 32 + cs * 8 + q] =
                cs * 2048 + (int)(__builtin_bit_cast(unsigned, tk8[q]) & 0x7FFu);
    }
}

// ---------------------------------------------------------------------------
// Stage D (proven R19): LDS-free, barrier-free; 4 waves/block, one row per wave.
// Coalesced 8-lanes/candidate rescore; packed-key fmax-butterfly top-6.
// ---------------------------------------------------------------------------
__launch_bounds__(256)
__global__ void stageD(const float* __restrict__ eh, const float* __restrict__ et,
                       const float* __restrict__ rowsum,
                       const int* __restrict__ candi,
                       unsigned short* __restrict__ m1, unsigned short* __restrict__ m2) {
    const int w = threadIdx.x >> 6, l = threadIdx.x & 63;
    const int i = blockIdx.x * 4 + w;
    const int c_own = l & 31;

    const int jown = candi[(size_t)i * 32 + c_own] & 8191;

    // ---- phase 1: fp64 rescore, 8 lanes per candidate, 4 passes ----
    const int q = l & 7, g8 = l >> 3;
    const float* er = &eh[(size_t)i * 256];
    double vres[4];
    #pragma unroll
    for (int p = 0; p < 4; p++) {
        const int cc = p * 8 + g8;
        const int jc = __shfl(jown, cc);
        const float* tr = &et[(size_t)jc * 256];
        double a = 0.0;
        #pragma unroll
        for (int tt = 0; tt < 8; tt++) {
            const int o = (tt * 8 + q) * 4;
            f32x4 av = *(const f32x4*)&er[o];
            f32x4 bv = *(const f32x4*)&tr[o];
            a += (double)av[0] * bv[0] + (double)av[1] * bv[1] +
                 (double)av[2] * bv[2] + (double)av[3] * bv[3];
        }
        a += __shfl_xor(a, 1);
        a += __shfl_xor(a, 2);
        a += __shfl_xor(a, 4);
        vres[p] = a * 0.0625;
    }
    const int src = (c_own & 7) * 8;
    double t0 = __shfl(vres[0], src), t1 = __shfl(vres[1], src);
    double t2 = __shfl(vres[2], src), t3 = __shfl(vres[3], src);
    const int ps = c_own >> 3;
    double v = ps == 0 ? t0 : ps == 1 ? t1 : ps == 2 ? t2 : t3;

    // ---- phase 2: packed-key top-6 (5-step fmax butterflies) ----
    unsigned long long kb = __builtin_bit_cast(unsigned long long, v);
    double key = __builtin_bit_cast(double, (kb & ~31ULL) | (unsigned long long)c_own);
    float wf[6]; int selc[6];
    #pragma unroll
    for (int s = 0; s < 6; s++) {
        double b = key;
        #pragma unroll
        for (int st = 1; st < 32; st <<= 1) {
            double ob = __shfl_xor(b, st);
            b = b > ob ? b : ob;
        }
        selc[s] = (int)(__builtin_bit_cast(unsigned long long, b) & 31ULL);
        wf[s] = (float)b;
        if (key == b) key = -1.0e300;   // kill winner (keys unique)
    }
    int selj[6];
    #pragma unroll
    for (int s = 0; s < 6; s++) selj[s] = __shfl(jown, selc[s]);

    float sp[6];
    {
        float mx = wf[0];
        #pragma unroll
        for (int s = 1; s < 6; s++) mx = fmaxf(mx, wf[s]);
        float se = 0.0f, e6[6];
        #pragma unroll
        for (int s = 0; s < 6; s++) { e6[s] = expf(wf[s] - mx); se += e6[s]; }
        #pragma unroll
        for (int s = 0; s < 6; s++) sp[s] = e6[s] / se;
    }

    // ---- phase 3: message construction, per-lane d-slice ----
    f32x4 eh4 = *(const f32x4*)&eh[(size_t)i * 256 + l * 4];
    f32x4 nb[6];
    #pragma unroll
    for (int k = 0; k < 6; k++)
        nb[k] = *(const f32x4*)&et[(size_t)selj[k] * 256 + l * 4];

    float pgs[6], pns[6];
    #pragma unroll
    for (int k = 0; k < 6; k++) {
        const float pk = sp[k];
        float pg = 0.0f;
        #pragma unroll
        for (int e = 0; e < 4; e++) {
            float ehd = eh4[e], nbd = nb[k][e];
            float ehr = pk * nbd + (1.0f - pk) * ehd;
            pg += tanhf(ehd + ehr);
        }
        #pragma unroll
        for (int st = 1; st < 64; st <<= 1) pg += __shfl_xor(pg, st);
        pgs[k] = pg;
        pns[k] = rowsum[selj[k]];
    }

    float skp[6];
    {
        float ka[6], mx = -3.0e38f, se = 0.0f;
        #pragma unroll
        for (int k = 0; k < 6; k++) { ka[k] = pns[k] * pgs[k]; mx = fmaxf(mx, ka[k]); }
        #pragma unroll
        for (int k = 0; k < 6; k++) { ka[k] = expf(ka[k] - mx); se += ka[k]; }
        #pragma unroll
        for (int k = 0; k < 6; k++) skp[k] = ka[k] / se;
    }

    f32x4 enh = {0.0f, 0.0f, 0.0f, 0.0f};
    #pragma unroll
    for (int k = 0; k < 6; k++) {
        const float kp = skp[k];
        #pragma unroll
        for (int e = 0; e < 4; e++) enh[e] += kp * nb[k][e];
    }
    short4v h1, h2;
    #pragma unroll
    for (int e = 0; e < 4; e++) {
        h1[e] = (short)f2bf(eh4[e] + enh[e]);
        h2[e] = (short)f2bf(eh4[e] * enh[e]);
    }
    *(short4v*)&m1[(size_t)i * 256 + l * 4] = h1;
    *(short4v*)&m2[(size_t)i * 256 + l * 4] = h2;
}

// ---------------------------------------------------------------------------
__launch_bounds__(256)
__global__ void gate2_k(const float* __restrict__ g1, const float* __restrict__ Ag2,
                        const float* __restrict__ bg2, float* __restrict__ glog) {
    const int i = blockIdx.x * 256 + threadIdx.x;
    float s = 0.0f;
    #pragma unroll 4
    for (int h = 0; h < 128; h++) s += g1[(size_t)i * 128 + h] * Ag2[h];
    glog[i] = s + bg2[0];
}

__launch_bounds__(1024)
__global__ void softmax_g(const float* __restrict__ glog, float* __restrict__ gexp,
                          float* __restrict__ scal) {
    const int t = threadIdx.x;
    __shared__ float red[1024];
    float v[8];
    float m = -3.0e38f;
    #pragma unroll
    for (int c = 0; c < 8; c++) { v[c] = glog[t + c * 1024]; m = fmaxf(m, v[c]); }
    red[t] = m; __syncthreads();
    for (int st = 512; st > 0; st >>= 1) {
        if (t < st) red[t] = fmaxf(red[t], red[t + st]);
        __syncthreads();
    }
    float gm = red[0]; __syncthreads();
    float s = 0.0f;
    #pragma unroll
    for (int c = 0; c < 8; c++) {
        float e = expf(v[c] - gm);
        gexp[t + c * 1024] = e;
        s += e;
    }
    red[t] = s; __syncthreads();
    for (int st = 512; st > 0; st >>= 1) {
        if (t < st) red[t] += red[t + st];
        __syncthreads();
    }
    if (t == 0) scal[0] = 1.0f / red[0];
}

__launch_bounds__(256)
__global__ void wsum_k(const float* __restrict__ emsg, const float* __restrict__ gexp,
                       float* __restrict__ egp) {
    const int b = blockIdx.x, d = threadIdx.x;
    float s = 0.0f;
    const int i0 = b * 128;
    for (int i = 0; i < 128; i++) s += gexp[i0 + i] * emsg[(size_t)(i0 + i) * 256 + d];
    egp[b * 256 + d] = s;
}
__global__ void egfinal_f(const float* __restrict__ egp, const float* __restrict__ scal,
                          float* __restrict__ out) {
    const int d = threadIdx.x;
    float s = 0.0f;
    for (int b = 0; b < 64; b++) s += egp[b * 256 + d];
    out[d] = s * scal[0];
}

__global__ void wsbad_k(float* __restrict__ out) { out[3] = 9000.0f; }

// ---------------------------------------------------------------------------
extern "C" void kernel_launch(void* const* d_in, const int* in_sizes, int n_in,
                              void* d_out, int out_size, void* d_ws, size_t ws_size,
                              hipStream_t stream) {
    (void)in_sizes; (void)n_in; (void)out_size;
    const float* x_path = (const float*)d_in[0];
    const float* fc1_W  = (const float*)d_in[1];
    const float* fc1_b  = (const float*)d_in[2];
    const float* Wh     = (const float*)d_in[3];
    const float* bh     = (const float*)d_in[4];
    const float* Wt     = (const float*)d_in[5];
    const float* bt     = (const float*)d_in[6];
    const float* W1     = (const float*)d_in[7];
    const float* b1     = (const float*)d_in[8];
    const float* W2     = (const float*)d_in[9];
    const float* b2     = (const float*)d_in[10];
    const float* Ag1    = (const float*)d_in[11];
    const float* bg1    = (const float*)d_in[12];
    const float* Ag2    = (const float*)d_in[13];
    const float* bg2    = (const float*)d_in[14];
    float* out_f = (float*)d_out;   // fp32: e_msg [0,2097152), e_g [2097152,2097408)

    const size_t WS_NEEDED = 26412048;
    if (ws_size < WS_NEEDED) {
        hipLaunchKernelGGL(wsbad_k, dim3(1), dim3(1), 0, stream, out_f);
        return;
    }

    char* ws = (char*)d_ws;
    float* x     = (float*)(ws + 0);
    unsigned short* eh16 = (unsigned short*)(ws + 0);
    unsigned short* et16 = (unsigned short*)(ws + 4194304);
    unsigned short* m1b  = (unsigned short*)(ws + 0);
    unsigned short* m2b  = (unsigned short*)(ws + 4194304);
    float* g1    = (float*)(ws + 0);          // 8192x128 fp32 (after m1b/m2b dead)
    float* eh    = (float*)(ws + 8388608);
    float* emsg  = out_f;                     // e_msg written straight to d_out
    float* et    = (float*)(ws + 16777216);
    int*   candi = (int*)  (ws + 25165824);
    float* rowsum= (float*)(ws + 26214400);   // meanp slot (dead after meanred)
    float* meanp = (float*)(ws + 26214400);
    float* meanv = (float*)(ws + 26279936);
    float* glog  = (float*)(ws + 26280960);
    float* gexp  = (float*)(ws + 26313728);
    float* egp   = (float*)(ws + 26346496);
    float* scal  = (float*)(ws + 26412032);

    // weight planes in temporarily-dead regions (all stream-ordered safe):
    unsigned short* Fp = (unsigned short*)(ws + 16777216);   // fc1, in et region
    unsigned short* WHp = (unsigned short*)(ws + 25165824);  // in candi region
    unsigned short* WTp = (unsigned short*)(ws + 25559040);
    unsigned short* P1 = (unsigned short*)(ws + 16777216);   // in et region (post-stageD)
    unsigned short* P2 = (unsigned short*)(ws + 17170432);
    unsigned short* Gp = (unsigned short*)(ws + 25165824);   // in candi region (post-stageD)

    dim3 gg(4, 128);
    // 1) x = leaky(x_path @ fc1_W + fc1_b)  [MFMA 3-split]
    hipLaunchKernelGGL(tsplit3, dim3(8, 32), dim3(256), 0, stream,
                       fc1_W, Fp, 1024, 256, 262144);
    hipLaunchKernelGGL((gemmM<1, 1, 0>), gg, dim3(256), 0, stream,
                       (const void*)x_path, Fp, fc1_b, x, 256, 1024, 262144);
    // 2) x = (x + mean(x)) * 0.5
    hipLaunchKernelGGL(colsum_k, dim3(64), dim3(256), 0, stream, x, meanp);
    hipLaunchKernelGGL(meanred_k, dim3(1), dim3(256), 0, stream, meanp, meanv);
    hipLaunchKernelGGL(finalize_x, dim3(2048), dim3(256), 0, stream, x, meanv);
    // 3) e_h, e_t  [MFMA 3-split, fp32-accurate]
    hipLaunchKernelGGL(tsplit3, dim3(8, 8), dim3(256), 0, stream,
                       Wh, WHp, 256, 256, 65536);
    hipLaunchKernelGGL(tsplit3, dim3(8, 8), dim3(256), 0, stream,
                       Wt, WTp, 256, 256, 65536);
    hipLaunchKernelGGL((gemmM<1, 0, 0>), gg, dim3(256), 0, stream,
                       (const void*)x, WHp, bh, eh, 256, 256, 65536);
    hipLaunchKernelGGL((gemmM<1, 0, 0>), gg, dim3(256), 0, stream,
                       (const void*)x, WTp, bt, et, 256, 256, 65536);
    // 4) bf16 copies + et row sums (fused)
    hipLaunchKernelGGL(prep_k, dim3(4096), dim3(256), 0, stream,
                       eh, et, eh16, et16, rowsum);
    // 5) screening: 512-thr blocks, 128 rows, 2-tile groups, 1 block/CU
    hipLaunchKernelGGL(screen2, dim3(4, 64), dim3(512), 0, stream, eh16, et16, candi);
    // 6) fp64 select + message -> m1b/m2b
    hipLaunchKernelGGL(stageD, dim3(2048), dim3(256), 0, stream, eh, et, rowsum,
                       candi, m1b, m2b);
    // 7) e_msg = leaky(m1@W1+b1) + leaky(m2@W2+b2)  -> straight into out_f
    hipLaunchKernelGGL(tsplit3, dim3(8, 8), dim3(256), 0, stream,
                       W1, P1, 256, 256, 65536);
    hipLaunchKernelGGL(tsplit3, dim3(8, 8), dim3(256), 0, stream,
                       W2, P2, 256, 256, 65536);
    hipLaunchKernelGGL((gemmM<0, 1, 0>), gg, dim3(256), 0, stream,
                       (const void*)m1b, P1, b1, emsg, 256, 256, 65536);
    hipLaunchKernelGGL((gemmM<0, 1, 1>), gg, dim3(256), 0, stream,
                       (const void*)m2b, P2, b2, emsg, 256, 256, 65536);
    // 8) readout: g1 = leaky(emsg@Ag1+bg1) [MFMA 3-split]; then small ops
    hipLaunchKernelGGL(tsplit3, dim3(4, 8), dim3(256), 0, stream,
                       Ag1, Gp, 256, 128, 32768);
    hipLaunchKernelGGL((gemmM<1, 1, 0>), dim3(2, 128), dim3(256), 0, stream,
                       (const void*)emsg, Gp, bg1, g1, 128, 256, 32768);
    hipLaunchKernelGGL(gate2_k, dim3(32), dim3(256), 0, stream, g1, Ag2, bg2, glog);
    hipLaunchKernelGGL(softmax_g, dim3(1), dim3(1024), 0, stream, glog, gexp, scal);
    hipLaunchKernelGGL(wsum_k, dim3(64), dim3(256), 0, stream, emsg, gexp, egp);
    hipLaunchKernelGGL(egfinal_f, dim3(1), dim3(256), 0, stream, egp, scal, out_f + 2097152);
}

// Round 12
// 311.970 us; speedup vs baseline: 1.1152x; 1.0520x over previous
//
#include <hip/hip_runtime.h>

// MOTCAT_Surv R22. R21 passed (328.2 us, absmax 0.0156); screen2 proven at its
// structural ceiling (64.4 us, 517 TF effective). Remaining ~264 us = GEMM chain
// + launch tail. R22 (no proven kernel touched): (a) fold mean-mix into eh/et
// bias: (x+mean)*0.5@W = (0.5x)@W + (bh + 0.5*mean@W) -> finalize_x DELETED
// (16MB traffic + launch); tiny mwv_k computes the bias vectors. (b) gemmD:
// eh+et in ONE 512-thr kernel, A staged/split once for both B mats (halves
// split VALU + A traffic, -1 launch). (c) gemmE: emsg = leaky(m1@W1+b1) +
// leaky(m2@W2+b2) in ONE kernel, sum written once -> 8MB ACCUM re-read gone.
// (d) paired tsplit3p launches. Launches 23 -> 18. Rounding deltas ~1e-7 rel
// (same class as R13/R19 changes that passed).

typedef __attribute__((ext_vector_type(8))) short short8;
typedef __attribute__((ext_vector_type(4))) short short4v;
typedef __attribute__((ext_vector_type(4))) float f32x4;

__device__ inline float bf2f(unsigned short b) {
    unsigned u = ((unsigned)b) << 16;
    return __builtin_bit_cast(float, u);
}
__device__ inline unsigned short f2bf(float f) {   // round-to-nearest-even
    unsigned u = __builtin_bit_cast(unsigned, f);
    unsigned r = u + 0x7fffu + ((u >> 16) & 1u);
    return (unsigned short)(r >> 16);
}
__device__ inline f32x4 mfma16(short8 a, short8 b, f32x4 c) {
    return __builtin_amdgcn_mfma_f32_16x16x32_bf16(a, b, c, 0, 0, 0);
}
// A-frag: lane holds A[m=lane&15][k=(lane>>4)*8+j]; B-frag: B[k][n=lane&15];
// C/D: col=lane&15 (n), row=(lane>>4)*4+reg (m) (learn_hip m89).

__device__ inline void gload_lds16(const unsigned short* g, unsigned short* l) {
    __builtin_amdgcn_global_load_lds(
        (const __attribute__((address_space(1))) void*)g,
        (__attribute__((address_space(3))) void*)l, 16, 0, 0);
}

// trunc-split fp32 -> bf16 hi/mid/lo (proven R21): exact residual subtractions,
// h+m+l error <= 2^-24 rel.
__device__ inline void split8(const f32x4 v0, const f32x4 v1,
                              short8& hi, short8& md, short8& lo) {
    #pragma unroll
    for (int e = 0; e < 8; e++) {
        float a = (e < 4) ? v0[e] : v1[e - 4];
        unsigned ua = __builtin_bit_cast(unsigned, a);
        float h = __builtin_bit_cast(float, ua & 0xFFFF0000u);
        float r1 = a - h;
        unsigned u1 = __builtin_bit_cast(unsigned, r1);
        float m = __builtin_bit_cast(float, u1 & 0xFFFF0000u);
        float r2 = r1 - m;
        unsigned u2 = __builtin_bit_cast(unsigned, r2);
        hi[e] = (short)(ua >> 16);
        md[e] = (short)(u1 >> 16);
        lo[e] = (short)(u2 >> 16);
    }
}
__device__ inline void split4(f32x4 v, short4v& hi, short4v& md, short4v& lo) {
    #pragma unroll
    for (int e = 0; e < 4; e++) {
        float a = v[e];
        unsigned ua = __builtin_bit_cast(unsigned, a);
        float h = __builtin_bit_cast(float, ua & 0xFFFF0000u);
        float r1 = a - h;
        unsigned u1 = __builtin_bit_cast(unsigned, r1);
        float m = __builtin_bit_cast(float, u1 & 0xFFFF0000u);
        float r2 = r1 - m;
        unsigned u2 = __builtin_bit_cast(unsigned, r2);
        hi[e] = (short)(ua >> 16);
        md[e] = (short)(u1 >> 16);
        lo[e] = (short)(u2 >> 16);
    }
}

// ---------------------------------------------------------------------------
// tsplit3: W [K][N] fp32 -> Bt planes [n][k] bf16 (hi, mid, lo) at out + p*PS.
// tsplit3p: two weights in one launch via blockIdx.z.
// ---------------------------------------------------------------------------
__device__ inline void tsplit_body(const float* __restrict__ W,
                                   unsigned short* __restrict__ out,
                                   int K, int N, int PS, int bx, int by, int t) {
    __shared__ float T[32][33];
    const int n0 = bx * 32, k0 = by * 32;
    {
        const int r = t >> 3, c = (t & 7) * 4;
        f32x4 v = *(const f32x4*)&W[(size_t)(k0 + r) * N + n0 + c];
        #pragma unroll
        for (int e = 0; e < 4; e++) T[r][c + e] = v[e];
    }
    __syncthreads();
    const int nr = t >> 3, kc = (t & 7) * 4;
    short4v h4, m4, l4;
    #pragma unroll
    for (int e = 0; e < 4; e++) {
        float a = T[kc + e][nr];
        unsigned short h = f2bf(a);
        float r1 = a - bf2f(h);
        unsigned short m = f2bf(r1);
        float r2 = r1 - bf2f(m);
        h4[e] = (short)h; m4[e] = (short)m; l4[e] = (short)f2bf(r2);
    }
    const size_t o = (size_t)(n0 + nr) * K + k0 + kc;
    *(short4v*)&out[o] = h4;
    *(short4v*)&out[(size_t)PS + o] = m4;
    *(short4v*)&out[(size_t)2 * PS + o] = l4;
}
__launch_bounds__(256)
__global__ void tsplit3(const float* __restrict__ W, unsigned short* __restrict__ out,
                        int K, int N, int PS) {
    tsplit_body(W, out, K, N, PS, blockIdx.x, blockIdx.y, threadIdx.x);
}
__launch_bounds__(256)
__global__ void tsplit3p(const float* __restrict__ Wa, const float* __restrict__ Wb,
                         unsigned short* __restrict__ oa, unsigned short* __restrict__ ob,
                         int K, int N, int PS) {
    tsplit_body(blockIdx.z ? Wb : Wa, blockIdx.z ? ob : oa,
                K, N, PS, blockIdx.x, blockIdx.y, threadIdx.x);
}

// ---------------------------------------------------------------------------
// gemmM (proven R21): C = act(A@B + bias) (+=C if ACCUM) on matrix cores.
// ---------------------------------------------------------------------------
template <int ASPLIT, int ACT, int ACCUM>
__launch_bounds__(256)
__global__ void gemmM(const void* __restrict__ Av,
                      const unsigned short* __restrict__ Bt,
                      const float* __restrict__ bias, float* __restrict__ C,
                      int N, int K, int BPS) {
    constexpr int APL = ASPLIT ? 3 : 1;
    constexpr int BPL = ASPLIT ? 3 : 2;
    __shared__ __align__(16) unsigned short LA[2][APL * 2048];
    __shared__ __align__(16) unsigned short LB[2][BPL * 2048];
    const int t = threadIdx.x;
    const int r0 = blockIdx.y * 64, c0 = blockIdx.x * 64;
    const int lid = t & 63, w = t >> 6, g = lid >> 4, m16 = lid & 15;
    const int wm = w >> 1, wn = w & 1;

    f32x4 acc[2][2];
    #pragma unroll
    for (int mf = 0; mf < 2; mf++)
        #pragma unroll
        for (int nf = 0; nf < 2; nf++) acc[mf][nf] = {0.0f, 0.0f, 0.0f, 0.0f};

    const int KT = K >> 5;
    const size_t aoff = (size_t)(r0 + (t >> 2)) * K + (t & 3) * 8;
    const size_t boff = (size_t)(c0 + (t >> 2)) * K + (t & 3) * 8;

    {
        #pragma unroll
        for (int p = 0; p < BPL; p++)
            gload_lds16(&Bt[(size_t)p * BPS + boff], &LB[0][p * 2048 + 8 * t]);
        if (ASPLIT) {
            const float* A = (const float*)Av;
            f32x4 v0 = *(const f32x4*)&A[aoff];
            f32x4 v1 = *(const f32x4*)&A[aoff + 4];
            short8 hi, md, lo;
            split8(v0, v1, hi, md, lo);
            *(short8*)&LA[0][8 * t] = hi;
            *(short8*)&LA[0][2048 + 8 * t] = md;
            *(short8*)&LA[0][4096 + 8 * t] = lo;
        } else {
            const unsigned short* A16 = (const unsigned short*)Av;
            gload_lds16(&A16[aoff], &LA[0][8 * t]);
        }
    }
    __syncthreads();

    for (int kt = 0; kt < KT; kt++) {
        const int cur = kt & 1, nxt = cur ^ 1;
        const bool hn = (kt + 1) < KT;
        f32x4 v0, v1;
        if (hn) {
            const size_t ko = (size_t)(kt + 1) * 32;
            #pragma unroll
            for (int p = 0; p < BPL; p++)
                gload_lds16(&Bt[(size_t)p * BPS + boff + ko],
                            &LB[nxt][p * 2048 + 8 * t]);
            if (ASPLIT) {
                const float* A = (const float*)Av;
                v0 = *(const f32x4*)&A[aoff + ko];
                v1 = *(const f32x4*)&A[aoff + ko + 4];
            } else {
                const unsigned short* A16 = (const unsigned short*)Av;
                gload_lds16(&A16[aoff + ko], &LA[nxt][8 * t]);
            }
        }
        short8 af[2][APL], bf[2][BPL];
        #pragma unroll
        for (int mf = 0; mf < 2; mf++) {
            const int row = wm * 32 + mf * 16 + m16;
            #pragma unroll
            for (int p = 0; p < APL; p++)
                af[mf][p] = *(const short8*)&LA[cur][p * 2048 + row * 32 + g * 8];
        }
        #pragma unroll
        for (int nf = 0; nf < 2; nf++) {
            const int col = wn * 32 + nf * 16 + m16;
            #pragma unroll
            for (int p = 0; p < BPL; p++)
                bf[nf][p] = *(const short8*)&LB[cur][p * 2048 + col * 32 + g * 8];
        }
        #pragma unroll
        for (int mf = 0; mf < 2; mf++)
            #pragma unroll
            for (int nf = 0; nf < 2; nf++) {
                if (ASPLIT) {
                    acc[mf][nf] = mfma16(af[mf][0], bf[nf][0], acc[mf][nf]); // hh
                    acc[mf][nf] = mfma16(af[mf][0], bf[nf][1], acc[mf][nf]); // hm
                    acc[mf][nf] = mfma16(af[mf][1], bf[nf][0], acc[mf][nf]); // mh
                    acc[mf][nf] = mfma16(af[mf][0], bf[nf][2], acc[mf][nf]); // hl
                    acc[mf][nf] = mfma16(af[mf][1], bf[nf][1], acc[mf][nf]); // mm
                    acc[mf][nf] = mfma16(af[mf][2], bf[nf][0], acc[mf][nf]); // lh
                } else {
                    acc[mf][nf] = mfma16(af[mf][0], bf[nf][0], acc[mf][nf]);
                    acc[mf][nf] = mfma16(af[mf][0], bf[nf][1], acc[mf][nf]);
                }
            }
        if (hn && ASPLIT) {
            short8 hi, md, lo;
            split8(v0, v1, hi, md, lo);
            *(short8*)&LA[nxt][8 * t] = hi;
            *(short8*)&LA[nxt][2048 + 8 * t] = md;
            *(short8*)&LA[nxt][4096 + 8 * t] = lo;
        }
        __syncthreads();
    }

    #pragma unroll
    for (int nf = 0; nf < 2; nf++) {
        const int col = c0 + wn * 32 + nf * 16 + m16;
        const float bv = bias[col];
        #pragma unroll
        for (int mf = 0; mf < 2; mf++) {
            #pragma unroll
            for (int r = 0; r < 4; r++) {
                const int row = r0 + wm * 32 + mf * 16 + g * 4 + r;
                float v = acc[mf][nf][r] + bv;
                if (ACT == 1) v = v > 0.0f ? v : 0.01f * v;
                size_t idx = (size_t)row * N + col;
                if (ACCUM) v += C[idx];
                C[idx] = v;
            }
        }
    }
}

// ---------------------------------------------------------------------------
// gemmD: dual-B shared-A. eh = (0.5x)@Wh + biasH; et = (0.5x)@Wt + biasT.
// 512 thr = 8 waves: waves 0-3 -> eh quadrants, 4-7 -> et. A staged+split ONCE.
// K=256 fixed (KT=8), N=256, 64x64 tile, grid (4,128).
// ---------------------------------------------------------------------------
__launch_bounds__(512)
__global__ void gemmD(const float* __restrict__ A,
                      const unsigned short* __restrict__ BH,
                      const unsigned short* __restrict__ BT,
                      const float* __restrict__ biasH, const float* __restrict__ biasT,
                      float* __restrict__ CH, float* __restrict__ CT, int BPS) {
    __shared__ __align__(16) unsigned short LA[2][3 * 2048];
    __shared__ __align__(16) unsigned short LB[2][6 * 2048];
    const int t = threadIdx.x;
    const int r0 = blockIdx.y * 64, c0 = blockIdx.x * 64;
    const int lid = t & 63, w = t >> 6, g = lid >> 4, m16 = lid & 15;
    const int mat = w >> 2, wsub = w & 3, wm = wsub >> 1, wn = wsub & 1;
    const int K = 256;

    f32x4 acc[2][2];
    #pragma unroll
    for (int mf = 0; mf < 2; mf++)
        #pragma unroll
        for (int nf = 0; nf < 2; nf++) acc[mf][nf] = {0.0f, 0.0f, 0.0f, 0.0f};

    // A staging map: thread t -> row t>>3, k-quad (t&7)*4
    const int arow = t >> 3, akq = (t & 7) * 4;
    const size_t aoff = (size_t)(r0 + arow) * K + akq;
    const int aldst = arow * 32 + akq;          // shorts, per plane
    // B staging: 3 granules/thread: L = t + s*512; kgran=L&3, col=(L>>2)&63, mp=L>>8
    int bmp[3], bdst[3];
    size_t bsrc[3];
    #pragma unroll
    for (int s = 0; s < 3; s++) {
        int L = t + s * 512;
        int mp = L >> 8;
        bmp[s] = mp;
        bdst[s] = mp * 2048 + (L & 255) * 8;
        int mm = mp >= 3, pl = mp - 3 * mm;
        const unsigned short* base = mm ? BT : BH;
        bsrc[s] = (size_t)(base - BH) + (size_t)pl * BPS +
                  (size_t)(c0 + ((L >> 2) & 63)) * K + (L & 3) * 8;
    }

    // prologue
    {
        #pragma unroll
        for (int s = 0; s < 3; s++)
            gload_lds16(&BH[bsrc[s]], &LB[0][bdst[s]]);
        f32x4 v = *(const f32x4*)&A[aoff];
        #pragma unroll
        for (int e = 0; e < 4; e++) v[e] *= 0.5f;
        short4v hi, md, lo;
        split4(v, hi, md, lo);
        *(short4v*)&LA[0][aldst] = hi;
        *(short4v*)&LA[0][2048 + aldst] = md;
        *(short4v*)&LA[0][4096 + aldst] = lo;
    }
    __syncthreads();

    for (int kt = 0; kt < 8; kt++) {
        const int cur = kt & 1, nxt = cur ^ 1;
        const bool hn = (kt + 1) < 8;
        f32x4 v;
        if (hn) {
            const size_t ko = (size_t)(kt + 1) * 32;
            #pragma unroll
            for (int s = 0; s < 3; s++)
                gload_lds16(&BH[bsrc[s] + ko], &LB[nxt][bdst[s]]);
            v = *(const f32x4*)&A[aoff + ko];
            #pragma unroll
            for (int e = 0; e < 4; e++) v[e] *= 0.5f;
        }
        short8 af[2][3], bf[2][3];
        #pragma unroll
        for (int mf = 0; mf < 2; mf++) {
            const int row = wm * 32 + mf * 16 + m16;
            #pragma unroll
            for (int p = 0; p < 3; p++)
                af[mf][p] = *(const short8*)&LA[cur][p * 2048 + row * 32 + g * 8];
        }
        #pragma unroll
        for (int nf = 0; nf < 2; nf++) {
            const int col = wn * 32 + nf * 16 + m16;
            #pragma unroll
            for (int p = 0; p < 3; p++)
                bf[nf][p] = *(const short8*)
                    &LB[cur][(mat * 3 + p) * 2048 + col * 32 + g * 8];
        }
        #pragma unroll
        for (int mf = 0; mf < 2; mf++)
            #pragma unroll
            for (int nf = 0; nf < 2; nf++) {
                acc[mf][nf] = mfma16(af[mf][0], bf[nf][0], acc[mf][nf]); // hh
                acc[mf][nf] = mfma16(af[mf][0], bf[nf][1], acc[mf][nf]); // hm
                acc[mf][nf] = mfma16(af[mf][1], bf[nf][0], acc[mf][nf]); // mh
                acc[mf][nf] = mfma16(af[mf][0], bf[nf][2], acc[mf][nf]); // hl
                acc[mf][nf] = mfma16(af[mf][1], bf[nf][1], acc[mf][nf]); // mm
                acc[mf][nf] = mfma16(af[mf][2], bf[nf][0], acc[mf][nf]); // lh
            }
        if (hn) {
            short4v hi, md, lo;
            split4(v, hi, md, lo);
            *(short4v*)&LA[nxt][aldst] = hi;
            *(short4v*)&LA[nxt][2048 + aldst] = md;
            *(short4v*)&LA[nxt][4096 + aldst] = lo;
        }
        __syncthreads();
    }

    float* C = mat ? CT : CH;
    const float* bias = mat ? biasT : biasH;
    #pragma unroll
    for (int nf = 0; nf < 2; nf++) {
        const int col = c0 + wn * 32 + nf * 16 + m16;
        const float bv = bias[col];
        #pragma unroll
        for (int mf = 0; mf < 2; mf++) {
            #pragma unroll
            for (int r = 0; r < 4; r++) {
                const int row = r0 + wm * 32 + mf * 16 + g * 4 + r;
                C[(size_t)row * 256 + col] = acc[mf][nf][r] + bv;
            }
        }
    }
}

// ---------------------------------------------------------------------------
// gemmE: emsg = leaky(m1@W1+b1) + leaky(m2@W2+b2), single pass (no C re-read).
// A bf16 (m1b, m2b via gload), B 2-plane each. 256 thr, 64x64, K=256, grid(4,128).
// ---------------------------------------------------------------------------
__launch_bounds__(256)
__global__ void gemmE(const unsigned short* __restrict__ A1,
                      const unsigned short* __restrict__ A2,
                      const unsigned short* __restrict__ P1,
                      const unsigned short* __restrict__ P2,
                      const float* __restrict__ b1, const float* __restrict__ b2,
                      float* __restrict__ C, int BPS) {
    __shared__ __align__(16) unsigned short LA[2][2 * 2048];
    __shared__ __align__(16) unsigned short LB[2][4 * 2048];
    const int t = threadIdx.x;
    const int r0 = blockIdx.y * 64, c0 = blockIdx.x * 64;
    const int lid = t & 63, w = t >> 6, g = lid >> 4, m16 = lid & 15;
    const int wm = w >> 1, wn = w & 1;
    const int K = 256;

    f32x4 acc[2][2][2];   // [mat][mf][nf]
    #pragma unroll
    for (int m = 0; m < 2; m++)
        #pragma unroll
        for (int mf = 0; mf < 2; mf++)
            #pragma unroll
            for (int nf = 0; nf < 2; nf++) acc[m][mf][nf] = {0.0f, 0.0f, 0.0f, 0.0f};

    const size_t aoff = (size_t)(r0 + (t >> 2)) * K + (t & 3) * 8;
    const size_t boff = (size_t)(c0 + (t >> 2)) * K + (t & 3) * 8;

    {
        gload_lds16(&A1[aoff], &LA[0][8 * t]);
        gload_lds16(&A2[aoff], &LA[0][2048 + 8 * t]);
        gload_lds16(&P1[boff], &LB[0][8 * t]);
        gload_lds16(&P1[(size_t)BPS + boff], &LB[0][2048 + 8 * t]);
        gload_lds16(&P2[boff], &LB[0][4096 + 8 * t]);
        gload_lds16(&P2[(size_t)BPS + boff], &LB[0][6144 + 8 * t]);
    }
    __syncthreads();

    for (int kt = 0; kt < 8; kt++) {
        const int cur = kt & 1, nxt = cur ^ 1;
        const bool hn = (kt + 1) < 8;
        if (hn) {
            const size_t ko = (size_t)(kt + 1) * 32;
            gload_lds16(&A1[aoff + ko], &LA[nxt][8 * t]);
            gload_lds16(&A2[aoff + ko], &LA[nxt][2048 + 8 * t]);
            gload_lds16(&P1[boff + ko], &LB[nxt][8 * t]);
            gload_lds16(&P1[(size_t)BPS + boff + ko], &LB[nxt][2048 + 8 * t]);
            gload_lds16(&P2[boff + ko], &LB[nxt][4096 + 8 * t]);
            gload_lds16(&P2[(size_t)BPS + boff + ko], &LB[nxt][6144 + 8 * t]);
        }
        short8 af[2][2], bf[2][2][2];   // af[mat][mf]; bf[mat][nf][plane]
        #pragma unroll
        for (int m = 0; m < 2; m++)
            #pragma unroll
            for (int mf = 0; mf < 2; mf++) {
                const int row = wm * 32 + mf * 16 + m16;
                af[m][mf] = *(const short8*)&LA[cur][m * 2048 + row * 32 + g * 8];
            }
        #pragma unroll
        for (int m = 0; m < 2; m++)
            #pragma unroll
            for (int nf = 0; nf < 2; nf++) {
                const int col = wn * 32 + nf * 16 + m16;
                #pragma unroll
                for (int p = 0; p < 2; p++)
                    bf[m][nf][p] = *(const short8*)
                        &LB[cur][(m * 2 + p) * 2048 + col * 32 + g * 8];
            }
        #pragma unroll
        for (int m = 0; m < 2; m++)
            #pragma unroll
            for (int mf = 0; mf < 2; mf++)
                #pragma unroll
                for (int nf = 0; nf < 2; nf++) {
                    acc[m][mf][nf] = mfma16(af[m][mf], bf[m][nf][0], acc[m][mf][nf]);
                    acc[m][mf][nf] = mfma16(af[m][mf], bf[m][nf][1], acc[m][mf][nf]);
                }
        __syncthreads();
    }

    #pragma unroll
    for (int nf = 0; nf < 2; nf++) {
        const int col = c0 + wn * 32 + nf * 16 + m16;
        const float bv1 = b1[col], bv2 = b2[col];
        #pragma unroll
        for (int mf = 0; mf < 2; mf++) {
            #pragma unroll
            for (int r = 0; r < 4; r++) {
                const int row = r0 + wm * 32 + mf * 16 + g * 4 + r;
                float v1 = acc[0][mf][nf][r] + bv1;
                v1 = v1 > 0.0f ? v1 : 0.01f * v1;
                float v2 = acc[1][mf][nf][r] + bv2;
                v2 = v2 > 0.0f ? v2 : 0.01f * v2;
                C[(size_t)row * 256 + col] = v1 + v2;
            }
        }
    }
}

// ---------------------------------------------------------------------------
__global__ void colsum_k(const float* __restrict__ x, float* __restrict__ out) {
    int d = threadIdx.x, b = blockIdx.x;
    float s = 0.0f;
    int i0 = b * 128;
    for (int i = 0; i < 128; i++) s += x[(size_t)(i0 + i) * 256 + d];
    out[b * 256 + d] = s;
}
__global__ void meanred_k(const float* __restrict__ p, float* __restrict__ mean) {
    int d = threadIdx.x;
    float s = 0.0f;
    for (int b = 0; b < 64; b++) s += p[b * 256 + d];
    mean[d] = s * (1.0f / 8192.0f);
}
// mwv_k: biasX[n] = bx[n] + 0.5 * sum_d mean[d]*W[d][n]; block 0 -> (Wh,bh,biasH),
// block 1 -> (Wt,bt,biasT). Coalesced over n.
__launch_bounds__(256)
__global__ void mwv_k(const float* __restrict__ mean,
                      const float* __restrict__ Wh, const float* __restrict__ bh,
                      const float* __restrict__ Wt, const float* __restrict__ bt,
                      float* __restrict__ biasH, float* __restrict__ biasT) {
    const int n = threadIdx.x;
    const float* W = blockIdx.x ? Wt : Wh;
    const float* bb = blockIdx.x ? bt : bh;
    float* o = blockIdx.x ? biasT : biasH;
    float s = 0.0f;
    for (int d = 0; d < 256; d++) s += mean[d] * W[d * 256 + n];
    o[n] = bb[n] + 0.5f * s;
}
// prep_k: blocks 0..2047: eh -> eh16 (f2bf); blocks 2048..4095: et -> et16 + rowsum.
__launch_bounds__(256)
__global__ void prep_k(const float* __restrict__ eh, const float* __restrict__ et,
                       unsigned short* __restrict__ eh16,
                       unsigned short* __restrict__ et16,
                       float* __restrict__ rowsum) {
    const int b = blockIdx.x;
    if (b < 2048) {
        size_t idx = (size_t)b * 256 + threadIdx.x;
        f32x4 v = *(const f32x4*)&eh[idx * 4];
        short4v h;
        #pragma unroll
        for (int e = 0; e < 4; e++) h[e] = (short)f2bf(v[e]);
        *(short4v*)&eh16[idx * 4] = h;
    } else {
        const int w = threadIdx.x >> 6, l = threadIdx.x & 63;
        const int i = (b - 2048) * 4 + w;
        f32x4 v = *(const f32x4*)&et[(size_t)i * 256 + l * 4];
        short4v h;
        #pragma unroll
        for (int e = 0; e < 4; e++) h[e] = (short)f2bf(v[e]);
        *(short4v*)&et16[(size_t)i * 256 + l * 4] = h;
        float s = v[0] + v[1] + v[2] + v[3];
        #pragma unroll
        for (int st = 1; st < 64; st <<= 1) s += __shfl_xor(s, st);
        if (l == 0) rowsum[i] = s;
    }
}

// ---------------------------------------------------------------------------
// float keys (col in low-11 mantissa bits), med3 insert. Ascending, tk[0]=min.
// ---------------------------------------------------------------------------
__device__ inline float packkey(float v, unsigned col) {
    unsigned u = (__builtin_bit_cast(unsigned, v) & 0xFFFFF800u) | col;
    return __builtin_bit_cast(float, u);
}
template<int NK>
__device__ inline void insf(float (&tk)[NK], float key) {
    #pragma unroll
    for (int k = 0; k < NK - 1; k++)
        tk[k] = __builtin_amdgcn_fmed3f(key, tk[k + 1], tk[k]);
    tk[NK - 1] = fmaxf(tk[NK - 1], key);
}

// ---------------------------------------------------------------------------
// screen2 (proven R18/R19): 512 thr = 8 waves, 128 rows/block, grid (4,64),
// 2-tile groups double-buffered, 1 barrier/group. Wave = rowset x col-half.
// ---------------------------------------------------------------------------
__launch_bounds__(512)
__global__ void screen2(const unsigned short* __restrict__ eh16,
                        const unsigned short* __restrict__ et16,
                        int* __restrict__ candi) {
    __shared__ __align__(16) unsigned short Bs[2][2][8192];
    __shared__ float mbuf[8][2][16][8];
    const int t = threadIdx.x;
    const int cs = blockIdx.x;
    const int r0 = blockIdx.y * 128;
    const int w = t >> 6, lid = t & 63, lg = lid >> 4, m16 = lid & 15;
    const int rs = w >> 1, ch = w & 1;

    short8 bfr[2][8];
    #pragma unroll
    for (int s = 0; s < 2; s++)
        #pragma unroll
        for (int ks = 0; ks < 8; ks++)
            bfr[s][ks] = *(const short8*)
                &eh16[(size_t)(r0 + rs * 32 + s * 16 + m16) * 256 + ks * 32 + lg * 8];

    float tk0[6], tk1[6];
    #pragma unroll
    for (int q = 0; q < 6; q++) { tk0[q] = -3.0e38f; tk1[q] = -3.0e38f; }

    int scol[2], goff[2], ldsl[2];
    #pragma unroll
    for (int c = 0; c < 2; c++) {
        int L = (w * 2 + c) * 64 + lid;
        int col = L >> 5, gs = L & 31;
        int gorig = (gs & 24) | ((gs ^ col) & 7);
        scol[c] = col; goff[c] = gorig * 8; ldsl[c] = L * 8;
    }

    #pragma unroll
    for (int tt = 0; tt < 2; tt++) {
        const int j0 = cs * 2048 + tt * 32;
        #pragma unroll
        for (int c = 0; c < 2; c++)
            gload_lds16(&et16[(size_t)(j0 + scol[c]) * 256 + goff[c]],
                        &Bs[0][tt][ldsl[c]]);
    }
    __syncthreads();

    const int swz = m16 & 7;
    const int cbase = (ch * 16 + m16) * 32;
    for (int gi = 0; gi < 32; gi++) {
        const int cur = gi & 1;
        if (gi + 1 < 32) {
            #pragma unroll
            for (int tt = 0; tt < 2; tt++) {
                const int j1 = cs * 2048 + ((gi + 1) * 2 + tt) * 32;
                #pragma unroll
                for (int c = 0; c < 2; c++)
                    gload_lds16(&et16[(size_t)(j1 + scol[c]) * 256 + goff[c]],
                                &Bs[cur ^ 1][tt][ldsl[c]]);
            }
        }
        #pragma unroll
        for (int tt = 0; tt < 2; tt++) {
            const int tile = gi * 2 + tt;
            const unsigned short* bst = Bs[cur][tt];
            f32x4 a0 = {0.0f, 0.0f, 0.0f, 0.0f}, a1 = a0;
            #pragma unroll
            for (int ks = 0; ks < 8; ks++) {
                const int gq = ks * 4 + lg;
                short8 e = *(const short8*)&bst[(cbase + (gq ^ swz)) * 8];
                a0 = mfma16(e, bfr[0][ks], a0);
                a1 = mfma16(e, bfr[1][ks], a1);
            }
            const unsigned cb = (unsigned)(tile * 32 + ch * 16 + lg * 4);
            #pragma unroll
            for (int r = 0; r < 4; r++) {
                insf<6>(tk0, packkey(a0[r], cb + (unsigned)r));
                insf<6>(tk1, packkey(a1[r], cb + (unsigned)r));
            }
        }
        __syncthreads();
    }

    #pragma unroll
    for (int s = 0; s < 2; s++) {
        float tk8[8];
        tk8[0] = -3.0e38f; tk8[1] = -3.0e38f;
        #pragma unroll
        for (int q = 0; q < 6; q++) tk8[q + 2] = s ? tk1[q] : tk0[q];
        #pragma unroll
        for (int step = 16; step <= 32; step <<= 1) {
            float ok[8];
            #pragma unroll
            for (int q = 0; q < 8; q++) ok[q] = __shfl_xor(tk8[q], step);
            #pragma unroll
            for (int q = 0; q < 8; q++) insf<8>(tk8, ok[q]);
        }
        if (lg == 0) {
            #pragma unroll
            for (int q = 0; q < 8; q++) mbuf[rs * 2 + s][ch][m16][q] = tk8[q];
        }
    }
    __syncthreads();

    if (t < 128) {
        float tk8[8];
        #pragma unroll
        for (int q = 0; q < 8; q++) tk8[q] = mbuf[t >> 4][0][t & 15][q];
        #pragma unroll
        for (int q = 0; q < 8; q++) insf<8>(tk8, mbuf[t >> 4][1][t & 15][q]);
        const int row = r0 + t;
        #pragma unroll
        for (int q = 0; q < 8; q++)
            candi[(size_t)row * 32 + cs * 8 + q] =
                cs * 2048 + (int)(__builtin_bit_cast(unsigned, tk8[q]) & 0x7FFu);
    }
}

// ---------------------------------------------------------------------------
// Stage D (proven R19): LDS-free, barrier-free; 4 waves/block, one row per wave.
// ---------------------------------------------------------------------------
__launch_bounds__(256)
__global__ void stageD(const float* __restrict__ eh, const float* __restrict__ et,
                       const float* __restrict__ rowsum,
                       const int* __restrict__ candi,
                       unsigned short* __restrict__ m1, unsigned short* __restrict__ m2) {
    const int w = threadIdx.x >> 6, l = threadIdx.x & 63;
    const int i = blockIdx.x * 4 + w;
    const int c_own = l & 31;

    const int jown = candi[(size_t)i * 32 + c_own] & 8191;

    const int q = l & 7, g8 = l >> 3;
    const float* er = &eh[(size_t)i * 256];
    double vres[4];
    #pragma unroll
    for (int p = 0; p < 4; p++) {
        const int cc = p * 8 + g8;
        const int jc = __shfl(jown, cc);
        const float* tr = &et[(size_t)jc * 256];
        double a = 0.0;
        #pragma unroll
        for (int tt = 0; tt < 8; tt++) {
            const int o = (tt * 8 + q) * 4;
            f32x4 av = *(const f32x4*)&er[o];
            f32x4 bv = *(const f32x4*)&tr[o];
            a += (double)av[0] * bv[0] + (double)av[1] * bv[1] +
                 (double)av[2] * bv[2] + (double)av[3] * bv[3];
        }
        a += __shfl_xor(a, 1);
        a += __shfl_xor(a, 2);
        a += __shfl_xor(a, 4);
        vres[p] = a * 0.0625;
    }
    const int src = (c_own & 7) * 8;
    double t0 = __shfl(vres[0], src), t1 = __shfl(vres[1], src);
    double t2 = __shfl(vres[2], src), t3 = __shfl(vres[3], src);
    const int ps = c_own >> 3;
    double v = ps == 0 ? t0 : ps == 1 ? t1 : ps == 2 ? t2 : t3;

    unsigned long long kb = __builtin_bit_cast(unsigned long long, v);
    double key = __builtin_bit_cast(double, (kb & ~31ULL) | (unsigned long long)c_own);
    float wf[6]; int selc[6];
    #pragma unroll
    for (int s = 0; s < 6; s++) {
        double b = key;
        #pragma unroll
        for (int st = 1; st < 32; st <<= 1) {
            double ob = __shfl_xor(b, st);
            b = b > ob ? b : ob;
        }
        selc[s] = (int)(__builtin_bit_cast(unsigned long long, b) & 31ULL);
        wf[s] = (float)b;
        if (key == b) key = -1.0e300;
    }
    int selj[6];
    #pragma unroll
    for (int s = 0; s < 6; s++) selj[s] = __shfl(jown, selc[s]);

    float sp[6];
    {
        float mx = wf[0];
        #pragma unroll
        for (int s = 1; s < 6; s++) mx = fmaxf(mx, wf[s]);
        float se = 0.0f, e6[6];
        #pragma unroll
        for (int s = 0; s < 6; s++) { e6[s] = expf(wf[s] - mx); se += e6[s]; }
        #pragma unroll
        for (int s = 0; s < 6; s++) sp[s] = e6[s] / se;
    }

    f32x4 eh4 = *(const f32x4*)&eh[(size_t)i * 256 + l * 4];
    f32x4 nb[6];
    #pragma unroll
    for (int k = 0; k < 6; k++)
        nb[k] = *(const f32x4*)&et[(size_t)selj[k] * 256 + l * 4];

    float pgs[6], pns[6];
    #pragma unroll
    for (int k = 0; k < 6; k++) {
        const float pk = sp[k];
        float pg = 0.0f;
        #pragma unroll
        for (int e = 0; e < 4; e++) {
            float ehd = eh4[e], nbd = nb[k][e];
            float ehr = pk * nbd + (1.0f - pk) * ehd;
            pg += tanhf(ehd + ehr);
        }
        #pragma unroll
        for (int st = 1; st < 64; st <<= 1) pg += __shfl_xor(pg, st);
        pgs[k] = pg;
        pns[k] = rowsum[selj[k]];
    }

    float skp[6];
    {
        float ka[6], mx = -3.0e38f, se = 0.0f;
        #pragma unroll
        for (int k = 0; k < 6; k++) { ka[k] = pns[k] * pgs[k]; mx = fmaxf(mx, ka[k]); }
        #pragma unroll
        for (int k = 0; k < 6; k++) { ka[k] = expf(ka[k] - mx); se += ka[k]; }
        #pragma unroll
        for (int k = 0; k < 6; k++) skp[k] = ka[k] / se;
    }

    f32x4 enh = {0.0f, 0.0f, 0.0f, 0.0f};
    #pragma unroll
    for (int k = 0; k < 6; k++) {
        const float kp = skp[k];
        #pragma unroll
        for (int e = 0; e < 4; e++) enh[e] += kp * nb[k][e];
    }
    short4v h1, h2;
    #pragma unroll
    for (int e = 0; e < 4; e++) {
        h1[e] = (short)f2bf(eh4[e] + enh[e]);
        h2[e] = (short)f2bf(eh4[e] * enh[e]);
    }
    *(short4v*)&m1[(size_t)i * 256 + l * 4] = h1;
    *(short4v*)&m2[(size_t)i * 256 + l * 4] = h2;
}

// ---------------------------------------------------------------------------
__launch_bounds__(256)
__global__ void gate2_k(const float* __restrict__ g1, const float* __restrict__ Ag2,
                        const float* __restrict__ bg2, float* __restrict__ glog) {
    const int i = blockIdx.x * 256 + threadIdx.x;
    float s = 0.0f;
    #pragma unroll 4
    for (int h = 0; h < 128; h++) s += g1[(size_t)i * 128 + h] * Ag2[h];
    glog[i] = s + bg2[0];
}

__launch_bounds__(1024)
__global__ void softmax_g(const float* __restrict__ glog, float* __restrict__ gexp,
                          float* __restrict__ scal) {
    const int t = threadIdx.x;
    __shared__ float red[1024];
    float v[8];
    float m = -3.0e38f;
    #pragma unroll
    for (int c = 0; c < 8; c++) { v[c] = glog[t + c * 1024]; m = fmaxf(m, v[c]); }
    red[t] = m; __syncthreads();
    for (int st = 512; st > 0; st >>= 1) {
        if (t < st) red[t] = fmaxf(red[t], red[t + st]);
        __syncthreads();
    }
    float gm = red[0]; __syncthreads();
    float s = 0.0f;
    #pragma unroll
    for (int c = 0; c < 8; c++) {
        float e = expf(v[c] - gm);
        gexp[t + c * 1024] = e;
        s += e;
    }
    red[t] = s; __syncthreads();
    for (int st = 512; st > 0; st >>= 1) {
        if (t < st) red[t] += red[t + st];
        __syncthreads();
    }
    if (t == 0) scal[0] = 1.0f / red[0];
}

__launch_bounds__(256)
__global__ void wsum_k(const float* __restrict__ emsg, const float* __restrict__ gexp,
                       float* __restrict__ egp) {
    const int b = blockIdx.x, d = threadIdx.x;
    float s = 0.0f;
    const int i0 = b * 128;
    for (int i = 0; i < 128; i++) s += gexp[i0 + i] * emsg[(size_t)(i0 + i) * 256 + d];
    egp[b * 256 + d] = s;
}
__global__ void egfinal_f(const float* __restrict__ egp, const float* __restrict__ scal,
                          float* __restrict__ out) {
    const int d = threadIdx.x;
    float s = 0.0f;
    for (int b = 0; b < 64; b++) s += egp[b * 256 + d];
    out[d] = s * scal[0];
}

__global__ void wsbad_k(float* __restrict__ out) { out[3] = 9000.0f; }

// ---------------------------------------------------------------------------
extern "C" void kernel_launch(void* const* d_in, const int* in_sizes, int n_in,
                              void* d_out, int out_size, void* d_ws, size_t ws_size,
                              hipStream_t stream) {
    (void)in_sizes; (void)n_in; (void)out_size;
    const float* x_path = (const float*)d_in[0];
    const float* fc1_W  = (const float*)d_in[1];
    const float* fc1_b  = (const float*)d_in[2];
    const float* Wh     = (const float*)d_in[3];
    const float* bh     = (const float*)d_in[4];
    const float* Wt     = (const float*)d_in[5];
    const float* bt     = (const float*)d_in[6];
    const float* W1     = (const float*)d_in[7];
    const float* b1     = (const float*)d_in[8];
    const float* W2     = (const float*)d_in[9];
    const float* b2     = (const float*)d_in[10];
    const float* Ag1    = (const float*)d_in[11];
    const float* bg1    = (const float*)d_in[12];
    const float* Ag2    = (const float*)d_in[13];
    const float* bg2    = (const float*)d_in[14];
    float* out_f = (float*)d_out;   // fp32: e_msg [0,2097152), e_g [2097152,2097408)

    const size_t WS_NEEDED = 26412048;
    if (ws_size < WS_NEEDED) {
        hipLaunchKernelGGL(wsbad_k, dim3(1), dim3(1), 0, stream, out_f);
        return;
    }

    char* ws = (char*)d_ws;
    float* x     = (float*)(ws + 0);
    unsigned short* eh16 = (unsigned short*)(ws + 0);
    unsigned short* et16 = (unsigned short*)(ws + 4194304);
    unsigned short* m1b  = (unsigned short*)(ws + 0);
    unsigned short* m2b  = (unsigned short*)(ws + 4194304);
    float* g1    = (float*)(ws + 0);          // 8192x128 fp32 (after m1b/m2b dead)
    float* eh    = (float*)(ws + 8388608);
    float* emsg  = out_f;                     // e_msg written straight to d_out
    float* et    = (float*)(ws + 16777216);
    int*   candi = (int*)  (ws + 25165824);
    float* rowsum= (float*)(ws + 26214400);   // [26214400, 26247168)
    float* meanp = (float*)(ws + 26214400);   // dead after meanred
    float* biasH = (float*)(ws + 26247168);   // 1KB
    float* biasT = (float*)(ws + 26248192);   // 1KB
    float* meanv = (float*)(ws + 26279936);
    float* glog  = (float*)(ws + 26280960);
    float* gexp  = (float*)(ws + 26313728);
    float* egp   = (float*)(ws + 26346496);
    float* scal  = (float*)(ws + 26412032);

    // weight planes in temporarily-dead regions (all stream-ordered safe):
    unsigned short* Fp = (unsigned short*)(ws + 16777216);   // fc1, in et region
    unsigned short* WHp = (unsigned short*)(ws + 25165824);  // in candi region
    unsigned short* WTp = (unsigned short*)(ws + 25559040);
    unsigned short* P1 = (unsigned short*)(ws + 16777216);   // in et region (post-stageD)
    unsigned short* P2 = (unsigned short*)(ws + 17170432);
    unsigned short* Gp = (unsigned short*)(ws + 25165824);   // in candi region (post-stageD)

    dim3 gg(4, 128);
    // 1) x = leaky(x_path @ fc1_W + fc1_b)  [MFMA 3-split]
    hipLaunchKernelGGL(tsplit3, dim3(8, 32), dim3(256), 0, stream,
                       fc1_W, Fp, 1024, 256, 262144);
    hipLaunchKernelGGL((gemmM<1, 1, 0>), gg, dim3(256), 0, stream,
                       (const void*)x_path, Fp, fc1_b, x, 256, 1024, 262144);
    // 2) mean(x) -> folded into eh/et bias (finalize_x deleted)
    hipLaunchKernelGGL(colsum_k, dim3(64), dim3(256), 0, stream, x, meanp);
    hipLaunchKernelGGL(meanred_k, dim3(1), dim3(256), 0, stream, meanp, meanv);
    hipLaunchKernelGGL(tsplit3p, dim3(8, 8, 2), dim3(256), 0, stream,
                       Wh, Wt, WHp, WTp, 256, 256, 65536);
    hipLaunchKernelGGL(mwv_k, dim3(2), dim3(256), 0, stream,
                       meanv, Wh, bh, Wt, bt, biasH, biasT);
    // 3) eh, et = (0.5x)@{Wh,Wt} + bias'  [dual-B shared-A MFMA 3-split]
    hipLaunchKernelGGL(gemmD, gg, dim3(512), 0, stream,
                       x, WHp, WTp, biasH, biasT, eh, et, 65536);
    // 4) bf16 copies + et row sums (fused)
    hipLaunchKernelGGL(prep_k, dim3(4096), dim3(256), 0, stream,
                       eh, et, eh16, et16, rowsum);
    // 5) screening
    hipLaunchKernelGGL(screen2, dim3(4, 64), dim3(512), 0, stream, eh16, et16, candi);
    // 6) fp64 select + message -> m1b/m2b
    hipLaunchKernelGGL(stageD, dim3(2048), dim3(256), 0, stream, eh, et, rowsum,
                       candi, m1b, m2b);
    // 7) e_msg = leaky(m1@W1+b1) + leaky(m2@W2+b2)  [single-pass dual gemm]
    hipLaunchKernelGGL(tsplit3p, dim3(8, 8, 2), dim3(256), 0, stream,
                       W1, W2, P1, P2, 256, 256, 65536);
    hipLaunchKernelGGL(gemmE, gg, dim3(256), 0, stream,
                       m1b, m2b, P1, P2, b1, b2, emsg, 65536);
    // 8) readout
    hipLaunchKernelGGL(tsplit3, dim3(4, 8), dim3(256), 0, stream,
                       Ag1, Gp, 256, 128, 32768);
    hipLaunchKernelGGL((gemmM<1, 1, 0>), dim3(2, 128), dim3(256), 0, stream,
                       (const void*)emsg, Gp, bg1, g1, 128, 256, 32768);
    hipLaunchKernelGGL(gate2_k, dim3(32), dim3(256), 0, stream, g1, Ag2, bg2, glog);
    hipLaunchKernelGGL(softmax_g, dim3(1), dim3(1024), 0, stream, glog, gexp, scal);
    hipLaunchKernelGGL(wsum_k, dim3(64), dim3(256), 0, stream, emsg, gexp, egp);
    hipLaunchKernelGGL(egfinal_f, dim3(1), dim3(256), 0, stream, egp, scal, out_f + 2097152);
}

// Round 13
// 300.471 us; speedup vs baseline: 1.1579x; 1.0383x over previous
//
#include <hip/hip_runtime.h>

// MOTCAT_Surv R23. R22 passed (312.0 us, absmax 0.0156). Tail fusions, all
// aliasing-audited, no proven inner loop touched: (a) eh16 DELETED -- screen2
// reads eh fp32 directly and f2bf-converts its bfr registers in-kernel (bit-
// identical values); prep shrinks to epk (et16+rowsum only, 24->12 MB).
// (Full prep-into-gemmD fusion is an x-region race -- checked, rejected.)
// (b) gemmG: gate2 fused into readout-GEMM epilogue (leaky*Ag2, m16-butterfly,
// atomicAdd glog); g1 8MB round-trip + launch gone; bg2 dropped EXACTLY
// (softmax shift-invariance); glog zeroed in colsum_k. (c) tsplitAll
// (fc1+Wh+Wt) and tsplit3t (W1+W2+Ag1) merge 5 tsplit launches into 2;
// meanred folded into mwv_k. Launches 18 -> 14.

typedef __attribute__((ext_vector_type(8))) short short8;
typedef __attribute__((ext_vector_type(4))) short short4v;
typedef __attribute__((ext_vector_type(4))) float f32x4;

__device__ inline float bf2f(unsigned short b) {
    unsigned u = ((unsigned)b) << 16;
    return __builtin_bit_cast(float, u);
}
__device__ inline unsigned short f2bf(float f) {   // round-to-nearest-even
    unsigned u = __builtin_bit_cast(unsigned, f);
    unsigned r = u + 0x7fffu + ((u >> 16) & 1u);
    return (unsigned short)(r >> 16);
}
__device__ inline f32x4 mfma16(short8 a, short8 b, f32x4 c) {
    return __builtin_amdgcn_mfma_f32_16x16x32_bf16(a, b, c, 0, 0, 0);
}
// A-frag: lane holds A[m=lane&15][k=(lane>>4)*8+j]; B-frag: B[k][n=lane&15];
// C/D: col=lane&15 (n), row=(lane>>4)*4+reg (m) (learn_hip m89).

__device__ inline void gload_lds16(const unsigned short* g, unsigned short* l) {
    __builtin_amdgcn_global_load_lds(
        (const __attribute__((address_space(1))) void*)g,
        (__attribute__((address_space(3))) void*)l, 16, 0, 0);
}

// trunc-split fp32 -> bf16 hi/mid/lo (proven R21): exact residual subtractions.
__device__ inline void split8(const f32x4 v0, const f32x4 v1,
                              short8& hi, short8& md, short8& lo) {
    #pragma unroll
    for (int e = 0; e < 8; e++) {
        float a = (e < 4) ? v0[e] : v1[e - 4];
        unsigned ua = __builtin_bit_cast(unsigned, a);
        float h = __builtin_bit_cast(float, ua & 0xFFFF0000u);
        float r1 = a - h;
        unsigned u1 = __builtin_bit_cast(unsigned, r1);
        float m = __builtin_bit_cast(float, u1 & 0xFFFF0000u);
        float r2 = r1 - m;
        unsigned u2 = __builtin_bit_cast(unsigned, r2);
        hi[e] = (short)(ua >> 16);
        md[e] = (short)(u1 >> 16);
        lo[e] = (short)(u2 >> 16);
    }
}
__device__ inline void split4(f32x4 v, short4v& hi, short4v& md, short4v& lo) {
    #pragma unroll
    for (int e = 0; e < 4; e++) {
        float a = v[e];
        unsigned ua = __builtin_bit_cast(unsigned, a);
        float h = __builtin_bit_cast(float, ua & 0xFFFF0000u);
        float r1 = a - h;
        unsigned u1 = __builtin_bit_cast(unsigned, r1);
        float m = __builtin_bit_cast(float, u1 & 0xFFFF0000u);
        float r2 = r1 - m;
        unsigned u2 = __builtin_bit_cast(unsigned, r2);
        hi[e] = (short)(ua >> 16);
        md[e] = (short)(u1 >> 16);
        lo[e] = (short)(u2 >> 16);
    }
}

// ---------------------------------------------------------------------------
// tsplit bodies: W [K][N] fp32 -> Bt planes [n][k] bf16 (hi,mid,lo) at out+p*PS.
// ---------------------------------------------------------------------------
__device__ inline void tsplit_body(const float* __restrict__ W,
                                   unsigned short* __restrict__ out,
                                   int K, int N, int PS, int bx, int by, int t) {
    __shared__ float T[32][33];
    const int n0 = bx * 32, k0 = by * 32;
    {
        const int r = t >> 3, c = (t & 7) * 4;
        f32x4 v = *(const f32x4*)&W[(size_t)(k0 + r) * N + n0 + c];
        #pragma unroll
        for (int e = 0; e < 4; e++) T[r][c + e] = v[e];
    }
    __syncthreads();
    const int nr = t >> 3, kc = (t & 7) * 4;
    short4v h4, m4, l4;
    #pragma unroll
    for (int e = 0; e < 4; e++) {
        float a = T[kc + e][nr];
        unsigned short h = f2bf(a);
        float r1 = a - bf2f(h);
        unsigned short m = f2bf(r1);
        float r2 = r1 - bf2f(m);
        h4[e] = (short)h; m4[e] = (short)m; l4[e] = (short)f2bf(r2);
    }
    const size_t o = (size_t)(n0 + nr) * K + k0 + kc;
    *(short4v*)&out[o] = h4;
    *(short4v*)&out[(size_t)PS + o] = m4;
    *(short4v*)&out[(size_t)2 * PS + o] = l4;
}
// fc1 (256 blocks) + Wh (64) + Wt (64)
__launch_bounds__(256)
__global__ void tsplitAll(const float* __restrict__ fc1_W, const float* __restrict__ Wh,
                          const float* __restrict__ Wt,
                          unsigned short* __restrict__ Fp,
                          unsigned short* __restrict__ WHp,
                          unsigned short* __restrict__ WTp) {
    const int idx = blockIdx.x, t = threadIdx.x;
    if (idx < 256) tsplit_body(fc1_W, Fp, 1024, 256, 262144, idx & 7, idx >> 3, t);
    else if (idx < 320) { int r = idx - 256; tsplit_body(Wh, WHp, 256, 256, 65536, r & 7, r >> 3, t); }
    else { int r = idx - 320; tsplit_body(Wt, WTp, 256, 256, 65536, r & 7, r >> 3, t); }
}
// W1 (64) + W2 (64) + Ag1 (32)
__launch_bounds__(256)
__global__ void tsplit3t(const float* __restrict__ W1, const float* __restrict__ W2,
                         const float* __restrict__ Ag1,
                         unsigned short* __restrict__ P1,
                         unsigned short* __restrict__ P2,
                         unsigned short* __restrict__ Gp) {
    const int idx = blockIdx.x, t = threadIdx.x;
    if (idx < 64) tsplit_body(W1, P1, 256, 256, 65536, idx & 7, idx >> 3, t);
    else if (idx < 128) { int r = idx - 64; tsplit_body(W2, P2, 256, 256, 65536, r & 7, r >> 3, t); }
    else { int r = idx - 128; tsplit_body(Ag1, Gp, 256, 128, 32768, r & 3, r >> 2, t); }
}

// ---------------------------------------------------------------------------
// gemmM (proven R21): C = act(A@B + bias) on matrix cores. (fc1 only now)
// ---------------------------------------------------------------------------
template <int ASPLIT, int ACT, int ACCUM>
__launch_bounds__(256)
__global__ void gemmM(const void* __restrict__ Av,
                      const unsigned short* __restrict__ Bt,
                      const float* __restrict__ bias, float* __restrict__ C,
                      int N, int K, int BPS) {
    constexpr int APL = ASPLIT ? 3 : 1;
    constexpr int BPL = ASPLIT ? 3 : 2;
    __shared__ __align__(16) unsigned short LA[2][APL * 2048];
    __shared__ __align__(16) unsigned short LB[2][BPL * 2048];
    const int t = threadIdx.x;
    const int r0 = blockIdx.y * 64, c0 = blockIdx.x * 64;
    const int lid = t & 63, w = t >> 6, g = lid >> 4, m16 = lid & 15;
    const int wm = w >> 1, wn = w & 1;

    f32x4 acc[2][2];
    #pragma unroll
    for (int mf = 0; mf < 2; mf++)
        #pragma unroll
        for (int nf = 0; nf < 2; nf++) acc[mf][nf] = {0.0f, 0.0f, 0.0f, 0.0f};

    const int KT = K >> 5;
    const size_t aoff = (size_t)(r0 + (t >> 2)) * K + (t & 3) * 8;
    const size_t boff = (size_t)(c0 + (t >> 2)) * K + (t & 3) * 8;

    {
        #pragma unroll
        for (int p = 0; p < BPL; p++)
            gload_lds16(&Bt[(size_t)p * BPS + boff], &LB[0][p * 2048 + 8 * t]);
        if (ASPLIT) {
            const float* A = (const float*)Av;
            f32x4 v0 = *(const f32x4*)&A[aoff];
            f32x4 v1 = *(const f32x4*)&A[aoff + 4];
            short8 hi, md, lo;
            split8(v0, v1, hi, md, lo);
            *(short8*)&LA[0][8 * t] = hi;
            *(short8*)&LA[0][2048 + 8 * t] = md;
            *(short8*)&LA[0][4096 + 8 * t] = lo;
        } else {
            const unsigned short* A16 = (const unsigned short*)Av;
            gload_lds16(&A16[aoff], &LA[0][8 * t]);
        }
    }
    __syncthreads();

    for (int kt = 0; kt < KT; kt++) {
        const int cur = kt & 1, nxt = cur ^ 1;
        const bool hn = (kt + 1) < KT;
        f32x4 v0, v1;
        if (hn) {
            const size_t ko = (size_t)(kt + 1) * 32;
            #pragma unroll
            for (int p = 0; p < BPL; p++)
                gload_lds16(&Bt[(size_t)p * BPS + boff + ko],
                            &LB[nxt][p * 2048 + 8 * t]);
            if (ASPLIT) {
                const float* A = (const float*)Av;
                v0 = *(const f32x4*)&A[aoff + ko];
                v1 = *(const f32x4*)&A[aoff + ko + 4];
            } else {
                const unsigned short* A16 = (const unsigned short*)Av;
                gload_lds16(&A16[aoff + ko], &LA[nxt][8 * t]);
            }
        }
        short8 af[2][APL], bf[2][BPL];
        #pragma unroll
        for (int mf = 0; mf < 2; mf++) {
            const int row = wm * 32 + mf * 16 + m16;
            #pragma unroll
            for (int p = 0; p < APL; p++)
                af[mf][p] = *(const short8*)&LA[cur][p * 2048 + row * 32 + g * 8];
        }
        #pragma unroll
        for (int nf = 0; nf < 2; nf++) {
            const int col = wn * 32 + nf * 16 + m16;
            #pragma unroll
            for (int p = 0; p < BPL; p++)
                bf[nf][p] = *(const short8*)&LB[cur][p * 2048 + col * 32 + g * 8];
        }
        #pragma unroll
        for (int mf = 0; mf < 2; mf++)
            #pragma unroll
            for (int nf = 0; nf < 2; nf++) {
                if (ASPLIT) {
                    acc[mf][nf] = mfma16(af[mf][0], bf[nf][0], acc[mf][nf]); // hh
                    acc[mf][nf] = mfma16(af[mf][0], bf[nf][1], acc[mf][nf]); // hm
                    acc[mf][nf] = mfma16(af[mf][1], bf[nf][0], acc[mf][nf]); // mh
                    acc[mf][nf] = mfma16(af[mf][0], bf[nf][2], acc[mf][nf]); // hl
                    acc[mf][nf] = mfma16(af[mf][1], bf[nf][1], acc[mf][nf]); // mm
                    acc[mf][nf] = mfma16(af[mf][2], bf[nf][0], acc[mf][nf]); // lh
                } else {
                    acc[mf][nf] = mfma16(af[mf][0], bf[nf][0], acc[mf][nf]);
                    acc[mf][nf] = mfma16(af[mf][0], bf[nf][1], acc[mf][nf]);
                }
            }
        if (hn && ASPLIT) {
            short8 hi, md, lo;
            split8(v0, v1, hi, md, lo);
            *(short8*)&LA[nxt][8 * t] = hi;
            *(short8*)&LA[nxt][2048 + 8 * t] = md;
            *(short8*)&LA[nxt][4096 + 8 * t] = lo;
        }
        __syncthreads();
    }

    #pragma unroll
    for (int nf = 0; nf < 2; nf++) {
        const int col = c0 + wn * 32 + nf * 16 + m16;
        const float bv = bias[col];
        #pragma unroll
        for (int mf = 0; mf < 2; mf++) {
            #pragma unroll
            for (int r = 0; r < 4; r++) {
                const int row = r0 + wm * 32 + mf * 16 + g * 4 + r;
                float v = acc[mf][nf][r] + bv;
                if (ACT == 1) v = v > 0.0f ? v : 0.01f * v;
                size_t idx = (size_t)row * N + col;
                if (ACCUM) v += C[idx];
                C[idx] = v;
            }
        }
    }
}

// ---------------------------------------------------------------------------
// gemmD (proven R22): dual-B shared-A. eh = (0.5x)@Wh + biasH; et = ... + biasT.
// ---------------------------------------------------------------------------
__launch_bounds__(512)
__global__ void gemmD(const float* __restrict__ A,
                      const unsigned short* __restrict__ BH,
                      const unsigned short* __restrict__ BT,
                      const float* __restrict__ biasH, const float* __restrict__ biasT,
                      float* __restrict__ CH, float* __restrict__ CT, int BPS) {
    __shared__ __align__(16) unsigned short LA[2][3 * 2048];
    __shared__ __align__(16) unsigned short LB[2][6 * 2048];
    const int t = threadIdx.x;
    const int r0 = blockIdx.y * 64, c0 = blockIdx.x * 64;
    const int lid = t & 63, w = t >> 6, g = lid >> 4, m16 = lid & 15;
    const int mat = w >> 2, wsub = w & 3, wm = wsub >> 1, wn = wsub & 1;
    const int K = 256;

    f32x4 acc[2][2];
    #pragma unroll
    for (int mf = 0; mf < 2; mf++)
        #pragma unroll
        for (int nf = 0; nf < 2; nf++) acc[mf][nf] = {0.0f, 0.0f, 0.0f, 0.0f};

    const int arow = t >> 3, akq = (t & 7) * 4;
    const size_t aoff = (size_t)(r0 + arow) * K + akq;
    const int aldst = arow * 32 + akq;
    int bdst[3];
    size_t bsrc[3];
    #pragma unroll
    for (int s = 0; s < 3; s++) {
        int L = t + s * 512;
        int mp = L >> 8;
        bdst[s] = mp * 2048 + (L & 255) * 8;
        int mm = mp >= 3, pl = mp - 3 * mm;
        const unsigned short* base = mm ? BT : BH;
        bsrc[s] = (size_t)(base - BH) + (size_t)pl * BPS +
                  (size_t)(c0 + ((L >> 2) & 63)) * K + (L & 3) * 8;
    }

    {
        #pragma unroll
        for (int s = 0; s < 3; s++)
            gload_lds16(&BH[bsrc[s]], &LB[0][bdst[s]]);
        f32x4 v = *(const f32x4*)&A[aoff];
        #pragma unroll
        for (int e = 0; e < 4; e++) v[e] *= 0.5f;
        short4v hi, md, lo;
        split4(v, hi, md, lo);
        *(short4v*)&LA[0][aldst] = hi;
        *(short4v*)&LA[0][2048 + aldst] = md;
        *(short4v*)&LA[0][4096 + aldst] = lo;
    }
    __syncthreads();

    for (int kt = 0; kt < 8; kt++) {
        const int cur = kt & 1, nxt = cur ^ 1;
        const bool hn = (kt + 1) < 8;
        f32x4 v;
        if (hn) {
            const size_t ko = (size_t)(kt + 1) * 32;
            #pragma unroll
            for (int s = 0; s < 3; s++)
                gload_lds16(&BH[bsrc[s] + ko], &LB[nxt][bdst[s]]);
            v = *(const f32x4*)&A[aoff + ko];
            #pragma unroll
            for (int e = 0; e < 4; e++) v[e] *= 0.5f;
        }
        short8 af[2][3], bf[2][3];
        #pragma unroll
        for (int mf = 0; mf < 2; mf++) {
            const int row = wm * 32 + mf * 16 + m16;
            #pragma unroll
            for (int p = 0; p < 3; p++)
                af[mf][p] = *(const short8*)&LA[cur][p * 2048 + row * 32 + g * 8];
        }
        #pragma unroll
        for (int nf = 0; nf < 2; nf++) {
            const int col = wn * 32 + nf * 16 + m16;
            #pragma unroll
            for (int p = 0; p < 3; p++)
                bf[nf][p] = *(const short8*)
                    &LB[cur][(mat * 3 + p) * 2048 + col * 32 + g * 8];
        }
        #pragma unroll
        for (int mf = 0; mf < 2; mf++)
            #pragma unroll
            for (int nf = 0; nf < 2; nf++) {
                acc[mf][nf] = mfma16(af[mf][0], bf[nf][0], acc[mf][nf]); // hh
                acc[mf][nf] = mfma16(af[mf][0], bf[nf][1], acc[mf][nf]); // hm
                acc[mf][nf] = mfma16(af[mf][1], bf[nf][0], acc[mf][nf]); // mh
                acc[mf][nf] = mfma16(af[mf][0], bf[nf][2], acc[mf][nf]); // hl
                acc[mf][nf] = mfma16(af[mf][1], bf[nf][1], acc[mf][nf]); // mm
                acc[mf][nf] = mfma16(af[mf][2], bf[nf][0], acc[mf][nf]); // lh
            }
        if (hn) {
            short4v hi, md, lo;
            split4(v, hi, md, lo);
            *(short4v*)&LA[nxt][aldst] = hi;
            *(short4v*)&LA[nxt][2048 + aldst] = md;
            *(short4v*)&LA[nxt][4096 + aldst] = lo;
        }
        __syncthreads();
    }

    float* C = mat ? CT : CH;
    const float* bias = mat ? biasT : biasH;
    #pragma unroll
    for (int nf = 0; nf < 2; nf++) {
        const int col = c0 + wn * 32 + nf * 16 + m16;
        const float bv = bias[col];
        #pragma unroll
        for (int mf = 0; mf < 2; mf++) {
            #pragma unroll
            for (int r = 0; r < 4; r++) {
                const int row = r0 + wm * 32 + mf * 16 + g * 4 + r;
                C[(size_t)row * 256 + col] = acc[mf][nf][r] + bv;
            }
        }
    }
}

// ---------------------------------------------------------------------------
// gemmE (proven R22): emsg = leaky(m1@W1+b1) + leaky(m2@W2+b2), single pass.
// ---------------------------------------------------------------------------
__launch_bounds__(256)
__global__ void gemmE(const unsigned short* __restrict__ A1,
                      const unsigned short* __restrict__ A2,
                      const unsigned short* __restrict__ P1,
                      const unsigned short* __restrict__ P2,
                      const float* __restrict__ b1, const float* __restrict__ b2,
                      float* __restrict__ C, int BPS) {
    __shared__ __align__(16) unsigned short LA[2][2 * 2048];
    __shared__ __align__(16) unsigned short LB[2][4 * 2048];
    const int t = threadIdx.x;
    const int r0 = blockIdx.y * 64, c0 = blockIdx.x * 64;
    const int lid = t & 63, w = t >> 6, g = lid >> 4, m16 = lid & 15;
    const int wm = w >> 1, wn = w & 1;
    const int K = 256;

    f32x4 acc[2][2][2];
    #pragma unroll
    for (int m = 0; m < 2; m++)
        #pragma unroll
        for (int mf = 0; mf < 2; mf++)
            #pragma unroll
            for (int nf = 0; nf < 2; nf++) acc[m][mf][nf] = {0.0f, 0.0f, 0.0f, 0.0f};

    const size_t aoff = (size_t)(r0 + (t >> 2)) * K + (t & 3) * 8;
    const size_t boff = (size_t)(c0 + (t >> 2)) * K + (t & 3) * 8;

    {
        gload_lds16(&A1[aoff], &LA[0][8 * t]);
        gload_lds16(&A2[aoff], &LA[0][2048 + 8 * t]);
        gload_lds16(&P1[boff], &LB[0][8 * t]);
        gload_lds16(&P1[(size_t)BPS + boff], &LB[0][2048 + 8 * t]);
        gload_lds16(&P2[boff], &LB[0][4096 + 8 * t]);
        gload_lds16(&P2[(size_t)BPS + boff], &LB[0][6144 + 8 * t]);
    }
    __syncthreads();

    for (int kt = 0; kt < 8; kt++) {
        const int cur = kt & 1, nxt = cur ^ 1;
        const bool hn = (kt + 1) < 8;
        if (hn) {
            const size_t ko = (size_t)(kt + 1) * 32;
            gload_lds16(&A1[aoff + ko], &LA[nxt][8 * t]);
            gload_lds16(&A2[aoff + ko], &LA[nxt][2048 + 8 * t]);
            gload_lds16(&P1[boff + ko], &LB[nxt][8 * t]);
            gload_lds16(&P1[(size_t)BPS + boff + ko], &LB[nxt][2048 + 8 * t]);
            gload_lds16(&P2[boff + ko], &LB[nxt][4096 + 8 * t]);
            gload_lds16(&P2[(size_t)BPS + boff + ko], &LB[nxt][6144 + 8 * t]);
        }
        short8 af[2][2], bf[2][2][2];
        #pragma unroll
        for (int m = 0; m < 2; m++)
            #pragma unroll
            for (int mf = 0; mf < 2; mf++) {
                const int row = wm * 32 + mf * 16 + m16;
                af[m][mf] = *(const short8*)&LA[cur][m * 2048 + row * 32 + g * 8];
            }
        #pragma unroll
        for (int m = 0; m < 2; m++)
            #pragma unroll
            for (int nf = 0; nf < 2; nf++) {
                const int col = wn * 32 + nf * 16 + m16;
                #pragma unroll
                for (int p = 0; p < 2; p++)
                    bf[m][nf][p] = *(const short8*)
                        &LB[cur][(m * 2 + p) * 2048 + col * 32 + g * 8];
            }
        #pragma unroll
        for (int m = 0; m < 2; m++)
            #pragma unroll
            for (int mf = 0; mf < 2; mf++)
                #pragma unroll
                for (int nf = 0; nf < 2; nf++) {
                    acc[m][mf][nf] = mfma16(af[m][mf], bf[m][nf][0], acc[m][mf][nf]);
                    acc[m][mf][nf] = mfma16(af[m][mf], bf[m][nf][1], acc[m][mf][nf]);
                }
        __syncthreads();
    }

    #pragma unroll
    for (int nf = 0; nf < 2; nf++) {
        const int col = c0 + wn * 32 + nf * 16 + m16;
        const float bv1 = b1[col], bv2 = b2[col];
        #pragma unroll
        for (int mf = 0; mf < 2; mf++) {
            #pragma unroll
            for (int r = 0; r < 4; r++) {
                const int row = r0 + wm * 32 + mf * 16 + g * 4 + r;
                float v1 = acc[0][mf][nf][r] + bv1;
                v1 = v1 > 0.0f ? v1 : 0.01f * v1;
                float v2 = acc[1][mf][nf][r] + bv2;
                v2 = v2 > 0.0f ? v2 : 0.01f * v2;
                C[(size_t)row * 256 + col] = v1 + v2;
            }
        }
    }
}

// ---------------------------------------------------------------------------
// gemmG: readout GEMM with fused gate: glog[row] += leaky((emsg@Ag1)[row][col]
// + bg1[col]) * Ag2[col], summed over cols (m16-butterfly + atomicAdd).
// Core loop = gemmM ASPLIT=1. N=128, K=256, grid (2,128). bg2 dropped (softmax
// shift-invariant -- exact).
// ---------------------------------------------------------------------------
__launch_bounds__(256)
__global__ void gemmG(const float* __restrict__ A,
                      const unsigned short* __restrict__ Bt,
                      const float* __restrict__ bias,
                      const float* __restrict__ Ag2, float* __restrict__ glog,
                      int BPS) {
    __shared__ __align__(16) unsigned short LA[2][3 * 2048];
    __shared__ __align__(16) unsigned short LB[2][3 * 2048];
    const int t = threadIdx.x;
    const int r0 = blockIdx.y * 64, c0 = blockIdx.x * 64;
    const int lid = t & 63, w = t >> 6, g = lid >> 4, m16 = lid & 15;
    const int wm = w >> 1, wn = w & 1;
    const int K = 256;

    f32x4 acc[2][2];
    #pragma unroll
    for (int mf = 0; mf < 2; mf++)
        #pragma unroll
        for (int nf = 0; nf < 2; nf++) acc[mf][nf] = {0.0f, 0.0f, 0.0f, 0.0f};

    const size_t aoff = (size_t)(r0 + (t >> 2)) * K + (t & 3) * 8;
    const size_t boff = (size_t)(c0 + (t >> 2)) * K + (t & 3) * 8;

    {
        #pragma unroll
        for (int p = 0; p < 3; p++)
            gload_lds16(&Bt[(size_t)p * BPS + boff], &LB[0][p * 2048 + 8 * t]);
        f32x4 v0 = *(const f32x4*)&A[aoff];
        f32x4 v1 = *(const f32x4*)&A[aoff + 4];
        short8 hi, md, lo;
        split8(v0, v1, hi, md, lo);
        *(short8*)&LA[0][8 * t] = hi;
        *(short8*)&LA[0][2048 + 8 * t] = md;
        *(short8*)&LA[0][4096 + 8 * t] = lo;
    }
    __syncthreads();

    for (int kt = 0; kt < 8; kt++) {
        const int cur = kt & 1, nxt = cur ^ 1;
        const bool hn = (kt + 1) < 8;
        f32x4 v0, v1;
        if (hn) {
            const size_t ko = (size_t)(kt + 1) * 32;
            #pragma unroll
            for (int p = 0; p < 3; p++)
                gload_lds16(&Bt[(size_t)p * BPS + boff + ko],
                            &LB[nxt][p * 2048 + 8 * t]);
            v0 = *(const f32x4*)&A[aoff + ko];
            v1 = *(const f32x4*)&A[aoff + ko + 4];
        }
        short8 af[2][3], bf[2][3];
        #pragma unroll
        for (int mf = 0; mf < 2; mf++) {
            const int row = wm * 32 + mf * 16 + m16;
            #pragma unroll
            for (int p = 0; p < 3; p++)
                af[mf][p] = *(const short8*)&LA[cur][p * 2048 + row * 32 + g * 8];
        }
        #pragma unroll
        for (int nf = 0; nf < 2; nf++) {
            const int col = wn * 32 + nf * 16 + m16;
            #pragma unroll
            for (int p = 0; p < 3; p++)
                bf[nf][p] = *(const short8*)&LB[cur][p * 2048 + col * 32 + g * 8];
        }
        #pragma unroll
        for (int mf = 0; mf < 2; mf++)
            #pragma unroll
            for (int nf = 0; nf < 2; nf++) {
                acc[mf][nf] = mfma16(af[mf][0], bf[nf][0], acc[mf][nf]);
                acc[mf][nf] = mfma16(af[mf][0], bf[nf][1], acc[mf][nf]);
                acc[mf][nf] = mfma16(af[mf][1], bf[nf][0], acc[mf][nf]);
                acc[mf][nf] = mfma16(af[mf][0], bf[nf][2], acc[mf][nf]);
                acc[mf][nf] = mfma16(af[mf][1], bf[nf][1], acc[mf][nf]);
                acc[mf][nf] = mfma16(af[mf][2], bf[nf][0], acc[mf][nf]);
            }
        if (hn) {
            short8 hi, md, lo;
            split8(v0, v1, hi, md, lo);
            *(short8*)&LA[nxt][8 * t] = hi;
            *(short8*)&LA[nxt][2048 + 8 * t] = md;
            *(short8*)&LA[nxt][4096 + 8 * t] = lo;
        }
        __syncthreads();
    }

    // fused gate epilogue
    float pp[2][4];
    #pragma unroll
    for (int mf = 0; mf < 2; mf++)
        #pragma unroll
        for (int r = 0; r < 4; r++) pp[mf][r] = 0.0f;
    #pragma unroll
    for (int nf = 0; nf < 2; nf++) {
        const int col = c0 + wn * 32 + nf * 16 + m16;
        const float bv = bias[col], a2 = Ag2[col];
        #pragma unroll
        for (int mf = 0; mf < 2; mf++) {
            #pragma unroll
            for (int r = 0; r < 4; r++) {
                float v = acc[mf][nf][r] + bv;
                v = v > 0.0f ? v : 0.01f * v;
                pp[mf][r] += v * a2;
            }
        }
    }
    #pragma unroll
    for (int st = 1; st < 16; st <<= 1)
        #pragma unroll
        for (int mf = 0; mf < 2; mf++)
            #pragma unroll
            for (int r = 0; r < 4; r++) pp[mf][r] += __shfl_xor(pp[mf][r], st);
    if (m16 == 0) {
        #pragma unroll
        for (int mf = 0; mf < 2; mf++)
            #pragma unroll
            for (int r = 0; r < 4; r++)
                atomicAdd(&glog[r0 + wm * 32 + mf * 16 + g * 4 + r], pp[mf][r]);
    }
}

// ---------------------------------------------------------------------------
__global__ void colsum_k(const float* __restrict__ x, float* __restrict__ out,
                         float* __restrict__ glog) {
    int d = threadIdx.x, b = blockIdx.x;
    float s = 0.0f;
    int i0 = b * 128;
    for (int i = 0; i < 128; i++) s += x[(size_t)(i0 + i) * 256 + d];
    out[b * 256 + d] = s;
    int tid = b * 256 + d;
    if (tid < 8192) glog[tid] = 0.0f;
}
// mwv_k: mean reduce (folded) + biasX[n] = bx[n] + 0.5*sum_d mean[d]*W[d][n].
__launch_bounds__(256)
__global__ void mwv_k(const float* __restrict__ meanp,
                      const float* __restrict__ Wh, const float* __restrict__ bh,
                      const float* __restrict__ Wt, const float* __restrict__ bt,
                      float* __restrict__ biasH, float* __restrict__ biasT) {
    __shared__ float mean[256];
    const int n = threadIdx.x;
    {
        float s = 0.0f;
        for (int b = 0; b < 64; b++) s += meanp[b * 256 + n];
        mean[n] = s * (1.0f / 8192.0f);
    }
    __syncthreads();
    const float* W = blockIdx.x ? Wt : Wh;
    const float* bb = blockIdx.x ? bt : bh;
    float* o = blockIdx.x ? biasT : biasH;
    float s = 0.0f;
    for (int d = 0; d < 256; d++) s += mean[d] * W[d * 256 + n];
    o[n] = bb[n] + 0.5f * s;
}
// epk: et -> et16 (f2bf) + rowsum. grid 2048 x 256.
__launch_bounds__(256)
__global__ void epk(const float* __restrict__ et, unsigned short* __restrict__ et16,
                    float* __restrict__ rowsum) {
    const int w = threadIdx.x >> 6, l = threadIdx.x & 63;
    const int i = blockIdx.x * 4 + w;
    f32x4 v = *(const f32x4*)&et[(size_t)i * 256 + l * 4];
    short4v h;
    #pragma unroll
    for (int e = 0; e < 4; e++) h[e] = (short)f2bf(v[e]);
    *(short4v*)&et16[(size_t)i * 256 + l * 4] = h;
    float s = v[0] + v[1] + v[2] + v[3];
    #pragma unroll
    for (int st = 1; st < 64; st <<= 1) s += __shfl_xor(s, st);
    if (l == 0) rowsum[i] = s;
}

// ---------------------------------------------------------------------------
// float keys (col in low-11 mantissa bits), med3 insert. Ascending, tk[0]=min.
// ---------------------------------------------------------------------------
__device__ inline float packkey(float v, unsigned col) {
    unsigned u = (__builtin_bit_cast(unsigned, v) & 0xFFFFF800u) | col;
    return __builtin_bit_cast(float, u);
}
template<int NK>
__device__ inline void insf(float (&tk)[NK], float key) {
    #pragma unroll
    for (int k = 0; k < NK - 1; k++)
        tk[k] = __builtin_amdgcn_fmed3f(key, tk[k + 1], tk[k]);
    tk[NK - 1] = fmaxf(tk[NK - 1], key);
}

// ---------------------------------------------------------------------------
// screen2 (proven R18/R19 loop; bfr init now converts from eh fp32 -- values
// bit-identical to the old prep-produced eh16): 512 thr, 128 rows/block,
// grid (4,64), 2-tile groups double-buffered, 1 barrier/group.
// ---------------------------------------------------------------------------
__launch_bounds__(512)
__global__ void screen2(const float* __restrict__ eh,
                        const unsigned short* __restrict__ et16,
                        int* __restrict__ candi) {
    __shared__ __align__(16) unsigned short Bs[2][2][8192];
    __shared__ float mbuf[8][2][16][8];
    const int t = threadIdx.x;
    const int cs = blockIdx.x;
    const int r0 = blockIdx.y * 128;
    const int w = t >> 6, lid = t & 63, lg = lid >> 4, m16 = lid & 15;
    const int rs = w >> 1, ch = w & 1;

    short8 bfr[2][8];
    #pragma unroll
    for (int s = 0; s < 2; s++)
        #pragma unroll
        for (int ks = 0; ks < 8; ks++) {
            const float* p = &eh[(size_t)(r0 + rs * 32 + s * 16 + m16) * 256
                                 + ks * 32 + lg * 8];
            f32x4 a = *(const f32x4*)p;
            f32x4 b = *(const f32x4*)(p + 4);
            short8 hh;
            #pragma unroll
            for (int e = 0; e < 4; e++) {
                hh[e] = (short)f2bf(a[e]);
                hh[4 + e] = (short)f2bf(b[e]);
            }
            bfr[s][ks] = hh;
        }

    float tk0[6], tk1[6];
    #pragma unroll
    for (int q = 0; q < 6; q++) { tk0[q] = -3.0e38f; tk1[q] = -3.0e38f; }

    int scol[2], goff[2], ldsl[2];
    #pragma unroll
    for (int c = 0; c < 2; c++) {
        int L = (w * 2 + c) * 64 + lid;
        int col = L >> 5, gs = L & 31;
        int gorig = (gs & 24) | ((gs ^ col) & 7);
        scol[c] = col; goff[c] = gorig * 8; ldsl[c] = L * 8;
    }

    #pragma unroll
    for (int tt = 0; tt < 2; tt++) {
        const int j0 = cs * 2048 + tt * 32;
        #pragma unroll
        for (int c = 0; c < 2; c++)
            gload_lds16(&et16[(size_t)(j0 + scol[c]) * 256 + goff[c]],
                        &Bs[0][tt][ldsl[c]]);
    }
    __syncthreads();

    const int swz = m16 & 7;
    const int cbase = (ch * 16 + m16) * 32;
    for (int gi = 0; gi < 32; gi++) {
        const int cur = gi & 1;
        if (gi + 1 < 32) {
            #pragma unroll
            for (int tt = 0; tt < 2; tt++) {
                const int j1 = cs * 2048 + ((gi + 1) * 2 + tt) * 32;
                #pragma unroll
                for (int c = 0; c < 2; c++)
                    gload_lds16(&et16[(size_t)(j1 + scol[c]) * 256 + goff[c]],
                                &Bs[cur ^ 1][tt][ldsl[c]]);
            }
        }
        #pragma unroll
        for (int tt = 0; tt < 2; tt++) {
            const int tile = gi * 2 + tt;
            const unsigned short* bst = Bs[cur][tt];
            f32x4 a0 = {0.0f, 0.0f, 0.0f, 0.0f}, a1 = a0;
            #pragma unroll
            for (int ks = 0; ks < 8; ks++) {
                const int gq = ks * 4 + lg;
                short8 e = *(const short8*)&bst[(cbase + (gq ^ swz)) * 8];
                a0 = mfma16(e, bfr[0][ks], a0);
                a1 = mfma16(e, bfr[1][ks], a1);
            }
            const unsigned cb = (unsigned)(tile * 32 + ch * 16 + lg * 4);
            #pragma unroll
            for (int r = 0; r < 4; r++) {
                insf<6>(tk0, packkey(a0[r], cb + (unsigned)r));
                insf<6>(tk1, packkey(a1[r], cb + (unsigned)r));
            }
        }
        __syncthreads();
    }

    #pragma unroll
    for (int s = 0; s < 2; s++) {
        float tk8[8];
        tk8[0] = -3.0e38f; tk8[1] = -3.0e38f;
        #pragma unroll
        for (int q = 0; q < 6; q++) tk8[q + 2] = s ? tk1[q] : tk0[q];
        #pragma unroll
        for (int step = 16; step <= 32; step <<= 1) {
            float ok[8];
            #pragma unroll
            for (int q = 0; q < 8; q++) ok[q] = __shfl_xor(tk8[q], step);
            #pragma unroll
            for (int q = 0; q < 8; q++) insf<8>(tk8, ok[q]);
        }
        if (lg == 0) {
            #pragma unroll
            for (int q = 0; q < 8; q++) mbuf[rs * 2 + s][ch][m16][q] = tk8[q];
        }
    }
    __syncthreads();

    if (t < 128) {
        float tk8[8];
        #pragma unroll
        for (int q = 0; q < 8; q++) tk8[q] = mbuf[t >> 4][0][t & 15][q];
        #pragma unroll
        for (int q = 0; q < 8; q++) insf<8>(tk8, mbuf[t >> 4][1][t & 15][q]);
        const int row = r0 + t;
        #pragma unroll
        for (int q = 0; q < 8; q++)
            candi[(size_t)row * 32 + cs * 8 + q] =
                cs * 2048 + (int)(__builtin_bit_cast(unsigned, tk8[q]) & 0x7FFu);
    }
}

// ---------------------------------------------------------------------------
// Stage D (proven R19): LDS-free, barrier-free; 4 waves/block, one row per wave.
// ---------------------------------------------------------------------------
__launch_bounds__(256)
__global__ void stageD(const float* __restrict__ eh, const float* __restrict__ et,
                       const float* __restrict__ rowsum,
                       const int* __restrict__ candi,
                       unsigned short* __restrict__ m1, unsigned short* __restrict__ m2) {
    const int w = threadIdx.x >> 6, l = threadIdx.x & 63;
    const int i = blockIdx.x * 4 + w;
    const int c_own = l & 31;

    const int jown = candi[(size_t)i * 32 + c_own] & 8191;

    const int q = l & 7, g8 = l >> 3;
    const float* er = &eh[(size_t)i * 256];
    double vres[4];
    #pragma unroll
    for (int p = 0; p < 4; p++) {
        const int cc = p * 8 + g8;
        const int jc = __shfl(jown, cc);
        const float* tr = &et[(size_t)jc * 256];
        double a = 0.0;
        #pragma unroll
        for (int tt = 0; tt < 8; tt++) {
            const int o = (tt * 8 + q) * 4;
            f32x4 av = *(const f32x4*)&er[o];
            f32x4 bv = *(const f32x4*)&tr[o];
            a += (double)av[0] * bv[0] + (double)av[1] * bv[1] +
                 (double)av[2] * bv[2] + (double)av[3] * bv[3];
        }
        a += __shfl_xor(a, 1);
        a += __shfl_xor(a, 2);
        a += __shfl_xor(a, 4);
        vres[p] = a * 0.0625;
    }
    const int src = (c_own & 7) * 8;
    double t0 = __shfl(vres[0], src), t1 = __shfl(vres[1], src);
    double t2 = __shfl(vres[2], src), t3 = __shfl(vres[3], src);
    const int ps = c_own >> 3;
    double v = ps == 0 ? t0 : ps == 1 ? t1 : ps == 2 ? t2 : t3;

    unsigned long long kb = __builtin_bit_cast(unsigned long long, v);
    double key = __builtin_bit_cast(double, (kb & ~31ULL) | (unsigned long long)c_own);
    float wf[6]; int selc[6];
    #pragma unroll
    for (int s = 0; s < 6; s++) {
        double b = key;
        #pragma unroll
        for (int st = 1; st < 32; st <<= 1) {
            double ob = __shfl_xor(b, st);
            b = b > ob ? b : ob;
        }
        selc[s] = (int)(__builtin_bit_cast(unsigned long long, b) & 31ULL);
        wf[s] = (float)b;
        if (key == b) key = -1.0e300;
    }
    int selj[6];
    #pragma unroll
    for (int s = 0; s < 6; s++) selj[s] = __shfl(jown, selc[s]);

    float sp[6];
    {
        float mx = wf[0];
        #pragma unroll
        for (int s = 1; s < 6; s++) mx = fmaxf(mx, wf[s]);
        float se = 0.0f, e6[6];
        #pragma unroll
        for (int s = 0; s < 6; s++) { e6[s] = expf(wf[s] - mx); se += e6[s]; }
        #pragma unroll
        for (int s = 0; s < 6; s++) sp[s] = e6[s] / se;
    }

    f32x4 eh4 = *(const f32x4*)&eh[(size_t)i * 256 + l * 4];
    f32x4 nb[6];
    #pragma unroll
    for (int k = 0; k < 6; k++)
        nb[k] = *(const f32x4*)&et[(size_t)selj[k] * 256 + l * 4];

    float pgs[6], pns[6];
    #pragma unroll
    for (int k = 0; k < 6; k++) {
        const float pk = sp[k];
        float pg = 0.0f;
        #pragma unroll
        for (int e = 0; e < 4; e++) {
            float ehd = eh4[e], nbd = nb[k][e];
            float ehr = pk * nbd + (1.0f - pk) * ehd;
            pg += tanhf(ehd + ehr);
        }
        #pragma unroll
        for (int st = 1; st < 64; st <<= 1) pg += __shfl_xor(pg, st);
        pgs[k] = pg;
        pns[k] = rowsum[selj[k]];
    }

    float skp[6];
    {
        float ka[6], mx = -3.0e38f, se = 0.0f;
        #pragma unroll
        for (int k = 0; k < 6; k++) { ka[k] = pns[k] * pgs[k]; mx = fmaxf(mx, ka[k]); }
        #pragma unroll
        for (int k = 0; k < 6; k++) { ka[k] = expf(ka[k] - mx); se += ka[k]; }
        #pragma unroll
        for (int k = 0; k < 6; k++) skp[k] = ka[k] / se;
    }

    f32x4 enh = {0.0f, 0.0f, 0.0f, 0.0f};
    #pragma unroll
    for (int k = 0; k < 6; k++) {
        const float kp = skp[k];
        #pragma unroll
        for (int e = 0; e < 4; e++) enh[e] += kp * nb[k][e];
    }
    short4v h1, h2;
    #pragma unroll
    for (int e = 0; e < 4; e++) {
        h1[e] = (short)f2bf(eh4[e] + enh[e]);
        h2[e] = (short)f2bf(eh4[e] * enh[e]);
    }
    *(short4v*)&m1[(size_t)i * 256 + l * 4] = h1;
    *(short4v*)&m2[(size_t)i * 256 + l * 4] = h2;
}

// ---------------------------------------------------------------------------
__launch_bounds__(1024)
__global__ void softmax_g(const float* __restrict__ glog, float* __restrict__ gexp,
                          float* __restrict__ scal) {
    const int t = threadIdx.x;
    __shared__ float red[1024];
    float v[8];
    float m = -3.0e38f;
    #pragma unroll
    for (int c = 0; c < 8; c++) { v[c] = glog[t + c * 1024]; m = fmaxf(m, v[c]); }
    red[t] = m; __syncthreads();
    for (int st = 512; st > 0; st >>= 1) {
        if (t < st) red[t] = fmaxf(red[t], red[t + st]);
        __syncthreads();
    }
    float gm = red[0]; __syncthreads();
    float s = 0.0f;
    #pragma unroll
    for (int c = 0; c < 8; c++) {
        float e = expf(v[c] - gm);
        gexp[t + c * 1024] = e;
        s += e;
    }
    red[t] = s; __syncthreads();
    for (int st = 512; st > 0; st >>= 1) {
        if (t < st) red[t] += red[t + st];
        __syncthreads();
    }
    if (t == 0) scal[0] = 1.0f / red[0];
}

__launch_bounds__(256)
__global__ void wsum_k(const float* __restrict__ emsg, const float* __restrict__ gexp,
                       float* __restrict__ egp) {
    const int b = blockIdx.x, d = threadIdx.x;
    float s = 0.0f;
    const int i0 = b * 128;
    for (int i = 0; i < 128; i++) s += gexp[i0 + i] * emsg[(size_t)(i0 + i) * 256 + d];
    egp[b * 256 + d] = s;
}
__global__ void egfinal_f(const float* __restrict__ egp, const float* __restrict__ scal,
                          float* __restrict__ out) {
    const int d = threadIdx.x;
    float s = 0.0f;
    for (int b = 0; b < 64; b++) s += egp[b * 256 + d];
    out[d] = s * scal[0];
}

__global__ void wsbad_k(float* __restrict__ out) { out[3] = 9000.0f; }

// ---------------------------------------------------------------------------
extern "C" void kernel_launch(void* const* d_in, const int* in_sizes, int n_in,
                              void* d_out, int out_size, void* d_ws, size_t ws_size,
                              hipStream_t stream) {
    (void)in_sizes; (void)n_in; (void)out_size;
    const float* x_path = (const float*)d_in[0];
    const float* fc1_W  = (const float*)d_in[1];
    const float* fc1_b  = (const float*)d_in[2];
    const float* Wh     = (const float*)d_in[3];
    const float* bh     = (const float*)d_in[4];
    const float* Wt     = (const float*)d_in[5];
    const float* bt     = (const float*)d_in[6];
    const float* W1     = (const float*)d_in[7];
    const float* b1     = (const float*)d_in[8];
    const float* W2     = (const float*)d_in[9];
    const float* b2     = (const float*)d_in[10];
    const float* Ag1    = (const float*)d_in[11];
    const float* bg1    = (const float*)d_in[12];
    const float* Ag2    = (const float*)d_in[13];
    float* out_f = (float*)d_out;   // fp32: e_msg [0,2097152), e_g [2097152,2097408)

    const size_t WS_NEEDED = 26412048;
    if (ws_size < WS_NEEDED) {
        hipLaunchKernelGGL(wsbad_k, dim3(1), dim3(1), 0, stream, out_f);
        return;
    }

    char* ws = (char*)d_ws;
    float* x     = (float*)(ws + 0);
    unsigned short* et16 = (unsigned short*)(ws + 4194304);
    unsigned short* m1b  = (unsigned short*)(ws + 0);
    unsigned short* m2b  = (unsigned short*)(ws + 4194304);
    float* eh    = (float*)(ws + 8388608);
    float* emsg  = out_f;                     // e_msg written straight to d_out
    float* et    = (float*)(ws + 16777216);
    int*   candi = (int*)  (ws + 25165824);
    float* rowsum= (float*)(ws + 26214400);
    float* meanp = (float*)(ws + 26214400);   // dead after mwv_k (rowsum written later)
    float* biasH = (float*)(ws + 26247168);
    float* biasT = (float*)(ws + 26248192);
    float* glog  = (float*)(ws + 26280960);
    float* gexp  = (float*)(ws + 26313728);
    float* egp   = (float*)(ws + 26346496);
    float* scal  = (float*)(ws + 26412032);

    // weight planes in temporarily-dead regions (all stream-ordered safe):
    unsigned short* Fp = (unsigned short*)(ws + 16777216);   // fc1, in et region
    unsigned short* WHp = (unsigned short*)(ws + 25165824);  // in candi region
    unsigned short* WTp = (unsigned short*)(ws + 25559040);
    unsigned short* P1 = (unsigned short*)(ws + 16777216);   // in et region (post-stageD)
    unsigned short* P2 = (unsigned short*)(ws + 17170432);
    unsigned short* Gp = (unsigned short*)(ws + 25165824);   // in candi region (post-stageD)

    dim3 gg(4, 128);
    // 1) all front weight splits (fc1 + Wh + Wt) in one launch
    hipLaunchKernelGGL(tsplitAll, dim3(384), dim3(256), 0, stream,
                       fc1_W, Wh, Wt, Fp, WHp, WTp);
    // 2) x = leaky(x_path @ fc1_W + fc1_b)  [MFMA 3-split]
    hipLaunchKernelGGL((gemmM<1, 1, 0>), gg, dim3(256), 0, stream,
                       (const void*)x_path, Fp, fc1_b, x, 256, 1024, 262144);
    // 3) column partial sums (+ glog zero for gemmG atomics)
    hipLaunchKernelGGL(colsum_k, dim3(64), dim3(256), 0, stream, x, meanp, glog);
    // 4) mean reduce + fold mean-mix into eh/et bias
    hipLaunchKernelGGL(mwv_k, dim3(2), dim3(256), 0, stream,
                       meanp, Wh, bh, Wt, bt, biasH, biasT);
    // 5) eh, et = (0.5x)@{Wh,Wt} + bias'  [dual-B shared-A MFMA 3-split]
    hipLaunchKernelGGL(gemmD, gg, dim3(512), 0, stream,
                       x, WHp, WTp, biasH, biasT, eh, et, 65536);
    // 6) et16 + rowsum (eh16 eliminated: screen2 converts eh in-kernel)
    hipLaunchKernelGGL(epk, dim3(2048), dim3(256), 0, stream, et, et16, rowsum);
    // 7) screening
    hipLaunchKernelGGL(screen2, dim3(4, 64), dim3(512), 0, stream, eh, et16, candi);
    // 8) fp64 select + message -> m1b/m2b
    hipLaunchKernelGGL(stageD, dim3(2048), dim3(256), 0, stream, eh, et, rowsum,
                       candi, m1b, m2b);
    // 9) back weight splits (W1 + W2 + Ag1) in one launch
    hipLaunchKernelGGL(tsplit3t, dim3(160), dim3(256), 0, stream,
                       W1, W2, Ag1, P1, P2, Gp);
    // 10) e_msg = leaky(m1@W1+b1) + leaky(m2@W2+b2)  [single-pass dual gemm]
    hipLaunchKernelGGL(gemmE, gg, dim3(256), 0, stream,
                       m1b, m2b, P1, P2, b1, b2, emsg, 65536);
    // 11) readout gemm + fused gate -> glog (bg2 dropped: softmax-invariant)
    hipLaunchKernelGGL(gemmG, dim3(2, 128), dim3(256), 0, stream,
                       emsg, Gp, bg1, Ag2, glog, 32768);
    // 12-14) softmax; weighted sum; final reduce
    hipLaunchKernelGGL(softmax_g, dim3(1), dim3(1024), 0, stream, glog, gexp, scal);
    hipLaunchKernelGGL(wsum_k, dim3(64), dim3(256), 0, stream, emsg, gexp, egp);
    hipLaunchKernelGGL(egfinal_f, dim3(1), dim3(256), 0, stream, egp, scal, out_f + 2097152);
}

// Round 14
// 293.421 us; speedup vs baseline: 1.1857x; 1.0240x over previous
//
#include <hip/hip_runtime.h>

// MOTCAT_Surv R24. R23 passed (300.5 us, absmax 0.0156). Tail cleanup only, no
// proven inner loop touched. Rejected on aliasing audit: epk-into-gemmD (et16
// [4,8.4M) overlaps x [0,8M) still being read -- race) and fc1-planes-output
// (12MB collides with eh). Rejected 32->24 candidates (truncated-key interloper
// analysis: top-8/quarter margin is required). This round: (a) colsum fused
// into fc1 gemmM epilogue (per-block col partials, g-butterfly, atomicAdd into
// colacc[256]; deletes launch + 8MB x re-read; mean error ~1e-6 = bias shift,
// harmless); (b) egfinal fused into wsum (atomicAdd x scal into e_g out,
// zeroed in softmax_g); (c) zeroing (colacc, glog) in tsplitAll.
// Launches 14 -> 12.

typedef __attribute__((ext_vector_type(8))) short short8;
typedef __attribute__((ext_vector_type(4))) short short4v;
typedef __attribute__((ext_vector_type(4))) float f32x4;

__device__ inline float bf2f(unsigned short b) {
    unsigned u = ((unsigned)b) << 16;
    return __builtin_bit_cast(float, u);
}
__device__ inline unsigned short f2bf(float f) {   // round-to-nearest-even
    unsigned u = __builtin_bit_cast(unsigned, f);
    unsigned r = u + 0x7fffu + ((u >> 16) & 1u);
    return (unsigned short)(r >> 16);
}
__device__ inline f32x4 mfma16(short8 a, short8 b, f32x4 c) {
    return __builtin_amdgcn_mfma_f32_16x16x32_bf16(a, b, c, 0, 0, 0);
}
// A-frag: lane holds A[m=lane&15][k=(lane>>4)*8+j]; B-frag: B[k][n=lane&15];
// C/D: col=lane&15 (n), row=(lane>>4)*4+reg (m) (learn_hip m89).

__device__ inline void gload_lds16(const unsigned short* g, unsigned short* l) {
    __builtin_amdgcn_global_load_lds(
        (const __attribute__((address_space(1))) void*)g,
        (__attribute__((address_space(3))) void*)l, 16, 0, 0);
}

// trunc-split fp32 -> bf16 hi/mid/lo (proven R21): exact residual subtractions.
__device__ inline void split8(const f32x4 v0, const f32x4 v1,
                              short8& hi, short8& md, short8& lo) {
    #pragma unroll
    for (int e = 0; e < 8; e++) {
        float a = (e < 4) ? v0[e] : v1[e - 4];
        unsigned ua = __builtin_bit_cast(unsigned, a);
        float h = __builtin_bit_cast(float, ua & 0xFFFF0000u);
        float r1 = a - h;
        unsigned u1 = __builtin_bit_cast(unsigned, r1);
        float m = __builtin_bit_cast(float, u1 & 0xFFFF0000u);
        float r2 = r1 - m;
        unsigned u2 = __builtin_bit_cast(unsigned, r2);
        hi[e] = (short)(ua >> 16);
        md[e] = (short)(u1 >> 16);
        lo[e] = (short)(u2 >> 16);
    }
}
__device__ inline void split4(f32x4 v, short4v& hi, short4v& md, short4v& lo) {
    #pragma unroll
    for (int e = 0; e < 4; e++) {
        float a = v[e];
        unsigned ua = __builtin_bit_cast(unsigned, a);
        float h = __builtin_bit_cast(float, ua & 0xFFFF0000u);
        float r1 = a - h;
        unsigned u1 = __builtin_bit_cast(unsigned, r1);
        float m = __builtin_bit_cast(float, u1 & 0xFFFF0000u);
        float r2 = r1 - m;
        unsigned u2 = __builtin_bit_cast(unsigned, r2);
        hi[e] = (short)(ua >> 16);
        md[e] = (short)(u1 >> 16);
        lo[e] = (short)(u2 >> 16);
    }
}

// ---------------------------------------------------------------------------
// tsplit bodies: W [K][N] fp32 -> Bt planes [n][k] bf16 (hi,mid,lo) at out+p*PS.
// ---------------------------------------------------------------------------
__device__ inline void tsplit_body(const float* __restrict__ W,
                                   unsigned short* __restrict__ out,
                                   int K, int N, int PS, int bx, int by, int t) {
    __shared__ float T[32][33];
    const int n0 = bx * 32, k0 = by * 32;
    {
        const int r = t >> 3, c = (t & 7) * 4;
        f32x4 v = *(const f32x4*)&W[(size_t)(k0 + r) * N + n0 + c];
        #pragma unroll
        for (int e = 0; e < 4; e++) T[r][c + e] = v[e];
    }
    __syncthreads();
    const int nr = t >> 3, kc = (t & 7) * 4;
    short4v h4, m4, l4;
    #pragma unroll
    for (int e = 0; e < 4; e++) {
        float a = T[kc + e][nr];
        unsigned short h = f2bf(a);
        float r1 = a - bf2f(h);
        unsigned short m = f2bf(r1);
        float r2 = r1 - bf2f(m);
        h4[e] = (short)h; m4[e] = (short)m; l4[e] = (short)f2bf(r2);
    }
    const size_t o = (size_t)(n0 + nr) * K + k0 + kc;
    *(short4v*)&out[o] = h4;
    *(short4v*)&out[(size_t)PS + o] = m4;
    *(short4v*)&out[(size_t)2 * PS + o] = l4;
}
// fc1 (256 blocks) + Wh (64) + Wt (64); also zeroes glog + colacc.
__launch_bounds__(256)
__global__ void tsplitAll(const float* __restrict__ fc1_W, const float* __restrict__ Wh,
                          const float* __restrict__ Wt,
                          unsigned short* __restrict__ Fp,
                          unsigned short* __restrict__ WHp,
                          unsigned short* __restrict__ WTp,
                          float* __restrict__ glog, float* __restrict__ colacc) {
    const int idx = blockIdx.x, t = threadIdx.x;
    const int zid = idx * 256 + t;
    if (zid < 8192) glog[zid] = 0.0f;
    if (zid < 256) colacc[zid] = 0.0f;
    if (idx < 256) tsplit_body(fc1_W, Fp, 1024, 256, 262144, idx & 7, idx >> 3, t);
    else if (idx < 320) { int r = idx - 256; tsplit_body(Wh, WHp, 256, 256, 65536, r & 7, r >> 3, t); }
    else { int r = idx - 320; tsplit_body(Wt, WTp, 256, 256, 65536, r & 7, r >> 3, t); }
}
// W1 (64) + W2 (64) + Ag1 (32)
__launch_bounds__(256)
__global__ void tsplit3t(const float* __restrict__ W1, const float* __restrict__ W2,
                         const float* __restrict__ Ag1,
                         unsigned short* __restrict__ P1,
                         unsigned short* __restrict__ P2,
                         unsigned short* __restrict__ Gp) {
    const int idx = blockIdx.x, t = threadIdx.x;
    if (idx < 64) tsplit_body(W1, P1, 256, 256, 65536, idx & 7, idx >> 3, t);
    else if (idx < 128) { int r = idx - 64; tsplit_body(W2, P2, 256, 256, 65536, r & 7, r >> 3, t); }
    else { int r = idx - 128; tsplit_body(Ag1, Gp, 256, 128, 32768, r & 3, r >> 2, t); }
}

// ---------------------------------------------------------------------------
// gemmM (proven R21 core; fc1-only): C = leaky(A@B + bias); epilogue also
// accumulates column partial sums into colacc (fused colsum).
// ---------------------------------------------------------------------------
__launch_bounds__(256)
__global__ void gemmM(const float* __restrict__ A,
                      const unsigned short* __restrict__ Bt,
                      const float* __restrict__ bias, float* __restrict__ C,
                      float* __restrict__ colacc, int N, int K, int BPS) {
    __shared__ __align__(16) unsigned short LA[2][3 * 2048];
    __shared__ __align__(16) unsigned short LB[2][3 * 2048];
    const int t = threadIdx.x;
    const int r0 = blockIdx.y * 64, c0 = blockIdx.x * 64;
    const int lid = t & 63, w = t >> 6, g = lid >> 4, m16 = lid & 15;
    const int wm = w >> 1, wn = w & 1;

    f32x4 acc[2][2];
    #pragma unroll
    for (int mf = 0; mf < 2; mf++)
        #pragma unroll
        for (int nf = 0; nf < 2; nf++) acc[mf][nf] = {0.0f, 0.0f, 0.0f, 0.0f};

    const int KT = K >> 5;
    const size_t aoff = (size_t)(r0 + (t >> 2)) * K + (t & 3) * 8;
    const size_t boff = (size_t)(c0 + (t >> 2)) * K + (t & 3) * 8;

    {
        #pragma unroll
        for (int p = 0; p < 3; p++)
            gload_lds16(&Bt[(size_t)p * BPS + boff], &LB[0][p * 2048 + 8 * t]);
        f32x4 v0 = *(const f32x4*)&A[aoff];
        f32x4 v1 = *(const f32x4*)&A[aoff + 4];
        short8 hi, md, lo;
        split8(v0, v1, hi, md, lo);
        *(short8*)&LA[0][8 * t] = hi;
        *(short8*)&LA[0][2048 + 8 * t] = md;
        *(short8*)&LA[0][4096 + 8 * t] = lo;
    }
    __syncthreads();

    for (int kt = 0; kt < KT; kt++) {
        const int cur = kt & 1, nxt = cur ^ 1;
        const bool hn = (kt + 1) < KT;
        f32x4 v0, v1;
        if (hn) {
            const size_t ko = (size_t)(kt + 1) * 32;
            #pragma unroll
            for (int p = 0; p < 3; p++)
                gload_lds16(&Bt[(size_t)p * BPS + boff + ko],
                            &LB[nxt][p * 2048 + 8 * t]);
            v0 = *(const f32x4*)&A[aoff + ko];
            v1 = *(const f32x4*)&A[aoff + ko + 4];
        }
        short8 af[2][3], bf[2][3];
        #pragma unroll
        for (int mf = 0; mf < 2; mf++) {
            const int row = wm * 32 + mf * 16 + m16;
            #pragma unroll
            for (int p = 0; p < 3; p++)
                af[mf][p] = *(const short8*)&LA[cur][p * 2048 + row * 32 + g * 8];
        }
        #pragma unroll
        for (int nf = 0; nf < 2; nf++) {
            const int col = wn * 32 + nf * 16 + m16;
            #pragma unroll
            for (int p = 0; p < 3; p++)
                bf[nf][p] = *(const short8*)&LB[cur][p * 2048 + col * 32 + g * 8];
        }
        #pragma unroll
        for (int mf = 0; mf < 2; mf++)
            #pragma unroll
            for (int nf = 0; nf < 2; nf++) {
                acc[mf][nf] = mfma16(af[mf][0], bf[nf][0], acc[mf][nf]); // hh
                acc[mf][nf] = mfma16(af[mf][0], bf[nf][1], acc[mf][nf]); // hm
                acc[mf][nf] = mfma16(af[mf][1], bf[nf][0], acc[mf][nf]); // mh
                acc[mf][nf] = mfma16(af[mf][0], bf[nf][2], acc[mf][nf]); // hl
                acc[mf][nf] = mfma16(af[mf][1], bf[nf][1], acc[mf][nf]); // mm
                acc[mf][nf] = mfma16(af[mf][2], bf[nf][0], acc[mf][nf]); // lh
            }
        if (hn) {
            short8 hi, md, lo;
            split8(v0, v1, hi, md, lo);
            *(short8*)&LA[nxt][8 * t] = hi;
            *(short8*)&LA[nxt][2048 + 8 * t] = md;
            *(short8*)&LA[nxt][4096 + 8 * t] = lo;
        }
        __syncthreads();
    }

    float csum[2] = {0.0f, 0.0f};
    #pragma unroll
    for (int nf = 0; nf < 2; nf++) {
        const int col = c0 + wn * 32 + nf * 16 + m16;
        const float bv = bias[col];
        #pragma unroll
        for (int mf = 0; mf < 2; mf++) {
            #pragma unroll
            for (int r = 0; r < 4; r++) {
                const int row = r0 + wm * 32 + mf * 16 + g * 4 + r;
                float v = acc[mf][nf][r] + bv;
                v = v > 0.0f ? v : 0.01f * v;
                C[(size_t)row * N + col] = v;
                csum[nf] += v;
            }
        }
    }
    // fused column-sum: reduce over g (lane bits 4-5), one atomic per (wave,col)
    #pragma unroll
    for (int st = 16; st <= 32; st <<= 1) {
        csum[0] += __shfl_xor(csum[0], st);
        csum[1] += __shfl_xor(csum[1], st);
    }
    if (g == 0) {
        atomicAdd(&colacc[c0 + wn * 32 + m16], csum[0]);
        atomicAdd(&colacc[c0 + wn * 32 + 16 + m16], csum[1]);
    }
}

// ---------------------------------------------------------------------------
// gemmD (proven R22): dual-B shared-A. eh = (0.5x)@Wh + biasH; et = ... + biasT.
// ---------------------------------------------------------------------------
__launch_bounds__(512)
__global__ void gemmD(const float* __restrict__ A,
                      const unsigned short* __restrict__ BH,
                      const unsigned short* __restrict__ BT,
                      const float* __restrict__ biasH, const float* __restrict__ biasT,
                      float* __restrict__ CH, float* __restrict__ CT, int BPS) {
    __shared__ __align__(16) unsigned short LA[2][3 * 2048];
    __shared__ __align__(16) unsigned short LB[2][6 * 2048];
    const int t = threadIdx.x;
    const int r0 = blockIdx.y * 64, c0 = blockIdx.x * 64;
    const int lid = t & 63, w = t >> 6, g = lid >> 4, m16 = lid & 15;
    const int mat = w >> 2, wsub = w & 3, wm = wsub >> 1, wn = wsub & 1;
    const int K = 256;

    f32x4 acc[2][2];
    #pragma unroll
    for (int mf = 0; mf < 2; mf++)
        #pragma unroll
        for (int nf = 0; nf < 2; nf++) acc[mf][nf] = {0.0f, 0.0f, 0.0f, 0.0f};

    const int arow = t >> 3, akq = (t & 7) * 4;
    const size_t aoff = (size_t)(r0 + arow) * K + akq;
    const int aldst = arow * 32 + akq;
    int bdst[3];
    size_t bsrc[3];
    #pragma unroll
    for (int s = 0; s < 3; s++) {
        int L = t + s * 512;
        int mp = L >> 8;
        bdst[s] = mp * 2048 + (L & 255) * 8;
        int mm = mp >= 3, pl = mp - 3 * mm;
        const unsigned short* base = mm ? BT : BH;
        bsrc[s] = (size_t)(base - BH) + (size_t)pl * BPS +
                  (size_t)(c0 + ((L >> 2) & 63)) * K + (L & 3) * 8;
    }

    {
        #pragma unroll
        for (int s = 0; s < 3; s++)
            gload_lds16(&BH[bsrc[s]], &LB[0][bdst[s]]);
        f32x4 v = *(const f32x4*)&A[aoff];
        #pragma unroll
        for (int e = 0; e < 4; e++) v[e] *= 0.5f;
        short4v hi, md, lo;
        split4(v, hi, md, lo);
        *(short4v*)&LA[0][aldst] = hi;
        *(short4v*)&LA[0][2048 + aldst] = md;
        *(short4v*)&LA[0][4096 + aldst] = lo;
    }
    __syncthreads();

    for (int kt = 0; kt < 8; kt++) {
        const int cur = kt & 1, nxt = cur ^ 1;
        const bool hn = (kt + 1) < 8;
        f32x4 v;
        if (hn) {
            const size_t ko = (size_t)(kt + 1) * 32;
            #pragma unroll
            for (int s = 0; s < 3; s++)
                gload_lds16(&BH[bsrc[s] + ko], &LB[nxt][bdst[s]]);
            v = *(const f32x4*)&A[aoff + ko];
            #pragma unroll
            for (int e = 0; e < 4; e++) v[e] *= 0.5f;
        }
        short8 af[2][3], bf[2][3];
        #pragma unroll
        for (int mf = 0; mf < 2; mf++) {
            const int row = wm * 32 + mf * 16 + m16;
            #pragma unroll
            for (int p = 0; p < 3; p++)
                af[mf][p] = *(const short8*)&LA[cur][p * 2048 + row * 32 + g * 8];
        }
        #pragma unroll
        for (int nf = 0; nf < 2; nf++) {
            const int col = wn * 32 + nf * 16 + m16;
            #pragma unroll
            for (int p = 0; p < 3; p++)
                bf[nf][p] = *(const short8*)
                    &LB[cur][(mat * 3 + p) * 2048 + col * 32 + g * 8];
        }
        #pragma unroll
        for (int mf = 0; mf < 2; mf++)
            #pragma unroll
            for (int nf = 0; nf < 2; nf++) {
                acc[mf][nf] = mfma16(af[mf][0], bf[nf][0], acc[mf][nf]); // hh
                acc[mf][nf] = mfma16(af[mf][0], bf[nf][1], acc[mf][nf]); // hm
                acc[mf][nf] = mfma16(af[mf][1], bf[nf][0], acc[mf][nf]); // mh
                acc[mf][nf] = mfma16(af[mf][0], bf[nf][2], acc[mf][nf]); // hl
                acc[mf][nf] = mfma16(af[mf][1], bf[nf][1], acc[mf][nf]); // mm
                acc[mf][nf] = mfma16(af[mf][2], bf[nf][0], acc[mf][nf]); // lh
            }
        if (hn) {
            short4v hi, md, lo;
            split4(v, hi, md, lo);
            *(short4v*)&LA[nxt][aldst] = hi;
            *(short4v*)&LA[nxt][2048 + aldst] = md;
            *(short4v*)&LA[nxt][4096 + aldst] = lo;
        }
        __syncthreads();
    }

    float* C = mat ? CT : CH;
    const float* bias = mat ? biasT : biasH;
    #pragma unroll
    for (int nf = 0; nf < 2; nf++) {
        const int col = c0 + wn * 32 + nf * 16 + m16;
        const float bv = bias[col];
        #pragma unroll
        for (int mf = 0; mf < 2; mf++) {
            #pragma unroll
            for (int r = 0; r < 4; r++) {
                const int row = r0 + wm * 32 + mf * 16 + g * 4 + r;
                C[(size_t)row * 256 + col] = acc[mf][nf][r] + bv;
            }
        }
    }
}

// ---------------------------------------------------------------------------
// gemmE (proven R22): emsg = leaky(m1@W1+b1) + leaky(m2@W2+b2), single pass.
// ---------------------------------------------------------------------------
__launch_bounds__(256)
__global__ void gemmE(const unsigned short* __restrict__ A1,
                      const unsigned short* __restrict__ A2,
                      const unsigned short* __restrict__ P1,
                      const unsigned short* __restrict__ P2,
                      const float* __restrict__ b1, const float* __restrict__ b2,
                      float* __restrict__ C, int BPS) {
    __shared__ __align__(16) unsigned short LA[2][2 * 2048];
    __shared__ __align__(16) unsigned short LB[2][4 * 2048];
    const int t = threadIdx.x;
    const int r0 = blockIdx.y * 64, c0 = blockIdx.x * 64;
    const int lid = t & 63, w = t >> 6, g = lid >> 4, m16 = lid & 15;
    const int wm = w >> 1, wn = w & 1;
    const int K = 256;

    f32x4 acc[2][2][2];
    #pragma unroll
    for (int m = 0; m < 2; m++)
        #pragma unroll
        for (int mf = 0; mf < 2; mf++)
            #pragma unroll
            for (int nf = 0; nf < 2; nf++) acc[m][mf][nf] = {0.0f, 0.0f, 0.0f, 0.0f};

    const size_t aoff = (size_t)(r0 + (t >> 2)) * K + (t & 3) * 8;
    const size_t boff = (size_t)(c0 + (t >> 2)) * K + (t & 3) * 8;

    {
        gload_lds16(&A1[aoff], &LA[0][8 * t]);
        gload_lds16(&A2[aoff], &LA[0][2048 + 8 * t]);
        gload_lds16(&P1[boff], &LB[0][8 * t]);
        gload_lds16(&P1[(size_t)BPS + boff], &LB[0][2048 + 8 * t]);
        gload_lds16(&P2[boff], &LB[0][4096 + 8 * t]);
        gload_lds16(&P2[(size_t)BPS + boff], &LB[0][6144 + 8 * t]);
    }
    __syncthreads();

    for (int kt = 0; kt < 8; kt++) {
        const int cur = kt & 1, nxt = cur ^ 1;
        const bool hn = (kt + 1) < 8;
        if (hn) {
            const size_t ko = (size_t)(kt + 1) * 32;
            gload_lds16(&A1[aoff + ko], &LA[nxt][8 * t]);
            gload_lds16(&A2[aoff + ko], &LA[nxt][2048 + 8 * t]);
            gload_lds16(&P1[boff + ko], &LB[nxt][8 * t]);
            gload_lds16(&P1[(size_t)BPS + boff + ko], &LB[nxt][2048 + 8 * t]);
            gload_lds16(&P2[boff + ko], &LB[nxt][4096 + 8 * t]);
            gload_lds16(&P2[(size_t)BPS + boff + ko], &LB[nxt][6144 + 8 * t]);
        }
        short8 af[2][2], bf[2][2][2];
        #pragma unroll
        for (int m = 0; m < 2; m++)
            #pragma unroll
            for (int mf = 0; mf < 2; mf++) {
                const int row = wm * 32 + mf * 16 + m16;
                af[m][mf] = *(const short8*)&LA[cur][m * 2048 + row * 32 + g * 8];
            }
        #pragma unroll
        for (int m = 0; m < 2; m++)
            #pragma unroll
            for (int nf = 0; nf < 2; nf++) {
                const int col = wn * 32 + nf * 16 + m16;
                #pragma unroll
                for (int p = 0; p < 2; p++)
                    bf[m][nf][p] = *(const short8*)
                        &LB[cur][(m * 2 + p) * 2048 + col * 32 + g * 8];
            }
        #pragma unroll
        for (int m = 0; m < 2; m++)
            #pragma unroll
            for (int mf = 0; mf < 2; mf++)
                #pragma unroll
                for (int nf = 0; nf < 2; nf++) {
                    acc[m][mf][nf] = mfma16(af[m][mf], bf[m][nf][0], acc[m][mf][nf]);
                    acc[m][mf][nf] = mfma16(af[m][mf], bf[m][nf][1], acc[m][mf][nf]);
                }
        __syncthreads();
    }

    #pragma unroll
    for (int nf = 0; nf < 2; nf++) {
        const int col = c0 + wn * 32 + nf * 16 + m16;
        const float bv1 = b1[col], bv2 = b2[col];
        #pragma unroll
        for (int mf = 0; mf < 2; mf++) {
            #pragma unroll
            for (int r = 0; r < 4; r++) {
                const int row = r0 + wm * 32 + mf * 16 + g * 4 + r;
                float v1 = acc[0][mf][nf][r] + bv1;
                v1 = v1 > 0.0f ? v1 : 0.01f * v1;
                float v2 = acc[1][mf][nf][r] + bv2;
                v2 = v2 > 0.0f ? v2 : 0.01f * v2;
                C[(size_t)row * 256 + col] = v1 + v2;
            }
        }
    }
}

// ---------------------------------------------------------------------------
// gemmG (proven R23): readout GEMM + fused gate -> glog atomics.
// ---------------------------------------------------------------------------
__launch_bounds__(256)
__global__ void gemmG(const float* __restrict__ A,
                      const unsigned short* __restrict__ Bt,
                      const float* __restrict__ bias,
                      const float* __restrict__ Ag2, float* __restrict__ glog,
                      int BPS) {
    __shared__ __align__(16) unsigned short LA[2][3 * 2048];
    __shared__ __align__(16) unsigned short LB[2][3 * 2048];
    const int t = threadIdx.x;
    const int r0 = blockIdx.y * 64, c0 = blockIdx.x * 64;
    const int lid = t & 63, w = t >> 6, g = lid >> 4, m16 = lid & 15;
    const int wm = w >> 1, wn = w & 1;
    const int K = 256;

    f32x4 acc[2][2];
    #pragma unroll
    for (int mf = 0; mf < 2; mf++)
        #pragma unroll
        for (int nf = 0; nf < 2; nf++) acc[mf][nf] = {0.0f, 0.0f, 0.0f, 0.0f};

    const size_t aoff = (size_t)(r0 + (t >> 2)) * K + (t & 3) * 8;
    const size_t boff = (size_t)(c0 + (t >> 2)) * K + (t & 3) * 8;

    {
        #pragma unroll
        for (int p = 0; p < 3; p++)
            gload_lds16(&Bt[(size_t)p * BPS + boff], &LB[0][p * 2048 + 8 * t]);
        f32x4 v0 = *(const f32x4*)&A[aoff];
        f32x4 v1 = *(const f32x4*)&A[aoff + 4];
        short8 hi, md, lo;
        split8(v0, v1, hi, md, lo);
        *(short8*)&LA[0][8 * t] = hi;
        *(short8*)&LA[0][2048 + 8 * t] = md;
        *(short8*)&LA[0][4096 + 8 * t] = lo;
    }
    __syncthreads();

    for (int kt = 0; kt < 8; kt++) {
        const int cur = kt & 1, nxt = cur ^ 1;
        const bool hn = (kt + 1) < 8;
        f32x4 v0, v1;
        if (hn) {
            const size_t ko = (size_t)(kt + 1) * 32;
            #pragma unroll
            for (int p = 0; p < 3; p++)
                gload_lds16(&Bt[(size_t)p * BPS + boff + ko],
                            &LB[nxt][p * 2048 + 8 * t]);
            v0 = *(const f32x4*)&A[aoff + ko];
            v1 = *(const f32x4*)&A[aoff + ko + 4];
        }
        short8 af[2][3], bf[2][3];
        #pragma unroll
        for (int mf = 0; mf < 2; mf++) {
            const int row = wm * 32 + mf * 16 + m16;
            #pragma unroll
            for (int p = 0; p < 3; p++)
                af[mf][p] = *(const short8*)&LA[cur][p * 2048 + row * 32 + g * 8];
        }
        #pragma unroll
        for (int nf = 0; nf < 2; nf++) {
            const int col = wn * 32 + nf * 16 + m16;
            #pragma unroll
            for (int p = 0; p < 3; p++)
                bf[nf][p] = *(const short8*)&LB[cur][p * 2048 + col * 32 + g * 8];
        }
        #pragma unroll
        for (int mf = 0; mf < 2; mf++)
            #pragma unroll
            for (int nf = 0; nf < 2; nf++) {
                acc[mf][nf] = mfma16(af[mf][0], bf[nf][0], acc[mf][nf]);
                acc[mf][nf] = mfma16(af[mf][0], bf[nf][1], acc[mf][nf]);
                acc[mf][nf] = mfma16(af[mf][1], bf[nf][0], acc[mf][nf]);
                acc[mf][nf] = mfma16(af[mf][0], bf[nf][2], acc[mf][nf]);
                acc[mf][nf] = mfma16(af[mf][1], bf[nf][1], acc[mf][nf]);
                acc[mf][nf] = mfma16(af[mf][2], bf[nf][0], acc[mf][nf]);
            }
        if (hn) {
            short8 hi, md, lo;
            split8(v0, v1, hi, md, lo);
            *(short8*)&LA[nxt][8 * t] = hi;
            *(short8*)&LA[nxt][2048 + 8 * t] = md;
            *(short8*)&LA[nxt][4096 + 8 * t] = lo;
        }
        __syncthreads();
    }

    float pp[2][4];
    #pragma unroll
    for (int mf = 0; mf < 2; mf++)
        #pragma unroll
        for (int r = 0; r < 4; r++) pp[mf][r] = 0.0f;
    #pragma unroll
    for (int nf = 0; nf < 2; nf++) {
        const int col = c0 + wn * 32 + nf * 16 + m16;
        const float bv = bias[col], a2 = Ag2[col];
        #pragma unroll
        for (int mf = 0; mf < 2; mf++) {
            #pragma unroll
            for (int r = 0; r < 4; r++) {
                float v = acc[mf][nf][r] + bv;
                v = v > 0.0f ? v : 0.01f * v;
                pp[mf][r] += v * a2;
            }
        }
    }
    #pragma unroll
    for (int st = 1; st < 16; st <<= 1)
        #pragma unroll
        for (int mf = 0; mf < 2; mf++)
            #pragma unroll
            for (int r = 0; r < 4; r++) pp[mf][r] += __shfl_xor(pp[mf][r], st);
    if (m16 == 0) {
        #pragma unroll
        for (int mf = 0; mf < 2; mf++)
            #pragma unroll
            for (int r = 0; r < 4; r++)
                atomicAdd(&glog[r0 + wm * 32 + mf * 16 + g * 4 + r], pp[mf][r]);
    }
}

// ---------------------------------------------------------------------------
// mwv_k: mean from colacc + biasX[n] = bx[n] + 0.5*sum_d mean[d]*W[d][n].
__launch_bounds__(256)
__global__ void mwv_k(const float* __restrict__ colacc,
                      const float* __restrict__ Wh, const float* __restrict__ bh,
                      const float* __restrict__ Wt, const float* __restrict__ bt,
                      float* __restrict__ biasH, float* __restrict__ biasT) {
    __shared__ float mean[256];
    const int n = threadIdx.x;
    mean[n] = colacc[n] * (1.0f / 8192.0f);
    __syncthreads();
    const float* W = blockIdx.x ? Wt : Wh;
    const float* bb = blockIdx.x ? bt : bh;
    float* o = blockIdx.x ? biasT : biasH;
    float s = 0.0f;
    for (int d = 0; d < 256; d++) s += mean[d] * W[d * 256 + n];
    o[n] = bb[n] + 0.5f * s;
}
// epk: et -> et16 (f2bf) + rowsum. grid 2048 x 256.
__launch_bounds__(256)
__global__ void epk(const float* __restrict__ et, unsigned short* __restrict__ et16,
                    float* __restrict__ rowsum) {
    const int w = threadIdx.x >> 6, l = threadIdx.x & 63;
    const int i = blockIdx.x * 4 + w;
    f32x4 v = *(const f32x4*)&et[(size_t)i * 256 + l * 4];
    short4v h;
    #pragma unroll
    for (int e = 0; e < 4; e++) h[e] = (short)f2bf(v[e]);
    *(short4v*)&et16[(size_t)i * 256 + l * 4] = h;
    float s = v[0] + v[1] + v[2] + v[3];
    #pragma unroll
    for (int st = 1; st < 64; st <<= 1) s += __shfl_xor(s, st);
    if (l == 0) rowsum[i] = s;
}

// ---------------------------------------------------------------------------
// float keys (col in low-11 mantissa bits), med3 insert. Ascending, tk[0]=min.
// ---------------------------------------------------------------------------
__device__ inline float packkey(float v, unsigned col) {
    unsigned u = (__builtin_bit_cast(unsigned, v) & 0xFFFFF800u) | col;
    return __builtin_bit_cast(float, u);
}
template<int NK>
__device__ inline void insf(float (&tk)[NK], float key) {
    #pragma unroll
    for (int k = 0; k < NK - 1; k++)
        tk[k] = __builtin_amdgcn_fmed3f(key, tk[k + 1], tk[k]);
    tk[NK - 1] = fmaxf(tk[NK - 1], key);
}

// ---------------------------------------------------------------------------
// screen2 (proven R23): 512 thr, 128 rows/block, grid (4,64), 2-tile groups
// double-buffered, 1 barrier/group; bfr converts from eh fp32 in-kernel.
// ---------------------------------------------------------------------------
__launch_bounds__(512)
__global__ void screen2(const float* __restrict__ eh,
                        const unsigned short* __restrict__ et16,
                        int* __restrict__ candi) {
    __shared__ __align__(16) unsigned short Bs[2][2][8192];
    __shared__ float mbuf[8][2][16][8];
    const int t = threadIdx.x;
    const int cs = blockIdx.x;
    const int r0 = blockIdx.y * 128;
    const int w = t >> 6, lid = t & 63, lg = lid >> 4, m16 = lid & 15;
    const int rs = w >> 1, ch = w & 1;

    short8 bfr[2][8];
    #pragma unroll
    for (int s = 0; s < 2; s++)
        #pragma unroll
        for (int ks = 0; ks < 8; ks++) {
            const float* p = &eh[(size_t)(r0 + rs * 32 + s * 16 + m16) * 256
                                 + ks * 32 + lg * 8];
            f32x4 a = *(const f32x4*)p;
            f32x4 b = *(const f32x4*)(p + 4);
            short8 hh;
            #pragma unroll
            for (int e = 0; e < 4; e++) {
                hh[e] = (short)f2bf(a[e]);
                hh[4 + e] = (short)f2bf(b[e]);
            }
            bfr[s][ks] = hh;
        }

    float tk0[6], tk1[6];
    #pragma unroll
    for (int q = 0; q < 6; q++) { tk0[q] = -3.0e38f; tk1[q] = -3.0e38f; }

    int scol[2], goff[2], ldsl[2];
    #pragma unroll
    for (int c = 0; c < 2; c++) {
        int L = (w * 2 + c) * 64 + lid;
        int col = L >> 5, gs = L & 31;
        int gorig = (gs & 24) | ((gs ^ col) & 7);
        scol[c] = col; goff[c] = gorig * 8; ldsl[c] = L * 8;
    }

    #pragma unroll
    for (int tt = 0; tt < 2; tt++) {
        const int j0 = cs * 2048 + tt * 32;
        #pragma unroll
        for (int c = 0; c < 2; c++)
            gload_lds16(&et16[(size_t)(j0 + scol[c]) * 256 + goff[c]],
                        &Bs[0][tt][ldsl[c]]);
    }
    __syncthreads();

    const int swz = m16 & 7;
    const int cbase = (ch * 16 + m16) * 32;
    for (int gi = 0; gi < 32; gi++) {
        const int cur = gi & 1;
        if (gi + 1 < 32) {
            #pragma unroll
            for (int tt = 0; tt < 2; tt++) {
                const int j1 = cs * 2048 + ((gi + 1) * 2 + tt) * 32;
                #pragma unroll
                for (int c = 0; c < 2; c++)
                    gload_lds16(&et16[(size_t)(j1 + scol[c]) * 256 + goff[c]],
                                &Bs[cur ^ 1][tt][ldsl[c]]);
            }
        }
        #pragma unroll
        for (int tt = 0; tt < 2; tt++) {
            const int tile = gi * 2 + tt;
            const unsigned short* bst = Bs[cur][tt];
            f32x4 a0 = {0.0f, 0.0f, 0.0f, 0.0f}, a1 = a0;
            #pragma unroll
            for (int ks = 0; ks < 8; ks++) {
                const int gq = ks * 4 + lg;
                short8 e = *(const short8*)&bst[(cbase + (gq ^ swz)) * 8];
                a0 = mfma16(e, bfr[0][ks], a0);
                a1 = mfma16(e, bfr[1][ks], a1);
            }
            const unsigned cb = (unsigned)(tile * 32 + ch * 16 + lg * 4);
            #pragma unroll
            for (int r = 0; r < 4; r++) {
                insf<6>(tk0, packkey(a0[r], cb + (unsigned)r));
                insf<6>(tk1, packkey(a1[r], cb + (unsigned)r));
            }
        }
        __syncthreads();
    }

    #pragma unroll
    for (int s = 0; s < 2; s++) {
        float tk8[8];
        tk8[0] = -3.0e38f; tk8[1] = -3.0e38f;
        #pragma unroll
        for (int q = 0; q < 6; q++) tk8[q + 2] = s ? tk1[q] : tk0[q];
        #pragma unroll
        for (int step = 16; step <= 32; step <<= 1) {
            float ok[8];
            #pragma unroll
            for (int q = 0; q < 8; q++) ok[q] = __shfl_xor(tk8[q], step);
            #pragma unroll
            for (int q = 0; q < 8; q++) insf<8>(tk8, ok[q]);
        }
        if (lg == 0) {
            #pragma unroll
            for (int q = 0; q < 8; q++) mbuf[rs * 2 + s][ch][m16][q] = tk8[q];
        }
    }
    __syncthreads();

    if (t < 128) {
        float tk8[8];
        #pragma unroll
        for (int q = 0; q < 8; q++) tk8[q] = mbuf[t >> 4][0][t & 15][q];
        #pragma unroll
        for (int q = 0; q < 8; q++) insf<8>(tk8, mbuf[t >> 4][1][t & 15][q]);
        const int row = r0 + t;
        #pragma unroll
        for (int q = 0; q < 8; q++)
            candi[(size_t)row * 32 + cs * 8 + q] =
                cs * 2048 + (int)(__builtin_bit_cast(unsigned, tk8[q]) & 0x7FFu);
    }
}

// ---------------------------------------------------------------------------
// Stage D (proven R19): LDS-free, barrier-free; 4 waves/block, one row per wave.
// ---------------------------------------------------------------------------
__launch_bounds__(256)
__global__ void stageD(const float* __restrict__ eh, const float* __restrict__ et,
                       const float* __restrict__ rowsum,
                       const int* __restrict__ candi,
                       unsigned short* __restrict__ m1, unsigned short* __restrict__ m2) {
    const int w = threadIdx.x >> 6, l = threadIdx.x & 63;
    const int i = blockIdx.x * 4 + w;
    const int c_own = l & 31;

    const int jown = candi[(size_t)i * 32 + c_own] & 8191;

    const int q = l & 7, g8 = l >> 3;
    const float* er = &eh[(size_t)i * 256];
    double vres[4];
    #pragma unroll
    for (int p = 0; p < 4; p++) {
        const int cc = p * 8 + g8;
        const int jc = __shfl(jown, cc);
        const float* tr = &et[(size_t)jc * 256];
        double a = 0.0;
        #pragma unroll
        for (int tt = 0; tt < 8; tt++) {
            const int o = (tt * 8 + q) * 4;
            f32x4 av = *(const f32x4*)&er[o];
            f32x4 bv = *(const f32x4*)&tr[o];
            a += (double)av[0] * bv[0] + (double)av[1] * bv[1] +
                 (double)av[2] * bv[2] + (double)av[3] * bv[3];
        }
        a += __shfl_xor(a, 1);
        a += __shfl_xor(a, 2);
        a += __shfl_xor(a, 4);
        vres[p] = a * 0.0625;
    }
    const int src = (c_own & 7) * 8;
    double t0 = __shfl(vres[0], src), t1 = __shfl(vres[1], src);
    double t2 = __shfl(vres[2], src), t3 = __shfl(vres[3], src);
    const int ps = c_own >> 3;
    double v = ps == 0 ? t0 : ps == 1 ? t1 : ps == 2 ? t2 : t3;

    unsigned long long kb = __builtin_bit_cast(unsigned long long, v);
    double key = __builtin_bit_cast(double, (kb & ~31ULL) | (unsigned long long)c_own);
    float wf[6]; int selc[6];
    #pragma unroll
    for (int s = 0; s < 6; s++) {
        double b = key;
        #pragma unroll
        for (int st = 1; st < 32; st <<= 1) {
            double ob = __shfl_xor(b, st);
            b = b > ob ? b : ob;
        }
        selc[s] = (int)(__builtin_bit_cast(unsigned long long, b) & 31ULL);
        wf[s] = (float)b;
        if (key == b) key = -1.0e300;
    }
    int selj[6];
    #pragma unroll
    for (int s = 0; s < 6; s++) selj[s] = __shfl(jown, selc[s]);

    float sp[6];
    {
        float mx = wf[0];
        #pragma unroll
        for (int s = 1; s < 6; s++) mx = fmaxf(mx, wf[s]);
        float se = 0.0f, e6[6];
        #pragma unroll
        for (int s = 0; s < 6; s++) { e6[s] = expf(wf[s] - mx); se += e6[s]; }
        #pragma unroll
        for (int s = 0; s < 6; s++) sp[s] = e6[s] / se;
    }

    f32x4 eh4 = *(const f32x4*)&eh[(size_t)i * 256 + l * 4];
    f32x4 nb[6];
    #pragma unroll
    for (int k = 0; k < 6; k++)
        nb[k] = *(const f32x4*)&et[(size_t)selj[k] * 256 + l * 4];

    float pgs[6], pns[6];
    #pragma unroll
    for (int k = 0; k < 6; k++) {
        const float pk = sp[k];
        float pg = 0.0f;
        #pragma unroll
        for (int e = 0; e < 4; e++) {
            float ehd = eh4[e], nbd = nb[k][e];
            float ehr = pk * nbd + (1.0f - pk) * ehd;
            pg += tanhf(ehd + ehr);
        }
        #pragma unroll
        for (int st = 1; st < 64; st <<= 1) pg += __shfl_xor(pg, st);
        pgs[k] = pg;
        pns[k] = rowsum[selj[k]];
    }

    float skp[6];
    {
        float ka[6], mx = -3.0e38f, se = 0.0f;
        #pragma unroll
        for (int k = 0; k < 6; k++) { ka[k] = pns[k] * pgs[k]; mx = fmaxf(mx, ka[k]); }
        #pragma unroll
        for (int k = 0; k < 6; k++) { ka[k] = expf(ka[k] - mx); se += ka[k]; }
        #pragma unroll
        for (int k = 0; k < 6; k++) skp[k] = ka[k] / se;
    }

    f32x4 enh = {0.0f, 0.0f, 0.0f, 0.0f};
    #pragma unroll
    for (int k = 0; k < 6; k++) {
        const float kp = skp[k];
        #pragma unroll
        for (int e = 0; e < 4; e++) enh[e] += kp * nb[k][e];
    }
    short4v h1, h2;
    #pragma unroll
    for (int e = 0; e < 4; e++) {
        h1[e] = (short)f2bf(eh4[e] + enh[e]);
        h2[e] = (short)f2bf(eh4[e] * enh[e]);
    }
    *(short4v*)&m1[(size_t)i * 256 + l * 4] = h1;
    *(short4v*)&m2[(size_t)i * 256 + l * 4] = h2;
}

// ---------------------------------------------------------------------------
__launch_bounds__(1024)
__global__ void softmax_g(const float* __restrict__ glog, float* __restrict__ gexp,
                          float* __restrict__ scal, float* __restrict__ oute) {
    const int t = threadIdx.x;
    __shared__ float red[1024];
    if (t < 256) oute[t] = 0.0f;   // zero e_g for wsum atomics
    float v[8];
    float m = -3.0e38f;
    #pragma unroll
    for (int c = 0; c < 8; c++) { v[c] = glog[t + c * 1024]; m = fmaxf(m, v[c]); }
    red[t] = m; __syncthreads();
    for (int st = 512; st > 0; st >>= 1) {
        if (t < st) red[t] = fmaxf(red[t], red[t + st]);
        __syncthreads();
    }
    float gm = red[0]; __syncthreads();
    float s = 0.0f;
    #pragma unroll
    for (int c = 0; c < 8; c++) {
        float e = expf(v[c] - gm);
        gexp[t + c * 1024] = e;
        s += e;
    }
    red[t] = s; __syncthreads();
    for (int st = 512; st > 0; st >>= 1) {
        if (t < st) red[t] += red[t + st];
        __syncthreads();
    }
    if (t == 0) scal[0] = 1.0f / red[0];
}

__launch_bounds__(256)
__global__ void wsum_k(const float* __restrict__ emsg, const float* __restrict__ gexp,
                       const float* __restrict__ scal, float* __restrict__ oute) {
    const int b = blockIdx.x, d = threadIdx.x;
    float s = 0.0f;
    const int i0 = b * 128;
    for (int i = 0; i < 128; i++) s += gexp[i0 + i] * emsg[(size_t)(i0 + i) * 256 + d];
    atomicAdd(&oute[d], s * scal[0]);
}

__global__ void wsbad_k(float* __restrict__ out) { out[3] = 9000.0f; }

// ---------------------------------------------------------------------------
extern "C" void kernel_launch(void* const* d_in, const int* in_sizes, int n_in,
                              void* d_out, int out_size, void* d_ws, size_t ws_size,
                              hipStream_t stream) {
    (void)in_sizes; (void)n_in; (void)out_size;
    const float* x_path = (const float*)d_in[0];
    const float* fc1_W  = (const float*)d_in[1];
    const float* fc1_b  = (const float*)d_in[2];
    const float* Wh     = (const float*)d_in[3];
    const float* bh     = (const float*)d_in[4];
    const float* Wt     = (const float*)d_in[5];
    const float* bt     = (const float*)d_in[6];
    const float* W1     = (const float*)d_in[7];
    const float* b1     = (const float*)d_in[8];
    const float* W2     = (const float*)d_in[9];
    const float* b2     = (const float*)d_in[10];
    const float* Ag1    = (const float*)d_in[11];
    const float* bg1    = (const float*)d_in[12];
    const float* Ag2    = (const float*)d_in[13];
    float* out_f = (float*)d_out;   // fp32: e_msg [0,2097152), e_g [2097152,2097408)

    const size_t WS_NEEDED = 26412048;
    if (ws_size < WS_NEEDED) {
        hipLaunchKernelGGL(wsbad_k, dim3(1), dim3(1), 0, stream, out_f);
        return;
    }

    char* ws = (char*)d_ws;
    float* x     = (float*)(ws + 0);
    unsigned short* et16 = (unsigned short*)(ws + 4194304);
    unsigned short* m1b  = (unsigned short*)(ws + 0);
    unsigned short* m2b  = (unsigned short*)(ws + 4194304);
    float* eh    = (float*)(ws + 8388608);
    float* emsg  = out_f;                     // e_msg written straight to d_out
    float* et    = (float*)(ws + 16777216);
    int*   candi = (int*)  (ws + 25165824);
    float* rowsum= (float*)(ws + 26214400);
    float* colacc= (float*)(ws + 26246912);   // 1KB (after rowsum's 32KB)
    float* biasH = (float*)(ws + 26247936);
    float* biasT = (float*)(ws + 26248960);
    float* glog  = (float*)(ws + 26280960);
    float* gexp  = (float*)(ws + 26313728);
    float* scal  = (float*)(ws + 26412032);

    // weight planes in temporarily-dead regions (all stream-ordered safe):
    unsigned short* Fp = (unsigned short*)(ws + 16777216);   // fc1, in et region
    unsigned short* WHp = (unsigned short*)(ws + 25165824);  // in candi region
    unsigned short* WTp = (unsigned short*)(ws + 25559040);
    unsigned short* P1 = (unsigned short*)(ws + 16777216);   // in et region (post-stageD)
    unsigned short* P2 = (unsigned short*)(ws + 17170432);
    unsigned short* Gp = (unsigned short*)(ws + 25165824);   // in candi region (post-stageD)

    dim3 gg(4, 128);
    // 1) front weight splits (fc1 + Wh + Wt) + zero glog/colacc
    hipLaunchKernelGGL(tsplitAll, dim3(384), dim3(256), 0, stream,
                       fc1_W, Wh, Wt, Fp, WHp, WTp, glog, colacc);
    // 2) x = leaky(x_path @ fc1_W + fc1_b)  [MFMA 3-split, fused col-sums]
    hipLaunchKernelGGL(gemmM, gg, dim3(256), 0, stream,
                       x_path, Fp, fc1_b, x, colacc, 256, 1024, 262144);
    // 3) mean (from colacc) + fold mean-mix into eh/et bias
    hipLaunchKernelGGL(mwv_k, dim3(2), dim3(256), 0, stream,
                       colacc, Wh, bh, Wt, bt, biasH, biasT);
    // 4) eh, et = (0.5x)@{Wh,Wt} + bias'  [dual-B shared-A MFMA 3-split]
    hipLaunchKernelGGL(gemmD, gg, dim3(512), 0, stream,
                       x, WHp, WTp, biasH, biasT, eh, et, 65536);
    // 5) et16 + rowsum
    hipLaunchKernelGGL(epk, dim3(2048), dim3(256), 0, stream, et, et16, rowsum);
    // 6) screening
    hipLaunchKernelGGL(screen2, dim3(4, 64), dim3(512), 0, stream, eh, et16, candi);
    // 7) fp64 select + message -> m1b/m2b
    hipLaunchKernelGGL(stageD, dim3(2048), dim3(256), 0, stream, eh, et, rowsum,
                       candi, m1b, m2b);
    // 8) back weight splits (W1 + W2 + Ag1)
    hipLaunchKernelGGL(tsplit3t, dim3(160), dim3(256), 0, stream,
                       W1, W2, Ag1, P1, P2, Gp);
    // 9) e_msg = leaky(m1@W1+b1) + leaky(m2@W2+b2)  [single-pass dual gemm]
    hipLaunchKernelGGL(gemmE, gg, dim3(256), 0, stream,
                       m1b, m2b, P1, P2, b1, b2, emsg, 65536);
    // 10) readout gemm + fused gate -> glog
    hipLaunchKernelGGL(gemmG, dim3(2, 128), dim3(256), 0, stream,
                       emsg, Gp, bg1, Ag2, glog, 32768);
    // 11-12) softmax (+ e_g zero); weighted sum -> e_g atomics
    hipLaunchKernelGGL(softmax_g, dim3(1), dim3(1024), 0, stream, glog, gexp, scal,
                       out_f + 2097152);
    hipLaunchKernelGGL(wsum_k, dim3(64), dim3(256), 0, stream, emsg, gexp, scal,
                       out_f + 2097152);
}